// Round 1
// baseline (4546.089 us; speedup 1.0000x reference)
//
#include <hip/hip_runtime.h>
#include <math.h>

#define NENT 40000
#define NTE  250000
#define NE   540000      // 2*NTE + NENT
#define DIM0 100
#define DIM  200
#define CCH  128
#define BQ   2048
#define FCK  25600       // CCH*DIM
#define EPSB 1e-5f
#define QCH  512         // query chunk for conv/fc
#define NSPLIT 8
#define KSEG 3200        // FCK / NSPLIT

// ---------------- alpha per edge ----------------
__global__ void k_alp(const int* __restrict__ aet, const float* __restrict__ a2,
                      const float* __restrict__ a3, float* alp1, float* alp2) {
    int e = blockIdx.x * 256 + threadIdx.x;
    if (e >= NE) return;
    int tt = (e < NTE) ? e + NTE : (e < 2 * NTE ? e - NTE : e);
    int t0 = aet[e], t1 = aet[tt];
    alp1[e] = a2[t0] + a2[t1];
    alp2[e] = a3[t0] + a3[t1];
}

// ---------------- edge aggregation (atomic) ----------------
__global__ void k_agg(const int* __restrict__ src, const int* __restrict__ dst,
                      const float* __restrict__ alp, const float* __restrict__ feats,
                      float* __restrict__ acc) {
    int wid = blockIdx.x * (blockDim.x >> 6) + (threadIdx.x >> 6);
    int lane = threadIdx.x & 63;
    int nw = gridDim.x * (blockDim.x >> 6);
    for (int e = wid; e < NE; e += nw) {
        int s = src[e], d = dst[e];
        float a = alp[e];
        const float* fs = feats + (long)s * DIM;
        float* ad = acc + (long)d * DIM;
        for (int j = lane; j < DIM; j += 64)
            unsafeAtomicAdd(&ad[j], fs[j] * a);
    }
}

// ---------------- bias + BN + tanh (in place) ----------------
__global__ void k_bntanh(float* __restrict__ x, const float* __restrict__ bias,
                         const float* __restrict__ bn) {
    long i = (long)blockIdx.x * blockDim.x + threadIdx.x;
    if (i >= (long)NENT * DIM) return;
    int j = (int)(i % DIM);
    float g = bn[j], be = bn[DIM + j], m = bn[2 * DIM + j], v = bn[3 * DIM + j];
    float val = x[i] + bias[j];
    val = g * (val - m) * rsqrtf(v + EPSB) + be;
    x[i] = tanhf(val);
}

// ---------------- transpose: out[k][m] = in[m][k] ----------------
__global__ void k_transpose(const float* __restrict__ in, float* __restrict__ out,
                            int M, int K) {
    __shared__ float t[32][33];
    int k0 = blockIdx.x * 32, m0 = blockIdx.y * 32;
    int tx = threadIdx.x & 31, ty = threadIdx.x >> 5;   // 256 thr: ty 0..7
    for (int i = ty; i < 32; i += 8) {
        int m = m0 + i, k = k0 + tx;
        t[i][tx] = (m < M && k < K) ? in[(long)m * K + k] : 0.f;
    }
    __syncthreads();
    for (int i = ty; i < 32; i += 8) {
        int k = k0 + i, m = m0 + tx;
        if (k < K && m < M) out[(long)k * M + m] = t[tx][i];
    }
}

// ---------------- build bn0-normalized conv input ----------------
__global__ void k_hq(const int* __restrict__ e1, const int* __restrict__ rel,
                     const float* __restrict__ eall, const float* __restrict__ embrel,
                     const float* __restrict__ bn0, float* __restrict__ hq) {
    int i = blockIdx.x * 256 + threadIdx.x;
    if (i >= BQ * 2 * DIM) return;
    int d = i % DIM, c = (i / DIM) & 1, b = i / (2 * DIM);
    float val = (c == 0) ? eall[(long)e1[b] * DIM + d]
                         : embrel[(long)rel[b] * DIM + d];
    float g = bn0[c], be = bn0[2 + c], m = bn0[4 + c], v = bn0[6 + c];
    hq[i] = g * (val - m) * rsqrtf(v + EPSB) + be;
}

// ---------------- conv1d + bias + bn1 + relu (one block per query) ----------------
__global__ __launch_bounds__(256) void k_conv(const float* __restrict__ hq,
                      const float* __restrict__ convw, const float* __restrict__ convb,
                      const float* __restrict__ bn1, float* __restrict__ hconv, int ch0) {
    int bl = blockIdx.x;           // 0..QCH-1
    int b = ch0 + bl;
    __shared__ float hql[2 * DIM];
    __shared__ float cw[CCH * 2 * 5];
    __shared__ float sc[CCH], sh[CCH];
    int t = threadIdx.x;
    for (int i = t; i < 2 * DIM; i += 256) hql[i] = hq[(long)b * 2 * DIM + i];
    for (int i = t; i < CCH * 2 * 5; i += 256) cw[i] = convw[i];
    if (t < CCH) {
        float g = bn1[t], be = bn1[CCH + t], m = bn1[2 * CCH + t], v = bn1[3 * CCH + t];
        float s = g * rsqrtf(v + EPSB);
        sc[t] = s;
        sh[t] = be - m * s + s * convb[t];
    }
    __syncthreads();
    for (int idx = t; idx < CCH * DIM; idx += 256) {
        int p = idx % DIM, c = idx / DIM;
        float sum = 0.f;
        #pragma unroll
        for (int i = 0; i < 2; i++) {
            #pragma unroll
            for (int k = 0; k < 5; k++) {
                int pp = p + k - 2;
                if (pp >= 0 && pp < DIM) sum += hql[i * DIM + pp] * cw[(c * 2 + i) * 5 + k];
            }
        }
        float val = sc[c] * sum + sh[c];
        hconv[(long)bl * FCK + idx] = fmaxf(val, 0.f);
    }
}

// ---------------- generic fp32 GEMM: C[M,N] = A[M,K] * B[K,N] (both row-major) ----
// tile 64x64, Ktile 32, 256 threads, 4x4 per thread. MODE 0: plain (guard n<N).
// MODE 1: sigmoid epilogue, float4 store (requires N % 64 == 0).
template<int MODE>
__global__ __launch_bounds__(256) void k_gemm64(
        const float* __restrict__ A, const float* __restrict__ B, float* __restrict__ C,
        int M, int N, int Kt, int lda, int ldb, int ldc,
        const int* __restrict__ gather, int kseg, long czstride) {
    __shared__ float asT[32][68];
    __shared__ float bs[32][64];
    C += (long)blockIdx.z * czstride;
    int kstart = blockIdx.z * kseg;
    int kend = kstart + kseg; if (kend > Kt) kend = Kt;
    int m0 = blockIdx.y * 64, n0 = blockIdx.x * 64;
    int t = threadIdx.x;
    int tx = t & 15, ty = t >> 4;
    float acc[4][4] = {};
    for (int k0 = kstart; k0 < kend; k0 += 32) {
        #pragma unroll
        for (int i = 0; i < 8; i++) {            // stage A (64r x 32k), transposed
            int idx = t + i * 256;
            int r = idx >> 5, kk = idx & 31;
            int row = m0 + r, k = k0 + kk;
            float v = 0.f;
            if (k < kend) {
                int ar = gather ? gather[row] : row;
                v = A[(long)ar * lda + k];
            }
            asT[kk][r] = v;
        }
        #pragma unroll
        for (int i = 0; i < 8; i++) {            // stage B (32k x 64n)
            int idx = t + i * 256;
            int kk = idx >> 6, nn = idx & 63;
            int k = k0 + kk, n = n0 + nn;
            bs[kk][nn] = (k < kend && n < N) ? B[(long)k * ldb + n] : 0.f;
        }
        __syncthreads();
        #pragma unroll
        for (int kk = 0; kk < 32; kk++) {
            float4 a4 = *(const float4*)&asT[kk][ty * 4];
            float4 b4 = *(const float4*)&bs[kk][tx * 4];
            float av[4] = {a4.x, a4.y, a4.z, a4.w};
            float bv[4] = {b4.x, b4.y, b4.z, b4.w};
            #pragma unroll
            for (int i = 0; i < 4; i++)
                #pragma unroll
                for (int j = 0; j < 4; j++)
                    acc[i][j] += av[i] * bv[j];
        }
        __syncthreads();
    }
    if (MODE == 0) {
        #pragma unroll
        for (int i = 0; i < 4; i++) {
            long row = m0 + ty * 4 + i;
            #pragma unroll
            for (int j = 0; j < 4; j++) {
                int col = n0 + tx * 4 + j;
                if (col < N) C[row * ldc + col] = acc[i][j];
            }
        }
    } else {
        #pragma unroll
        for (int i = 0; i < 4; i++) {
            long row = m0 + ty * 4 + i;
            float4 o;
            o.x = 1.f / (1.f + __expf(-acc[i][0]));
            o.y = 1.f / (1.f + __expf(-acc[i][1]));
            o.z = 1.f / (1.f + __expf(-acc[i][2]));
            o.w = 1.f / (1.f + __expf(-acc[i][3]));
            *(float4*)&C[row * ldc + n0 + tx * 4] = o;
        }
    }
}

// ---------------- split-K reduce + fc bias + bn2 + relu ----------------
__global__ void k_fcreduce(const float* __restrict__ fcpart, const float* __restrict__ fcb,
                           const float* __restrict__ bn2, float* __restrict__ h3) {
    int i = blockIdx.x * 256 + threadIdx.x;
    if (i >= BQ * DIM) return;
    int j = i % DIM;
    float s = 0.f;
    #pragma unroll
    for (int ks = 0; ks < NSPLIT; ks++) s += fcpart[(long)ks * BQ * DIM + i];
    s += fcb[j];
    float g = bn2[j], be = bn2[DIM + j], m = bn2[2 * DIM + j], v = bn2[3 * DIM + j];
    s = g * (s - m) * rsqrtf(v + EPSB) + be;
    h3[i] = fmaxf(s, 0.f);
}

extern "C" void kernel_launch(void* const* d_in, const int* in_sizes, int n_in,
                              void* d_out, int out_size, void* d_ws, size_t ws_size,
                              hipStream_t stream) {
    (void)in_sizes; (void)n_in; (void)out_size; (void)ws_size;
    const int* src      = (const int*)d_in[0];
    const int* dst      = (const int*)d_in[1];
    const int* aet      = (const int*)d_in[2];
    const int* e1       = (const int*)d_in[3];
    const int* rel      = (const int*)d_in[4];
    const int* entity   = (const int*)d_in[5];
    const float* emb_e  = (const float*)d_in[6];
    const float* embrel = (const float*)d_in[7];
    const float* w2     = (const float*)d_in[8];
    const float* b2     = (const float*)d_in[9];
    const float* alpha2 = (const float*)d_in[10];
    const float* w3     = (const float*)d_in[11];
    const float* b3     = (const float*)d_in[12];
    const float* alpha3 = (const float*)d_in[13];
    const float* bn3    = (const float*)d_in[14];
    const float* bn4    = (const float*)d_in[15];
    const float* bn0    = (const float*)d_in[16];
    const float* bn1    = (const float*)d_in[17];
    const float* bn2    = (const float*)d_in[18];
    const float* convw  = (const float*)d_in[19];
    const float* convb  = (const float*)d_in[20];
    const float* fcw    = (const float*)d_in[21];
    const float* fcb    = (const float*)d_in[22];
    float* out = (float*)d_out;
    float* ws = (float*)d_ws;

    // workspace layout (floats)
    float* feats  = ws;                  //  8,000,000  [40000 x 200]
    float* acc    = ws + 8000000;        //  8,000,000
    float* xbuf   = ws + 16000000;       //  8,000,000  (e_all)
    float* eT     = ws + 24000000;       //  8,000,000  [200 x 40000]
    float* fcwT   = ws + 32000000;       //  5,120,000  [25600 x 200]
    float* alp1   = ws + 37120000;       //    540,000
    float* alp2   = ws + 37660000;       //    540,000
    float* hq     = ws + 38200000;       //    819,200  [2048 x 2 x 200]
    float* fcpart = ws + 39019200;       //  3,276,800  [8 x 2048 x 200]
    float* h3     = ws + 42296000;       //    409,600
    float* hconv  = ws;                  // reuse feats+acc region: 13,107,200 floats

    // zero aggregation targets (acc + xbuf contiguous)
    hipMemsetAsync(acc, 0, (size_t)16000000 * 4, stream);

    k_alp<<<(NE + 255) / 256, 256, 0, stream>>>(aet, alpha2, alpha3, alp1, alp2);

    // GCN layer 1: feats = emb_e[entity] @ w2  (M=40000,N=200,K=100)
    k_gemm64<0><<<dim3(4, 625, 1), 256, 0, stream>>>(emb_e, w2, feats,
        NENT, DIM, DIM0, DIM0, DIM, DIM, entity, DIM0, 0);
    k_agg<<<2048, 256, 0, stream>>>(src, dst, alp1, feats, acc);
    k_bntanh<<<(NENT * DIM + 255) / 256, 256, 0, stream>>>(acc, b2, bn3);

    // GCN layer 2: feats = x1 @ w3  (M=40000,N=200,K=200)
    k_gemm64<0><<<dim3(4, 625, 1), 256, 0, stream>>>(acc, w3, feats,
        NENT, DIM, DIM, DIM, DIM, DIM, nullptr, DIM, 0);
    k_agg<<<2048, 256, 0, stream>>>(src, dst, alp2, feats, xbuf);
    k_bntanh<<<(NENT * DIM + 255) / 256, 256, 0, stream>>>(xbuf, b3, bn4);

    // transposes for GEMM-friendly B operands
    k_transpose<<<dim3(7, 1250), 256, 0, stream>>>(xbuf, eT, NENT, DIM);
    k_transpose<<<dim3(800, 7), 256, 0, stream>>>(fcw, fcwT, DIM, FCK);

    // decoder input (bn0 applied)
    k_hq<<<(BQ * 2 * DIM + 255) / 256, 256, 0, stream>>>(e1, rel, xbuf, embrel, bn0, hq);

    // conv + fc in query chunks of QCH
    for (int ch = 0; ch < BQ / QCH; ch++) {
        int ch0 = ch * QCH;
        k_conv<<<QCH, 256, 0, stream>>>(hq, convw, convb, bn1, hconv, ch0);
        // fc: [QCH, 25600] @ [25600, 200] with split-K=8 into fcpart
        k_gemm64<0><<<dim3(4, QCH / 64, NSPLIT), 256, 0, stream>>>(hconv, fcwT,
            fcpart + (long)ch0 * DIM, QCH, DIM, FCK, FCK, DIM, DIM,
            nullptr, KSEG, (long)BQ * DIM);
    }
    k_fcreduce<<<(BQ * DIM + 255) / 256, 256, 0, stream>>>(fcpart, fcb, bn2, h3);

    // final: sigmoid(h3 @ e_all^T)  (M=2048, N=40000, K=200)
    k_gemm64<1><<<dim3(625, 32, 1), 256, 0, stream>>>(h3, eT, out,
        BQ, NENT, DIM, DIM, NENT, NENT, nullptr, DIM, 0);
}

// Round 2
// 3352.927 us; speedup vs baseline: 1.3559x; 1.3559x over previous
//
#include <hip/hip_runtime.h>
#include <math.h>

#define NENT 40000
#define NTE  250000
#define NE   540000      // 2*NTE + NENT
#define DIM0 100
#define DIM  200
#define CCH  128
#define BQ   2048
#define FCK  25600       // CCH*DIM
#define EPSB 1e-5f
#define QCH  512         // query chunk for conv/fc
#define NSPLIT 8
#define KSEG 3200        // FCK / NSPLIT
#define KPAD 224         // K=200 padded to 7*32 for final gemm

typedef short bf16x8 __attribute__((ext_vector_type(8)));
typedef float f32x4 __attribute__((ext_vector_type(4)));

// split float into bf16 hi + bf16 lo (round-to-nearest each); hi+lo ~ fp32-17bit
__device__ __forceinline__ void split_bf16(float x, unsigned short& hi, unsigned short& lo) {
    unsigned u = __float_as_uint(x);
    unsigned r = (u + 0x7fffu + ((u >> 16) & 1u)) >> 16;
    hi = (unsigned short)r;
    float rem = x - __uint_as_float(r << 16);
    unsigned u2 = __float_as_uint(rem);
    unsigned r2 = (u2 + 0x7fffu + ((u2 >> 16) & 1u)) >> 16;
    lo = (unsigned short)r2;
}

// ---------------- alpha per edge ----------------
__global__ void k_alp(const int* __restrict__ aet, const float* __restrict__ a2,
                      const float* __restrict__ a3, float* alp1, float* alp2) {
    int e = blockIdx.x * 256 + threadIdx.x;
    if (e >= NE) return;
    int tt = (e < NTE) ? e + NTE : (e < 2 * NTE ? e - NTE : e);
    int t0 = aet[e], t1 = aet[tt];
    alp1[e] = a2[t0] + a2[t1];
    alp2[e] = a3[t0] + a3[t1];
}

// ---------------- edge aggregation (atomic) ----------------
__global__ void k_agg(const int* __restrict__ src, const int* __restrict__ dst,
                      const float* __restrict__ alp, const float* __restrict__ feats,
                      float* __restrict__ acc) {
    int wid = blockIdx.x * (blockDim.x >> 6) + (threadIdx.x >> 6);
    int lane = threadIdx.x & 63;
    int nw = gridDim.x * (blockDim.x >> 6);
    for (int e = wid; e < NE; e += nw) {
        int s = src[e], d = dst[e];
        float a = alp[e];
        const float* fs = feats + (long)s * DIM;
        float* ad = acc + (long)d * DIM;
        for (int j = lane; j < DIM; j += 64)
            unsafeAtomicAdd(&ad[j], fs[j] * a);
    }
}

// ---------------- bias + BN + tanh (in place) ----------------
__global__ void k_bntanh(float* __restrict__ x, const float* __restrict__ bias,
                         const float* __restrict__ bn) {
    long i = (long)blockIdx.x * blockDim.x + threadIdx.x;
    if (i >= (long)NENT * DIM) return;
    int j = (int)(i % DIM);
    float g = bn[j], be = bn[DIM + j], m = bn[2 * DIM + j], v = bn[3 * DIM + j];
    float val = x[i] + bias[j];
    val = g * (val - m) * rsqrtf(v + EPSB) + be;
    x[i] = tanhf(val);
}

// ---------------- build bn0-normalized conv input ----------------
__global__ void k_hq(const int* __restrict__ e1, const int* __restrict__ rel,
                     const float* __restrict__ eall, const float* __restrict__ embrel,
                     const float* __restrict__ bn0, float* __restrict__ hq) {
    int i = blockIdx.x * 256 + threadIdx.x;
    if (i >= BQ * 2 * DIM) return;
    int d = i % DIM, c = (i / DIM) & 1, b = i / (2 * DIM);
    float val = (c == 0) ? eall[(long)e1[b] * DIM + d]
                         : embrel[(long)rel[b] * DIM + d];
    float g = bn0[c], be = bn0[2 + c], m = bn0[4 + c], v = bn0[6 + c];
    hq[i] = g * (val - m) * rsqrtf(v + EPSB) + be;
}

// ---------------- pack e_all -> bf16 hi/lo planes [NENT][KPAD] ----------------
__global__ void k_pack_e(const float* __restrict__ x, unsigned short* __restrict__ eh,
                         unsigned short* __restrict__ el) {
    int i = blockIdx.x * 256 + threadIdx.x;
    if (i >= NENT * KPAD) return;
    int j = i % KPAD, m = i / KPAD;
    unsigned short hi = 0, lo = 0;
    if (j < DIM) split_bf16(x[(long)m * DIM + j], hi, lo);
    eh[i] = hi; el[i] = lo;
}

// ---------------- pack fcw -> bf16 hi/lo planes [208][FCK] ----------------
__global__ void k_pack_fcw(const float* __restrict__ w, unsigned short* __restrict__ wh,
                           unsigned short* __restrict__ wl) {
    long i = (long)blockIdx.x * 256 + threadIdx.x;
    if (i >= (long)208 * FCK) return;
    int r = (int)(i / FCK);
    unsigned short hi = 0, lo = 0;
    if (r < DIM) split_bf16(w[i], hi, lo);
    wh[i] = hi; wl[i] = lo;
}

// ---------------- conv1d + bias + bn1 + relu -> bf16 hi/lo planes ----------------
__global__ __launch_bounds__(256) void k_conv(const float* __restrict__ hq,
                      const float* __restrict__ convw, const float* __restrict__ convb,
                      const float* __restrict__ bn1, unsigned short* __restrict__ hch,
                      unsigned short* __restrict__ hcl, int ch0) {
    int bl = blockIdx.x;           // 0..QCH-1
    int b = ch0 + bl;
    __shared__ float hql[2 * DIM];
    __shared__ float cw[CCH * 2 * 5];
    __shared__ float sc[CCH], sh[CCH];
    int t = threadIdx.x;
    for (int i = t; i < 2 * DIM; i += 256) hql[i] = hq[(long)b * 2 * DIM + i];
    for (int i = t; i < CCH * 2 * 5; i += 256) cw[i] = convw[i];
    if (t < CCH) {
        float g = bn1[t], be = bn1[CCH + t], m = bn1[2 * CCH + t], v = bn1[3 * CCH + t];
        float s = g * rsqrtf(v + EPSB);
        sc[t] = s;
        sh[t] = be - m * s + s * convb[t];
    }
    __syncthreads();
    for (int idx = t; idx < CCH * DIM; idx += 256) {
        int p = idx % DIM, c = idx / DIM;
        float sum = 0.f;
        #pragma unroll
        for (int i = 0; i < 2; i++) {
            #pragma unroll
            for (int k = 0; k < 5; k++) {
                int pp = p + k - 2;
                if (pp >= 0 && pp < DIM) sum += hql[i * DIM + pp] * cw[(c * 2 + i) * 5 + k];
            }
        }
        float val = fmaxf(sc[c] * sum + sh[c], 0.f);
        unsigned short hi, lo;
        split_bf16(val, hi, lo);
        hch[(long)bl * FCK + idx] = hi;
        hcl[(long)bl * FCK + idx] = lo;
    }
}

// ---------------- fp32 GEMM for the two GCN layers (M=40000, small K) --------
template<int MODE>
__global__ __launch_bounds__(256) void k_gemm64(
        const float* __restrict__ A, const float* __restrict__ B, float* __restrict__ C,
        int M, int N, int Kt, int lda, int ldb, int ldc,
        const int* __restrict__ gather, int kseg, long czstride) {
    __shared__ float asT[32][68];
    __shared__ float bs[32][64];
    C += (long)blockIdx.z * czstride;
    int kstart = blockIdx.z * kseg;
    int kend = kstart + kseg; if (kend > Kt) kend = Kt;
    int m0 = blockIdx.y * 64, n0 = blockIdx.x * 64;
    int t = threadIdx.x;
    int tx = t & 15, ty = t >> 4;
    float acc[4][4] = {};
    for (int k0 = kstart; k0 < kend; k0 += 32) {
        #pragma unroll
        for (int i = 0; i < 8; i++) {
            int idx = t + i * 256;
            int r = idx >> 5, kk = idx & 31;
            int row = m0 + r, k = k0 + kk;
            float v = 0.f;
            if (k < kend) {
                int ar = gather ? gather[row] : row;
                v = A[(long)ar * lda + k];
            }
            asT[kk][r] = v;
        }
        #pragma unroll
        for (int i = 0; i < 8; i++) {
            int idx = t + i * 256;
            int kk = idx >> 6, nn = idx & 63;
            int k = k0 + kk, n = n0 + nn;
            bs[kk][nn] = (k < kend && n < N) ? B[(long)k * ldb + n] : 0.f;
        }
        __syncthreads();
        #pragma unroll
        for (int kk = 0; kk < 32; kk++) {
            float4 a4 = *(const float4*)&asT[kk][ty * 4];
            float4 b4 = *(const float4*)&bs[kk][tx * 4];
            float av[4] = {a4.x, a4.y, a4.z, a4.w};
            float bv[4] = {b4.x, b4.y, b4.z, b4.w};
            #pragma unroll
            for (int i = 0; i < 4; i++)
                #pragma unroll
                for (int j = 0; j < 4; j++)
                    acc[i][j] += av[i] * bv[j];
        }
        __syncthreads();
    }
    #pragma unroll
    for (int i = 0; i < 4; i++) {
        long row = m0 + ty * 4 + i;
        #pragma unroll
        for (int j = 0; j < 4; j++) {
            int col = n0 + tx * 4 + j;
            if (col < N) C[row * ldc + col] = acc[i][j];
        }
    }
}

// ---------------- FC: [QCH,25600] x fcw^T -> fcpart, MFMA hi/lo split --------
__global__ __launch_bounds__(256) void k_mfma_fc(
        const unsigned short* __restrict__ Ahi, const unsigned short* __restrict__ Alo,
        const unsigned short* __restrict__ Bhi, const unsigned short* __restrict__ Blo,
        float* __restrict__ part, int ch0) {
    int split = blockIdx.x;                 // 0..NSPLIT-1
    int w = threadIdx.x >> 6, l = threadIdx.x & 63;
    int mloc = blockIdx.y * 64 + w * 16 + (l & 15);
    int kb = split * KSEG + (l >> 4) * 8;
    const unsigned short* aph = Ahi + (long)mloc * FCK + kb;
    const unsigned short* apl = Alo + (long)mloc * FCK + kb;
    int nrow = l & 15;
    f32x4 acc[13];
    #pragma unroll
    for (int i = 0; i < 13; i++) acc[i] = (f32x4){0.f, 0.f, 0.f, 0.f};
    for (int ks = 0; ks < KSEG; ks += 32) {
        bf16x8 ah = *(const bf16x8*)(aph + ks);
        bf16x8 al = *(const bf16x8*)(apl + ks);
        #pragma unroll
        for (int nt = 0; nt < 13; nt++) {
            const bf16x8 bh = *(const bf16x8*)(Bhi + (long)(nt * 16 + nrow) * FCK + kb + ks);
            const bf16x8 bl = *(const bf16x8*)(Blo + (long)(nt * 16 + nrow) * FCK + kb + ks);
            acc[nt] = __builtin_amdgcn_mfma_f32_16x16x32_bf16(ah, bh, acc[nt], 0, 0, 0);
            acc[nt] = __builtin_amdgcn_mfma_f32_16x16x32_bf16(ah, bl, acc[nt], 0, 0, 0);
            acc[nt] = __builtin_amdgcn_mfma_f32_16x16x32_bf16(al, bh, acc[nt], 0, 0, 0);
        }
    }
    int rowbase = ch0 + blockIdx.y * 64 + w * 16 + (l >> 4) * 4;
    #pragma unroll
    for (int nt = 0; nt < 13; nt++) {
        int col = nt * 16 + nrow;
        if (col < DIM) {
            #pragma unroll
            for (int r = 0; r < 4; r++)
                part[(long)split * BQ * DIM + (long)(rowbase + r) * DIM + col] = acc[nt][r];
        }
    }
}

// ---------------- split-K reduce + fc bias + bn2 + relu -> h3 bf16 planes ----
__global__ void k_fcreduce(const float* __restrict__ fcpart, const float* __restrict__ fcb,
                           const float* __restrict__ bn2, unsigned short* __restrict__ h3h,
                           unsigned short* __restrict__ h3l) {
    int i = blockIdx.x * 256 + threadIdx.x;
    if (i >= BQ * KPAD) return;
    int j = i % KPAD, b = i / KPAD;
    unsigned short hi = 0, lo = 0;
    if (j < DIM) {
        float s = 0.f;
        #pragma unroll
        for (int ks = 0; ks < NSPLIT; ks++) s += fcpart[(long)ks * BQ * DIM + (long)b * DIM + j];
        s += fcb[j];
        float g = bn2[j], be = bn2[DIM + j], m = bn2[2 * DIM + j], v = bn2[3 * DIM + j];
        s = g * (s - m) * rsqrtf(v + EPSB) + be;
        s = fmaxf(s, 0.f);
        split_bf16(s, hi, lo);
    }
    h3h[i] = hi; h3l[i] = lo;
}

// ---------------- final: sigmoid(h3 @ e_all^T), MFMA hi/lo split -------------
__global__ __launch_bounds__(256) void k_mfma_final(
        const unsigned short* __restrict__ Ahi, const unsigned short* __restrict__ Alo,
        const unsigned short* __restrict__ Bhi, const unsigned short* __restrict__ Blo,
        float* __restrict__ out) {
    int w = threadIdx.x >> 6, l = threadIdx.x & 63;
    int n0 = blockIdx.x * 64;
    int m0 = blockIdx.y * 128 + w * 32;
    int arow = m0 + (l & 15);
    int brow = n0 + (l & 15);
    int kb = (l >> 4) * 8;
    const unsigned short* a0h = Ahi + (long)arow * KPAD + kb;
    const unsigned short* a0l = Alo + (long)arow * KPAD + kb;
    const unsigned short* bph = Bhi + (long)brow * KPAD + kb;
    const unsigned short* bpl = Blo + (long)brow * KPAD + kb;
    f32x4 acc[2][4];
    #pragma unroll
    for (int i = 0; i < 2; i++)
        #pragma unroll
        for (int j = 0; j < 4; j++) acc[i][j] = (f32x4){0.f, 0.f, 0.f, 0.f};
    for (int kt = 0; kt < 7; kt++) {
        int ko = kt * 32;
        bf16x8 ah0 = *(const bf16x8*)(a0h + ko);
        bf16x8 al0 = *(const bf16x8*)(a0l + ko);
        bf16x8 ah1 = *(const bf16x8*)(a0h + 16 * KPAD + ko);
        bf16x8 al1 = *(const bf16x8*)(a0l + 16 * KPAD + ko);
        #pragma unroll
        for (int nt = 0; nt < 4; nt++) {
            bf16x8 bh = *(const bf16x8*)(bph + (long)nt * 16 * KPAD + ko);
            bf16x8 bl = *(const bf16x8*)(bpl + (long)nt * 16 * KPAD + ko);
            acc[0][nt] = __builtin_amdgcn_mfma_f32_16x16x32_bf16(ah0, bh, acc[0][nt], 0, 0, 0);
            acc[0][nt] = __builtin_amdgcn_mfma_f32_16x16x32_bf16(ah0, bl, acc[0][nt], 0, 0, 0);
            acc[0][nt] = __builtin_amdgcn_mfma_f32_16x16x32_bf16(al0, bh, acc[0][nt], 0, 0, 0);
            acc[1][nt] = __builtin_amdgcn_mfma_f32_16x16x32_bf16(ah1, bh, acc[1][nt], 0, 0, 0);
            acc[1][nt] = __builtin_amdgcn_mfma_f32_16x16x32_bf16(ah1, bl, acc[1][nt], 0, 0, 0);
            acc[1][nt] = __builtin_amdgcn_mfma_f32_16x16x32_bf16(al1, bh, acc[1][nt], 0, 0, 0);
        }
    }
    int colb = n0 + (l & 15);
    int rowb = m0 + (l >> 4) * 4;
    #pragma unroll
    for (int mt = 0; mt < 2; mt++)
        #pragma unroll
        for (int r = 0; r < 4; r++) {
            long row = rowb + mt * 16 + r;
            #pragma unroll
            for (int nt = 0; nt < 4; nt++) {
                float v = acc[mt][nt][r];
                out[row * NENT + colb + nt * 16] = 1.f / (1.f + __expf(-v));
            }
        }
}

extern "C" void kernel_launch(void* const* d_in, const int* in_sizes, int n_in,
                              void* d_out, int out_size, void* d_ws, size_t ws_size,
                              hipStream_t stream) {
    (void)in_sizes; (void)n_in; (void)out_size; (void)ws_size;
    const int* src      = (const int*)d_in[0];
    const int* dst      = (const int*)d_in[1];
    const int* aet      = (const int*)d_in[2];
    const int* e1       = (const int*)d_in[3];
    const int* rel      = (const int*)d_in[4];
    const int* entity   = (const int*)d_in[5];
    const float* emb_e  = (const float*)d_in[6];
    const float* embrel = (const float*)d_in[7];
    const float* w2     = (const float*)d_in[8];
    const float* b2     = (const float*)d_in[9];
    const float* alpha2 = (const float*)d_in[10];
    const float* w3     = (const float*)d_in[11];
    const float* b3     = (const float*)d_in[12];
    const float* alpha3 = (const float*)d_in[13];
    const float* bn3    = (const float*)d_in[14];
    const float* bn4    = (const float*)d_in[15];
    const float* bn0    = (const float*)d_in[16];
    const float* bn1    = (const float*)d_in[17];
    const float* bn2    = (const float*)d_in[18];
    const float* convw  = (const float*)d_in[19];
    const float* convb  = (const float*)d_in[20];
    const float* fcw    = (const float*)d_in[21];
    const float* fcb    = (const float*)d_in[22];
    float* out = (float*)d_out;
    float* ws = (float*)d_ws;

    // ---- workspace layout (float offsets) ----
    float* feats   = ws;                         // 8.00M  [40000 x 200]
    float* acc     = ws + 8000000;               // 8.00M
    float* xbuf    = ws + 16000000;              // 8.00M  (e_all fp32)
    float* alp1    = ws + 24000000;              // 0.54M  (dead after agg2)
    float* alp2    = ws + 24540000;              // 0.54M
    unsigned short* e_hi  = (unsigned short*)(ws + 24000000);  // 4.48M f (overlays alp, used later)
    unsigned short* e_lo  = (unsigned short*)(ws + 28480000);  // 4.48M f
    unsigned short* fcw_h = (unsigned short*)(ws + 32960000);  // 2.6624M f [208][25600]
    unsigned short* fcw_l = (unsigned short*)(ws + 35622400);  // 2.6624M f
    float* hq      = ws + 38290000;              // 0.8192M [2048][2][200]
    float* fcpart  = ws + 39110000;              // 3.2768M [8][2048][200]
    unsigned short* h3_h  = (unsigned short*)(ws + 42386800);  // 0.2294M f [2048][224]
    unsigned short* h3_l  = (unsigned short*)(ws + 42616176);  // 0.2294M f
    unsigned short* hc_h  = (unsigned short*)ws;               // 6.55M f  (reuses feats)
    unsigned short* hc_l  = (unsigned short*)(ws + 6600000);   // 6.55M f  (reuses feats/acc)

    // zero aggregation targets (acc + xbuf contiguous)
    hipMemsetAsync(acc, 0, (size_t)16000000 * 4, stream);

    k_alp<<<(NE + 255) / 256, 256, 0, stream>>>(aet, alpha2, alpha3, alp1, alp2);

    // GCN layer 1: feats = emb_e[entity] @ w2  (M=40000,N=200,K=100)
    k_gemm64<0><<<dim3(4, 625, 1), 256, 0, stream>>>(emb_e, w2, feats,
        NENT, DIM, DIM0, DIM0, DIM, DIM, entity, DIM0, 0);
    k_agg<<<2048, 256, 0, stream>>>(src, dst, alp1, feats, acc);
    k_bntanh<<<(NENT * DIM + 255) / 256, 256, 0, stream>>>(acc, b2, bn3);

    // GCN layer 2: feats = x1 @ w3  (M=40000,N=200,K=200)
    k_gemm64<0><<<dim3(4, 625, 1), 256, 0, stream>>>(acc, w3, feats,
        NENT, DIM, DIM, DIM, DIM, DIM, nullptr, DIM, 0);
    k_agg<<<2048, 256, 0, stream>>>(src, dst, alp2, feats, xbuf);
    k_bntanh<<<(NENT * DIM + 255) / 256, 256, 0, stream>>>(xbuf, b3, bn4);

    // decoder input (bn0 applied) — reads xbuf, must run before anything clobbers it
    k_hq<<<(BQ * 2 * DIM + 255) / 256, 256, 0, stream>>>(e1, rel, xbuf, embrel, bn0, hq);

    // pack e_all and fcw into bf16 hi/lo planes
    k_pack_e<<<(NENT * KPAD + 255) / 256, 256, 0, stream>>>(xbuf, e_hi, e_lo);
    k_pack_fcw<<<(int)(((long)208 * FCK + 255) / 256), 256, 0, stream>>>(fcw, fcw_h, fcw_l);

    // conv + fc in query chunks of QCH
    for (int ch = 0; ch < BQ / QCH; ch++) {
        int ch0 = ch * QCH;
        k_conv<<<QCH, 256, 0, stream>>>(hq, convw, convb, bn1, hc_h, hc_l, ch0);
        k_mfma_fc<<<dim3(NSPLIT, QCH / 64), 256, 0, stream>>>(hc_h, hc_l, fcw_h, fcw_l,
                                                              fcpart, ch0);
    }
    k_fcreduce<<<(BQ * KPAD + 255) / 256, 256, 0, stream>>>(fcpart, fcb, bn2, h3_h, h3_l);

    // final: sigmoid(h3 @ e_all^T)  (M=2048, N=40000, K=200->224)
    k_mfma_final<<<dim3(NENT / 64, BQ / 128), 256, 0, stream>>>(h3_h, h3_l, e_hi, e_lo, out);
}

// Round 3
// 1812.836 us; speedup vs baseline: 2.5077x; 1.8495x over previous
//
#include <hip/hip_runtime.h>
#include <math.h>

#define NENT 40000
#define NTE  250000
#define NE   540000      // 2*NTE + NENT
#define DIM0 100
#define DIM  200
#define CCH  128
#define BQ   2048
#define FCK  25600       // CCH*DIM
#define FCK2 25632       // padded k-stride for fcw planes (OOB-safe k tail)
#define EPSB 1e-5f
#define CSPLIT 16        // channel groups for fused conv+fc
#define CPG  8           // channels per group
#define KPAD 224         // K=200 padded to 7*32

typedef short bf16x8 __attribute__((ext_vector_type(8)));
typedef float f32x4 __attribute__((ext_vector_type(4)));

// split float into bf16 hi + bf16 lo (round-to-nearest each); hi+lo ~ fp32-17bit
__device__ __forceinline__ void split_bf16(float x, unsigned short& hi, unsigned short& lo) {
    unsigned u = __float_as_uint(x);
    unsigned r = (u + 0x7fffu + ((u >> 16) & 1u)) >> 16;
    hi = (unsigned short)r;
    float rem = x - __uint_as_float(r << 16);
    unsigned u2 = __float_as_uint(rem);
    unsigned r2 = (u2 + 0x7fffu + ((u2 >> 16) & 1u)) >> 16;
    lo = (unsigned short)r2;
}

// ---------------- alpha per edge ----------------
__global__ void k_alp(const int* __restrict__ aet, const float* __restrict__ a2,
                      const float* __restrict__ a3, float* alp1, float* alp2) {
    int e = blockIdx.x * 256 + threadIdx.x;
    if (e >= NE) return;
    int tt = (e < NTE) ? e + NTE : (e < 2 * NTE ? e - NTE : e);
    int t0 = aet[e], t1 = aet[tt];
    alp1[e] = a2[t0] + a2[t1];
    alp2[e] = a3[t0] + a3[t1];
}

// ---------------- edge aggregation (atomic) ----------------
__global__ void k_agg(const int* __restrict__ src, const int* __restrict__ dst,
                      const float* __restrict__ alp, const float* __restrict__ feats,
                      float* __restrict__ acc) {
    int wid = blockIdx.x * (blockDim.x >> 6) + (threadIdx.x >> 6);
    int lane = threadIdx.x & 63;
    int nw = gridDim.x * (blockDim.x >> 6);
    for (int e = wid; e < NE; e += nw) {
        int s = src[e], d = dst[e];
        float a = alp[e];
        const float* fs = feats + (long)s * DIM;
        float* ad = acc + (long)d * DIM;
        for (int j = lane; j < DIM; j += 64)
            unsafeAtomicAdd(&ad[j], fs[j] * a);
    }
}

// ---------------- bias + BN + tanh (in place, fp32) ----------------
__global__ void k_bntanh(float* __restrict__ x, const float* __restrict__ bias,
                         const float* __restrict__ bn) {
    long i = (long)blockIdx.x * blockDim.x + threadIdx.x;
    if (i >= (long)NENT * DIM) return;
    int j = (int)(i % DIM);
    float g = bn[j], be = bn[DIM + j], m = bn[2 * DIM + j], v = bn[3 * DIM + j];
    float val = x[i] + bias[j];
    val = g * (val - m) * rsqrtf(v + EPSB) + be;
    x[i] = tanhf(val);
}

// ---------------- bias + BN + tanh -> bf16 hi/lo planes [NENT][KPAD] ---------
__global__ void k_bntanh_pack(const float* __restrict__ x, const float* __restrict__ bias,
                              const float* __restrict__ bn, unsigned short* __restrict__ oh,
                              unsigned short* __restrict__ ol) {
    long i = (long)blockIdx.x * 256 + threadIdx.x;
    if (i >= (long)NENT * KPAD) return;
    int j = (int)(i % KPAD);
    long row = i / KPAD;
    unsigned short hi = 0, lo = 0;
    if (j < DIM) {
        float g = bn[j], be = bn[DIM + j], m = bn[2 * DIM + j], v = bn[3 * DIM + j];
        float val = x[row * DIM + j] + bias[j];
        val = g * (val - m) * rsqrtf(v + EPSB) + be;
        val = tanhf(val);
        split_bf16(val, hi, lo);
    }
    oh[i] = hi; ol[i] = lo;
}

// ---------------- pack emb_e[entity] -> hi/lo planes [NENT][128] -------------
__global__ void k_pack_A1(const float* __restrict__ emb, const int* __restrict__ ent,
                          unsigned short* __restrict__ ah, unsigned short* __restrict__ al) {
    long i = (long)blockIdx.x * 256 + threadIdx.x;
    if (i >= (long)NENT * 128) return;
    int k = (int)(i & 127);
    long m = i >> 7;
    unsigned short hi = 0, lo = 0;
    if (k < DIM0) split_bf16(emb[(long)ent[m] * DIM0 + k], hi, lo);
    ah[i] = hi; al[i] = lo;
}

// ---------------- pack+transpose layer weight [kin][200] -> [208][kpad] ------
__global__ void k_pack_B(const float* __restrict__ w, unsigned short* __restrict__ bh,
                         unsigned short* __restrict__ bl, int kin, int kpad) {
    int i = blockIdx.x * 256 + threadIdx.x;
    if (i >= 208 * kpad) return;
    int k = i % kpad, n = i / kpad;
    unsigned short hi = 0, lo = 0;
    if (k < kin && n < DIM) split_bf16(w[(long)k * DIM + n], hi, lo);
    bh[i] = hi; bl[i] = lo;
}

// ---------------- build bn0-normalized conv input ----------------
__global__ void k_hq(const int* __restrict__ e1, const int* __restrict__ rel,
                     const float* __restrict__ eall, const float* __restrict__ embrel,
                     const float* __restrict__ bn0, float* __restrict__ hq) {
    int i = blockIdx.x * 256 + threadIdx.x;
    if (i >= BQ * 2 * DIM) return;
    int d = i % DIM, c = (i / DIM) & 1, b = i / (2 * DIM);
    float val = (c == 0) ? eall[(long)e1[b] * DIM + d]
                         : embrel[(long)rel[b] * DIM + d];
    float g = bn0[c], be = bn0[2 + c], m = bn0[4 + c], v = bn0[6 + c];
    hq[i] = g * (val - m) * rsqrtf(v + EPSB) + be;
}

// ---------------- pack e_all -> bf16 hi/lo planes [NENT][KPAD] ----------------
__global__ void k_pack_e(const float* __restrict__ x, unsigned short* __restrict__ eh,
                         unsigned short* __restrict__ el) {
    long i = (long)blockIdx.x * 256 + threadIdx.x;
    if (i >= (long)NENT * KPAD) return;
    int j = (int)(i % KPAD);
    long m = i / KPAD;
    unsigned short hi = 0, lo = 0;
    if (j < DIM) split_bf16(x[m * DIM + j], hi, lo);
    eh[i] = hi; el[i] = lo;
}

// ---------------- pack fcw [200][25600] -> hi/lo planes [208][FCK2] -----------
__global__ void k_pack_fcw(const float* __restrict__ w, unsigned short* __restrict__ wh,
                           unsigned short* __restrict__ wl) {
    long i = (long)blockIdx.x * 256 + threadIdx.x;
    if (i >= (long)208 * FCK2) return;
    int k = (int)(i % FCK2);
    int n = (int)(i / FCK2);
    unsigned short hi = 0, lo = 0;
    if (k < FCK && n < DIM) split_bf16(w[(long)n * FCK + k], hi, lo);
    wh[i] = hi; wl[i] = lo;
}

// ---------------- layer GEMM: planes A[M][kpad] x planes B[208][kpad] -> C fp32
// grid (M/64); block 256 thr = 4 waves, wave = 16-row m-tile, 13 n-tiles.
__global__ __launch_bounds__(256) void k_gemm_mfma(
        const unsigned short* __restrict__ Ah, const unsigned short* __restrict__ Al,
        const unsigned short* __restrict__ Bh, const unsigned short* __restrict__ Bl,
        float* __restrict__ C, int kpad) {
    int w = threadIdx.x >> 6, l = threadIdx.x & 63;
    long m0 = (long)blockIdx.x * 64 + w * 16;
    long arow = m0 + (l & 15);
    int kg = (l >> 4) * 8;
    const unsigned short* ahp = Ah + arow * kpad + kg;
    const unsigned short* alp = Al + arow * kpad + kg;
    f32x4 acc[13];
    #pragma unroll
    for (int i = 0; i < 13; i++) acc[i] = (f32x4){0.f, 0.f, 0.f, 0.f};
    for (int kb = 0; kb < kpad; kb += 32) {
        bf16x8 a_h = *(const bf16x8*)(ahp + kb);
        bf16x8 a_l = *(const bf16x8*)(alp + kb);
        #pragma unroll
        for (int nt = 0; nt < 13; nt++) {
            long boff = (long)(nt * 16 + (l & 15)) * kpad + kb + kg;
            bf16x8 b_h = *(const bf16x8*)(Bh + boff);
            bf16x8 b_l = *(const bf16x8*)(Bl + boff);
            acc[nt] = __builtin_amdgcn_mfma_f32_16x16x32_bf16(a_h, b_h, acc[nt], 0, 0, 0);
            acc[nt] = __builtin_amdgcn_mfma_f32_16x16x32_bf16(a_h, b_l, acc[nt], 0, 0, 0);
            acc[nt] = __builtin_amdgcn_mfma_f32_16x16x32_bf16(a_l, b_h, acc[nt], 0, 0, 0);
        }
    }
    long rowo = m0 + (l >> 4) * 4;
    #pragma unroll
    for (int nt = 0; nt < 13; nt++) {
        int col = nt * 16 + (l & 15);
        if (col < DIM) {
            #pragma unroll
            for (int rr = 0; rr < 4; rr++)
                C[(rowo + rr) * DIM + col] = acc[nt][rr];
        }
    }
}

// ---------------- fused conv1d+bn1+relu+FC: hq -> fcpart partials -------------
// grid (CSPLIT, BQ/32). block: 32 query rows, 256 thr = 4 waves.
// per channel: conv slice [32][200] -> LDS bf16 hi/lo, then MFMA vs fcw slice.
__global__ __launch_bounds__(256) void k_convfc(
        const float* __restrict__ hq, const float* __restrict__ convw,
        const float* __restrict__ convb, const float* __restrict__ bn1,
        const unsigned short* __restrict__ Bh, const unsigned short* __restrict__ Bl,
        float* __restrict__ part) {
    __shared__ unsigned short AhS[32][232];
    __shared__ unsigned short AlS[32][232];
    __shared__ float cwl[CPG][12];
    int g = blockIdx.x;
    int rowbase = blockIdx.y * 32;
    int t = threadIdx.x;
    if (t < CPG * 10) {
        int c = t / 10, k = t % 10;
        cwl[c][k] = convw[(g * CPG + c) * 10 + k];
    }
    if (t < CPG) {
        int c = g * CPG + t;
        float gm = bn1[c], be = bn1[CCH + c], m = bn1[2 * CCH + c], v = bn1[3 * CCH + c];
        float s = gm * rsqrtf(v + EPSB);
        cwl[t][10] = s;
        cwl[t][11] = be - m * s + s * convb[c];
    }
    // zero the k-pad tail [200,232)
    for (int i = t; i < 32 * 32; i += 256) {
        int r = i >> 5, k = 200 + (i & 31);
        AhS[r][k] = 0; AlS[r][k] = 0;
    }
    // conv window into registers: row r = t>>3, p-chunk q = t&7 (25 wide + halo)
    int r = t >> 3, q = t & 7, p0 = q * 25;
    long brow = rowbase + r;
    float w0[29], w1[29];
    #pragma unroll
    for (int j = 0; j < 29; j++) {
        int p = p0 - 2 + j;
        bool ok = (p >= 0 && p < DIM);
        w0[j] = ok ? hq[brow * 400 + p] : 0.f;
        w1[j] = ok ? hq[brow * 400 + DIM + p] : 0.f;
    }
    __syncthreads();
    int w = t >> 6, l = t & 63;
    int mt = w >> 1;
    int half = w & 1;
    int nt0 = half ? 7 : 0;
    f32x4 acc[7];
    #pragma unroll
    for (int i = 0; i < 7; i++) acc[i] = (f32x4){0.f, 0.f, 0.f, 0.f};
    int arow_l = mt * 16 + (l & 15);
    int kg = (l >> 4) * 8;
    for (int cc = 0; cc < CPG; ++cc) {
        int c = g * CPG + cc;
        float cw[10];
        #pragma unroll
        for (int k = 0; k < 10; k++) cw[k] = cwl[cc][k];
        float sc_ = cwl[cc][10], sh_ = cwl[cc][11];
        #pragma unroll
        for (int e = 0; e < 25; e++) {
            float s = 0.f;
            #pragma unroll
            for (int k = 0; k < 5; k++) s += w0[e + k] * cw[k] + w1[e + k] * cw[5 + k];
            float val = fmaxf(sc_ * s + sh_, 0.f);
            unsigned short hi, lo;
            split_bf16(val, hi, lo);
            AhS[r][p0 + e] = hi;
            AlS[r][p0 + e] = lo;
        }
        __syncthreads();
        const unsigned short* ahp = &AhS[arow_l][kg];
        const unsigned short* alp = &AlS[arow_l][kg];
        #pragma unroll
        for (int kb = 0; kb < KPAD; kb += 32) {
            bf16x8 a_h = *(const bf16x8*)(ahp + kb);
            bf16x8 a_l = *(const bf16x8*)(alp + kb);
            #pragma unroll
            for (int j = 0; j < 7; j++) {
                if (!(half && j == 6)) {
                    int nt = nt0 + j;
                    long boff = (long)(nt * 16 + (l & 15)) * FCK2 + c * DIM + kb + kg;
                    bf16x8 b_h = *(const bf16x8*)(Bh + boff);
                    bf16x8 b_l = *(const bf16x8*)(Bl + boff);
                    acc[j] = __builtin_amdgcn_mfma_f32_16x16x32_bf16(a_h, b_h, acc[j], 0, 0, 0);
                    acc[j] = __builtin_amdgcn_mfma_f32_16x16x32_bf16(a_h, b_l, acc[j], 0, 0, 0);
                    acc[j] = __builtin_amdgcn_mfma_f32_16x16x32_bf16(a_l, b_h, acc[j], 0, 0, 0);
                }
            }
        }
        __syncthreads();
    }
    long rowo = rowbase + mt * 16 + (l >> 4) * 4;
    #pragma unroll
    for (int j = 0; j < 7; j++) {
        if (!(half && j == 6)) {
            int col = (nt0 + j) * 16 + (l & 15);
            if (col < DIM) {
                #pragma unroll
                for (int rr = 0; rr < 4; rr++)
                    part[((long)g * BQ + rowo + rr) * DIM + col] = acc[j][rr];
            }
        }
    }
}

// ---------------- reduce partials + fc bias + bn2 + relu -> h3 bf16 planes ----
__global__ void k_fcreduce(const float* __restrict__ fcpart, const float* __restrict__ fcb,
                           const float* __restrict__ bn2, unsigned short* __restrict__ h3h,
                           unsigned short* __restrict__ h3l) {
    int i = blockIdx.x * 256 + threadIdx.x;
    if (i >= BQ * KPAD) return;
    int j = i % KPAD, b = i / KPAD;
    unsigned short hi = 0, lo = 0;
    if (j < DIM) {
        float s = 0.f;
        #pragma unroll
        for (int ks = 0; ks < CSPLIT; ks++) s += fcpart[((long)ks * BQ + b) * DIM + j];
        s += fcb[j];
        float g = bn2[j], be = bn2[DIM + j], m = bn2[2 * DIM + j], v = bn2[3 * DIM + j];
        s = g * (s - m) * rsqrtf(v + EPSB) + be;
        s = fmaxf(s, 0.f);
        split_bf16(s, hi, lo);
    }
    h3h[i] = hi; h3l[i] = lo;
}

// ---------------- final: sigmoid(h3 @ e_all^T), MFMA hi/lo split -------------
__global__ __launch_bounds__(256) void k_mfma_final(
        const unsigned short* __restrict__ Ahi, const unsigned short* __restrict__ Alo,
        const unsigned short* __restrict__ Bhi, const unsigned short* __restrict__ Blo,
        float* __restrict__ out) {
    int w = threadIdx.x >> 6, l = threadIdx.x & 63;
    int n0 = blockIdx.x * 64;
    int m0 = blockIdx.y * 128 + w * 32;
    int arow = m0 + (l & 15);
    int brow = n0 + (l & 15);
    int kb = (l >> 4) * 8;
    const unsigned short* a0h = Ahi + (long)arow * KPAD + kb;
    const unsigned short* a0l = Alo + (long)arow * KPAD + kb;
    const unsigned short* bph = Bhi + (long)brow * KPAD + kb;
    const unsigned short* bpl = Blo + (long)brow * KPAD + kb;
    f32x4 acc[2][4];
    #pragma unroll
    for (int i = 0; i < 2; i++)
        #pragma unroll
        for (int j = 0; j < 4; j++) acc[i][j] = (f32x4){0.f, 0.f, 0.f, 0.f};
    for (int kt = 0; kt < 7; kt++) {
        int ko = kt * 32;
        bf16x8 ah0 = *(const bf16x8*)(a0h + ko);
        bf16x8 al0 = *(const bf16x8*)(a0l + ko);
        bf16x8 ah1 = *(const bf16x8*)(a0h + 16 * KPAD + ko);
        bf16x8 al1 = *(const bf16x8*)(a0l + 16 * KPAD + ko);
        #pragma unroll
        for (int nt = 0; nt < 4; nt++) {
            bf16x8 bh = *(const bf16x8*)(bph + (long)nt * 16 * KPAD + ko);
            bf16x8 bl = *(const bf16x8*)(bpl + (long)nt * 16 * KPAD + ko);
            acc[0][nt] = __builtin_amdgcn_mfma_f32_16x16x32_bf16(ah0, bh, acc[0][nt], 0, 0, 0);
            acc[0][nt] = __builtin_amdgcn_mfma_f32_16x16x32_bf16(ah0, bl, acc[0][nt], 0, 0, 0);
            acc[0][nt] = __builtin_amdgcn_mfma_f32_16x16x32_bf16(al0, bh, acc[0][nt], 0, 0, 0);
            acc[1][nt] = __builtin_amdgcn_mfma_f32_16x16x32_bf16(ah1, bh, acc[1][nt], 0, 0, 0);
            acc[1][nt] = __builtin_amdgcn_mfma_f32_16x16x32_bf16(ah1, bl, acc[1][nt], 0, 0, 0);
            acc[1][nt] = __builtin_amdgcn_mfma_f32_16x16x32_bf16(al1, bh, acc[1][nt], 0, 0, 0);
        }
    }
    int colb = n0 + (l & 15);
    int rowb = m0 + (l >> 4) * 4;
    #pragma unroll
    for (int mt = 0; mt < 2; mt++)
        #pragma unroll
        for (int r = 0; r < 4; r++) {
            long row = rowb + mt * 16 + r;
            #pragma unroll
            for (int nt = 0; nt < 4; nt++) {
                float v = acc[mt][nt][r];
                out[row * NENT + colb + nt * 16] = 1.f / (1.f + __expf(-v));
            }
        }
}

extern "C" void kernel_launch(void* const* d_in, const int* in_sizes, int n_in,
                              void* d_out, int out_size, void* d_ws, size_t ws_size,
                              hipStream_t stream) {
    (void)in_sizes; (void)n_in; (void)out_size; (void)ws_size;
    const int* src      = (const int*)d_in[0];
    const int* dst      = (const int*)d_in[1];
    const int* aet      = (const int*)d_in[2];
    const int* e1       = (const int*)d_in[3];
    const int* rel      = (const int*)d_in[4];
    const int* entity   = (const int*)d_in[5];
    const float* emb_e  = (const float*)d_in[6];
    const float* embrel = (const float*)d_in[7];
    const float* w2     = (const float*)d_in[8];
    const float* b2     = (const float*)d_in[9];
    const float* alpha2 = (const float*)d_in[10];
    const float* w3     = (const float*)d_in[11];
    const float* b3     = (const float*)d_in[12];
    const float* alpha3 = (const float*)d_in[13];
    const float* bn3    = (const float*)d_in[14];
    const float* bn4    = (const float*)d_in[15];
    const float* bn0    = (const float*)d_in[16];
    const float* bn1    = (const float*)d_in[17];
    const float* bn2    = (const float*)d_in[18];
    const float* convw  = (const float*)d_in[19];
    const float* convb  = (const float*)d_in[20];
    const float* fcw    = (const float*)d_in[21];
    const float* fcb    = (const float*)d_in[22];
    float* out = (float*)d_out;
    float* ws = (float*)d_ws;

    // ---- workspace layout (float offsets), with lifetime-based reuse ----
    float* feats = ws;                         // 0 .. 8.00M   (gemm out, agg src; dead after agg2)
    float* acc   = ws + 8000000;               // 8M .. 16M    (agg1 dst; dead after bntanh1)
    unsigned short* e_hi = (unsigned short*)ws;              // overlays feats (written at pack_e)
    unsigned short* e_lo = (unsigned short*)(ws + 8000000);  // overlays acc
    unsigned short* a1_h = (unsigned short*)(ws + 16000000); // 2.56M f (dead after gemm1)
    unsigned short* a1_l = (unsigned short*)(ws + 18560000); // 2.56M f
    unsigned short* a2_h = (unsigned short*)(ws + 16000000); // 4.48M f (written after a1 dead)
    unsigned short* a2_l = (unsigned short*)(ws + 20480000); // 4.48M f -> ends 24.96M
    unsigned short* fcw_h = (unsigned short*)(ws + 16000000); // 2.666M f (written after a2 dead)
    unsigned short* fcw_l = (unsigned short*)(ws + 18670000); // 2.666M f -> ends 21.34M
    float* xbuf  = ws + 25000000;              // 25M .. 33M   (e_all fp32)
    float* alp1  = ws + 33000000;              // 0.54M
    float* alp2  = ws + 33540000;              // 0.54M -> 34.08M
    unsigned short* w2t_h = (unsigned short*)(ws + 34100000); // 208*128 shorts
    unsigned short* w2t_l = (unsigned short*)(ws + 34120000);
    unsigned short* w3t_h = (unsigned short*)(ws + 34140000); // 208*224 shorts
    unsigned short* w3t_l = (unsigned short*)(ws + 34170000); // -> 34.20M
    float* hq    = ws + 34200000;              // 0.8192M -> 35.02M
    float* fcpart = ws + 35100000;             // 6.5536M -> 41.66M
    unsigned short* h3_h = (unsigned short*)(ws + 41700000);  // 2048*224 shorts
    unsigned short* h3_l = (unsigned short*)(ws + 41930000);  // -> 42.16M floats total

    hipMemsetAsync(acc, 0, (size_t)8000000 * 4, stream);
    hipMemsetAsync(xbuf, 0, (size_t)8000000 * 4, stream);

    k_alp<<<(NE + 255) / 256, 256, 0, stream>>>(aet, alpha2, alpha3, alp1, alp2);

    // pack A1 (emb_e gathered) and layer weights
    k_pack_A1<<<(NENT * 128) / 256, 256, 0, stream>>>(emb_e, entity, a1_h, a1_l);
    k_pack_B<<<(208 * 128 + 255) / 256, 256, 0, stream>>>(w2, w2t_h, w2t_l, DIM0, 128);
    k_pack_B<<<(208 * KPAD + 255) / 256, 256, 0, stream>>>(w3, w3t_h, w3t_l, DIM, KPAD);

    // GCN layer 1: feats = emb_e[entity] @ w2
    k_gemm_mfma<<<NENT / 64, 256, 0, stream>>>(a1_h, a1_l, w2t_h, w2t_l, feats, 128);
    k_agg<<<2048, 256, 0, stream>>>(src, dst, alp1, feats, acc);
    k_bntanh_pack<<<(NENT * KPAD + 255) / 256, 256, 0, stream>>>(acc, b2, bn3, a2_h, a2_l);

    // GCN layer 2: feats = x1 @ w3
    k_gemm_mfma<<<NENT / 64, 256, 0, stream>>>(a2_h, a2_l, w3t_h, w3t_l, feats, KPAD);
    k_agg<<<2048, 256, 0, stream>>>(src, dst, alp2, feats, xbuf);
    k_bntanh<<<(NENT * DIM + 255) / 256, 256, 0, stream>>>(xbuf, b3, bn4);

    // decoder input (bn0 applied)
    k_hq<<<(BQ * 2 * DIM + 255) / 256, 256, 0, stream>>>(e1, rel, xbuf, embrel, bn0, hq);

    // pack e_all (into regions freed by feats/acc) and fcw
    k_pack_e<<<(NENT * KPAD + 255) / 256, 256, 0, stream>>>(xbuf, e_hi, e_lo);
    k_pack_fcw<<<(int)(((long)208 * FCK2 + 255) / 256), 256, 0, stream>>>(fcw, fcw_h, fcw_l);

    // fused conv + fc -> channel-group partials
    k_convfc<<<dim3(CSPLIT, BQ / 32), 256, 0, stream>>>(hq, convw, convb, bn1,
                                                        fcw_h, fcw_l, fcpart);
    k_fcreduce<<<(BQ * KPAD + 255) / 256, 256, 0, stream>>>(fcpart, fcb, bn2, h3_h, h3_l);

    // final: sigmoid(h3 @ e_all^T)
    k_mfma_final<<<dim3(NENT / 64, BQ / 128), 256, 0, stream>>>(h3_h, h3_l, e_hi, e_lo, out);
}

// Round 5
// 1215.983 us; speedup vs baseline: 3.7386x; 1.4908x over previous
//
#include <hip/hip_runtime.h>
#include <math.h>

#define NENT 40000
#define NTE  250000
#define NE   540000      // 2*NTE + NENT
#define DIM0 100
#define DIM  200
#define CCH  128
#define BQ   2048
#define FCK  25600       // CCH*DIM
#define EPSB 1e-5f
#define KPAD 224         // 200 padded to 7*32
#define NSPLIT 32        // split-K for FC
#define KSEG 800         // FCK / NSPLIT
#define QCH  512         // query rows per conv/fc chunk

typedef short bf16x8 __attribute__((ext_vector_type(8)));
typedef float f32x4 __attribute__((ext_vector_type(4)));

__device__ __forceinline__ void split_bf16(float x, unsigned short& hi, unsigned short& lo) {
    unsigned u = __float_as_uint(x);
    unsigned r = (u + 0x7fffu + ((u >> 16) & 1u)) >> 16;
    hi = (unsigned short)r;
    float rem = x - __uint_as_float(r << 16);
    unsigned u2 = __float_as_uint(rem);
    unsigned r2 = (u2 + 0x7fffu + ((u2 >> 16) & 1u)) >> 16;
    lo = (unsigned short)r2;
}

#if defined(__has_builtin)
#if __has_builtin(__builtin_amdgcn_global_load_lds)
#define HAVE_GLL 1
#endif
#endif

__device__ __forceinline__ void gload_lds16(const void* g, void* l) {
#ifdef HAVE_GLL
    __builtin_amdgcn_global_load_lds((const __attribute__((address_space(1))) unsigned int*)g,
                                     (__attribute__((address_space(3))) unsigned int*)l, 16, 0, 0);
#else
    *(uint4*)l = *(const uint4*)g;
#endif
}

// =================== CSR build ===================
__global__ void k_hist(const int* __restrict__ dst, int* __restrict__ deg) {
    int e = blockIdx.x * 256 + threadIdx.x;
    if (e < NE) atomicAdd(&deg[dst[e]], 1);
}

__global__ __launch_bounds__(1024) void k_scan(const int* __restrict__ deg,
        int* __restrict__ rowptr, int* __restrict__ cursor) {
    __shared__ int sh[1024];
    __shared__ int carry_s;
    int t = threadIdx.x;
    if (t == 0) { carry_s = 0; rowptr[0] = 0; }
    __syncthreads();
    for (int c = 0; c < 40; c++) {
        int idx = c * 1024 + t;
        int v = (idx < NENT) ? deg[idx] : 0;
        sh[t] = v;
        __syncthreads();
        #pragma unroll
        for (int off = 1; off < 1024; off <<= 1) {
            int add = (t >= off) ? sh[t - off] : 0;
            __syncthreads();
            sh[t] += add;
            __syncthreads();
        }
        int incl = sh[t];
        int base = carry_s;
        __syncthreads();
        if (idx < NENT) {
            rowptr[idx + 1] = base + incl;
            cursor[idx] = base + incl - v;
        }
        if (t == 1023) carry_s = base + incl;
        __syncthreads();
    }
}

__global__ void k_scatter(const int* __restrict__ src, const int* __restrict__ dst,
                          const int* __restrict__ aet, const float* __restrict__ a2t,
                          const float* __restrict__ a3t, int* __restrict__ cursor,
                          int* __restrict__ ssrc, float* __restrict__ sa1,
                          float* __restrict__ sa2) {
    int e = blockIdx.x * 256 + threadIdx.x;
    if (e >= NE) return;
    int tt = (e < NTE) ? e + NTE : (e < 2 * NTE ? e - NTE : e);
    int t0 = aet[e], t1 = aet[tt];
    int pos = atomicAdd(&cursor[dst[e]], 1);
    ssrc[pos] = src[e];
    sa1[pos] = a2t[t0] + a2t[t1];
    sa2[pos] = a3t[t0] + a3t[t1];
}

// =================== CSR aggregation: one wave per dst row ===================
__global__ __launch_bounds__(256) void k_agg_csr(const int* __restrict__ rowptr,
        const int* __restrict__ ssrc, const float* __restrict__ sa,
        const float* __restrict__ feats, float* __restrict__ outb) {
    int w = threadIdx.x >> 6, l = threadIdx.x & 63;
    int row = blockIdx.x * 4 + w;
    int beg = rowptr[row], end = rowptr[row + 1];
    float s0 = 0.f, s1 = 0.f, s2 = 0.f, s3 = 0.f;
    for (int i = beg; i < end; i++) {
        int sidx = ssrc[i];
        float a = sa[i];
        const float* f = feats + (long)sidx * DIM;
        s0 += a * f[l];
        s1 += a * f[l + 64];
        s2 += a * f[l + 128];
        if (l < 8) s3 += a * f[l + 192];
    }
    float* o = outb + (long)row * DIM;
    o[l] = s0; o[l + 64] = s1; o[l + 128] = s2;
    if (l < 8) o[l + 192] = s3;
}

// =================== packing kernels ===================
__global__ void k_bntanh(float* __restrict__ x, const float* __restrict__ bias,
                         const float* __restrict__ bn) {
    long i = (long)blockIdx.x * blockDim.x + threadIdx.x;
    if (i >= (long)NENT * DIM) return;
    int j = (int)(i % DIM);
    float g = bn[j], be = bn[DIM + j], m = bn[2 * DIM + j], v = bn[3 * DIM + j];
    float val = x[i] + bias[j];
    val = g * (val - m) * rsqrtf(v + EPSB) + be;
    x[i] = tanhf(val);
}

__global__ void k_bntanh_pack(const float* __restrict__ x, const float* __restrict__ bias,
                              const float* __restrict__ bn, unsigned short* __restrict__ oh,
                              unsigned short* __restrict__ ol) {
    long i = (long)blockIdx.x * 256 + threadIdx.x;
    if (i >= (long)NENT * KPAD) return;
    int j = (int)(i % KPAD);
    long row = i / KPAD;
    unsigned short hi = 0, lo = 0;
    if (j < DIM) {
        float g = bn[j], be = bn[DIM + j], m = bn[2 * DIM + j], v = bn[3 * DIM + j];
        float val = x[row * DIM + j] + bias[j];
        val = g * (val - m) * rsqrtf(v + EPSB) + be;
        val = tanhf(val);
        split_bf16(val, hi, lo);
    }
    oh[i] = hi; ol[i] = lo;
}

__global__ void k_pack_A1(const float* __restrict__ emb, const int* __restrict__ ent,
                          unsigned short* __restrict__ ah, unsigned short* __restrict__ al) {
    long i = (long)blockIdx.x * 256 + threadIdx.x;
    if (i >= (long)NENT * 128) return;
    int k = (int)(i & 127);
    long m = i >> 7;
    unsigned short hi = 0, lo = 0;
    if (k < DIM0) split_bf16(emb[(long)ent[m] * DIM0 + k], hi, lo);
    ah[i] = hi; al[i] = lo;
}

__global__ void k_pack_B(const float* __restrict__ w, unsigned short* __restrict__ bh,
                         unsigned short* __restrict__ bl, int kin, int kpad) {
    int i = blockIdx.x * 256 + threadIdx.x;
    if (i >= 208 * kpad) return;
    int k = i % kpad, n = i / kpad;
    unsigned short hi = 0, lo = 0;
    if (k < kin && n < DIM) split_bf16(w[(long)k * DIM + n], hi, lo);
    bh[i] = hi; bl[i] = lo;
}

__global__ void k_hq(const int* __restrict__ e1, const int* __restrict__ rel,
                     const float* __restrict__ eall, const float* __restrict__ embrel,
                     const float* __restrict__ bn0, float* __restrict__ hq) {
    int i = blockIdx.x * 256 + threadIdx.x;
    if (i >= BQ * 2 * DIM) return;
    int d = i % DIM, c = (i / DIM) & 1, b = i / (2 * DIM);
    float val = (c == 0) ? eall[(long)e1[b] * DIM + d]
                         : embrel[(long)rel[b] * DIM + d];
    float g = bn0[c], be = bn0[2 + c], m = bn0[4 + c], v = bn0[6 + c];
    hq[i] = g * (val - m) * rsqrtf(v + EPSB) + be;
}

__global__ void k_pack_e(const float* __restrict__ x, unsigned short* __restrict__ eh,
                         unsigned short* __restrict__ el) {
    long i = (long)blockIdx.x * 256 + threadIdx.x;
    if (i >= (long)NENT * KPAD) return;
    int j = (int)(i % KPAD);
    long m = i / KPAD;
    unsigned short hi = 0, lo = 0;
    if (j < DIM) split_bf16(x[m * DIM + j], hi, lo);
    eh[i] = hi; el[i] = lo;
}

__global__ void k_pack_fcw(const float* __restrict__ w, unsigned short* __restrict__ wh,
                           unsigned short* __restrict__ wl) {
    long i = (long)blockIdx.x * 256 + threadIdx.x;
    if (i >= (long)208 * FCK) return;
    int k = (int)(i % FCK);
    int n = (int)(i / FCK);
    unsigned short hi = 0, lo = 0;
    if (n < DIM) split_bf16(w[(long)n * FCK + k], hi, lo);
    wh[i] = hi; wl[i] = lo;
}

// =================== layer GEMM (direct-B, small K) ===================
__global__ __launch_bounds__(256) void k_gemm_mfma(
        const unsigned short* __restrict__ Ah, const unsigned short* __restrict__ Al,
        const unsigned short* __restrict__ Bh, const unsigned short* __restrict__ Bl,
        float* __restrict__ C, int kpad) {
    int w = threadIdx.x >> 6, l = threadIdx.x & 63;
    long m0 = (long)blockIdx.x * 64 + w * 16;
    long arow = m0 + (l & 15);
    int kg = (l >> 4) * 8;
    const unsigned short* ahp = Ah + arow * kpad + kg;
    const unsigned short* alp = Al + arow * kpad + kg;
    f32x4 acc[13];
    #pragma unroll
    for (int i = 0; i < 13; i++) acc[i] = (f32x4){0.f, 0.f, 0.f, 0.f};
    for (int kb = 0; kb < kpad; kb += 32) {
        bf16x8 a_h = *(const bf16x8*)(ahp + kb);
        bf16x8 a_l = *(const bf16x8*)(alp + kb);
        #pragma unroll
        for (int nt = 0; nt < 13; nt++) {
            long boff = (long)(nt * 16 + (l & 15)) * kpad + kb + kg;
            bf16x8 b_h = *(const bf16x8*)(Bh + boff);
            bf16x8 b_l = *(const bf16x8*)(Bl + boff);
            acc[nt] = __builtin_amdgcn_mfma_f32_16x16x32_bf16(a_h, b_h, acc[nt], 0, 0, 0);
            acc[nt] = __builtin_amdgcn_mfma_f32_16x16x32_bf16(a_h, b_l, acc[nt], 0, 0, 0);
            acc[nt] = __builtin_amdgcn_mfma_f32_16x16x32_bf16(a_l, b_h, acc[nt], 0, 0, 0);
        }
    }
    long rowo = m0 + (l >> 4) * 4;
    #pragma unroll
    for (int nt = 0; nt < 13; nt++) {
        int col = nt * 16 + (l & 15);
        if (col < DIM) {
            #pragma unroll
            for (int rr = 0; rr < 4; rr++)
                C[(rowo + rr) * DIM + col] = acc[nt][rr];
        }
    }
}

// =================== conv1d + bn1 + relu -> hconv bf16 planes (chunk) =========
__global__ __launch_bounds__(256) void k_conv2(const float* __restrict__ hq,
        const float* __restrict__ convw, const float* __restrict__ convb,
        const float* __restrict__ bn1, unsigned short* __restrict__ hch,
        unsigned short* __restrict__ hcl, int rowoff) {
    __shared__ float hql[400];
    __shared__ float cwl[1280];
    __shared__ float scs[128], shs[128];
    int bl = blockIdx.x;
    int t = threadIdx.x;
    long b = rowoff + bl;
    for (int i = t; i < 400; i += 256) hql[i] = hq[b * 400 + i];
    for (int i = t; i < 1280; i += 256) cwl[i] = convw[i];
    if (t < 128) {
        float g = bn1[t], be = bn1[CCH + t], m = bn1[2 * CCH + t], v = bn1[3 * CCH + t];
        float s = g * rsqrtf(v + EPSB);
        scs[t] = s;
        shs[t] = be - m * s + s * convb[t];
    }
    __syncthreads();
    int c = t >> 1, half = t & 1, p0 = half * 100;
    float cw[10];
    #pragma unroll
    for (int k = 0; k < 10; k++) cw[k] = cwl[c * 10 + k];
    float sc_ = scs[c], sh_ = shs[c];
    long obase = (long)bl * FCK + c * DIM + p0;
    for (int pc = 0; pc < 100; pc += 4) {
        float w0[8], w1[8];
        #pragma unroll
        for (int j = 0; j < 8; j++) {
            int pp = p0 + pc - 2 + j;
            bool ok = (pp >= 0 && pp < DIM);
            w0[j] = ok ? hql[pp] : 0.f;
            w1[j] = ok ? hql[DIM + pp] : 0.f;
        }
        unsigned short h4[4], l4[4];
        #pragma unroll
        for (int j = 0; j < 4; j++) {
            float s = 0.f;
            #pragma unroll
            for (int k = 0; k < 5; k++) s += w0[j + k] * cw[k] + w1[j + k] * cw[5 + k];
            float val = fmaxf(sc_ * s + sh_, 0.f);
            split_bf16(val, h4[j], l4[j]);
        }
        *(ushort4*)&hch[obase + pc] = make_ushort4(h4[0], h4[1], h4[2], h4[3]);
        *(ushort4*)&hcl[obase + pc] = make_ushort4(l4[0], l4[1], l4[2], l4[3]);
    }
}

// =================== FC GEMM: LDS-staged B, split-K, atomic accumulate ========
// grid (NSPLIT, QCH/64). A = hc chunk [QCH][FCK] planes; B = fcw planes [208][FCK].
__global__ __launch_bounds__(256) void k_fc2(
        const unsigned short* __restrict__ Ah, const unsigned short* __restrict__ Al,
        const unsigned short* __restrict__ Bh, const unsigned short* __restrict__ Bl,
        float* __restrict__ fcsum, int rowoff) {
    __shared__ __align__(16) unsigned short ldsB[2][13312];  // [buf][plane(6656) x2]
    int split = blockIdx.x, mb = blockIdx.y;
    int t = threadIdx.x;
    int w = t >> 6, l = t & 63;
    int kbase = split * KSEG;
    long arow = mb * 64 + w * 16 + (l & 15);
    int kg = (l >> 4) * 8;
    const unsigned short* ahp = Ah + arow * FCK + kbase + kg;
    const unsigned short* alp = Al + arow * FCK + kbase + kg;

    // stage k-step 0 into buf 0
    #pragma unroll
    for (int i = 0; i < 7; i++) {
        int u = i * 256 + t;
        if (u < 1664) {
            int pl = (u >= 832) ? 1 : 0;
            int s2 = u - pl * 832;
            int r = s2 >> 2, kc = s2 & 3;
            const unsigned short* g = (pl ? Bl : Bh) + (long)r * FCK + kbase + kc * 8;
            gload_lds16(g, &ldsB[0][u * 8]);
        }
    }
    bf16x8 aNh = *(const bf16x8*)(ahp);
    bf16x8 aNl = *(const bf16x8*)(alp);

    f32x4 acc[13];
    #pragma unroll
    for (int i = 0; i < 13; i++) acc[i] = (f32x4){0.f, 0.f, 0.f, 0.f};

    int buf = 0;
    for (int ks = 0; ks < 25; ks++) {
        __syncthreads();   // drains staged loads; readers of other buf done
        if (ks + 1 < 25) {
            int knext = kbase + (ks + 1) * 32;
            #pragma unroll
            for (int i = 0; i < 7; i++) {
                int u = i * 256 + t;
                if (u < 1664) {
                    int pl = (u >= 832) ? 1 : 0;
                    int s2 = u - pl * 832;
                    int r = s2 >> 2, kc = s2 & 3;
                    const unsigned short* g = (pl ? Bl : Bh) + (long)r * FCK + knext + kc * 8;
                    gload_lds16(g, &ldsB[buf ^ 1][u * 8]);
                }
            }
        }
        bf16x8 aCh = aNh, aCl = aNl;
        if (ks + 1 < 25) {
            aNh = *(const bf16x8*)(ahp + (ks + 1) * 32);
            aNl = *(const bf16x8*)(alp + (ks + 1) * 32);
        }
        const unsigned short* bh_base = &ldsB[buf][(l & 15) * 32 + kg];
        const unsigned short* bl_base = bh_base + 6656;
        #pragma unroll
        for (int nt = 0; nt < 13; nt++) {
            bf16x8 b_h = *(const bf16x8*)(bh_base + nt * 512);
            bf16x8 b_l = *(const bf16x8*)(bl_base + nt * 512);
            acc[nt] = __builtin_amdgcn_mfma_f32_16x16x32_bf16(aCh, b_h, acc[nt], 0, 0, 0);
            acc[nt] = __builtin_amdgcn_mfma_f32_16x16x32_bf16(aCh, b_l, acc[nt], 0, 0, 0);
            acc[nt] = __builtin_amdgcn_mfma_f32_16x16x32_bf16(aCl, b_h, acc[nt], 0, 0, 0);
        }
        buf ^= 1;
    }
    long rowo = rowoff + mb * 64 + w * 16 + (l >> 4) * 4;
    #pragma unroll
    for (int nt = 0; nt < 13; nt++) {
        int col = nt * 16 + (l & 15);
        if (col < DIM) {
            #pragma unroll
            for (int rr = 0; rr < 4; rr++)
                unsafeAtomicAdd(&fcsum[(rowo + rr) * DIM + col], acc[nt][rr]);
        }
    }
}

// =================== fcsum + bias + bn2 + relu -> h3 planes ===================
__global__ void k_fcreduce(const float* __restrict__ fcsum, const float* __restrict__ fcb,
                           const float* __restrict__ bn2, unsigned short* __restrict__ h3h,
                           unsigned short* __restrict__ h3l) {
    int i = blockIdx.x * 256 + threadIdx.x;
    if (i >= BQ * KPAD) return;
    int j = i % KPAD, b = i / KPAD;
    unsigned short hi = 0, lo = 0;
    if (j < DIM) {
        float s = fcsum[(long)b * DIM + j] + fcb[j];
        float g = bn2[j], be = bn2[DIM + j], m = bn2[2 * DIM + j], v = bn2[3 * DIM + j];
        s = g * (s - m) * rsqrtf(v + EPSB) + be;
        s = fmaxf(s, 0.f);
        split_bf16(s, hi, lo);
    }
    h3h[i] = hi; h3l[i] = lo;
}

// =================== final: sigmoid(h3 @ e_all^T) ===================
__global__ __launch_bounds__(256) void k_mfma_final(
        const unsigned short* __restrict__ Ahi, const unsigned short* __restrict__ Alo,
        const unsigned short* __restrict__ Bhi, const unsigned short* __restrict__ Blo,
        float* __restrict__ out) {
    int w = threadIdx.x >> 6, l = threadIdx.x & 63;
    int n0 = blockIdx.x * 64;
    int m0 = blockIdx.y * 128 + w * 32;
    int arow = m0 + (l & 15);
    int brow = n0 + (l & 15);
    int kb = (l >> 4) * 8;
    const unsigned short* a0h = Ahi + (long)arow * KPAD + kb;
    const unsigned short* a0l = Alo + (long)arow * KPAD + kb;
    const unsigned short* bph = Bhi + (long)brow * KPAD + kb;
    const unsigned short* bpl = Blo + (long)brow * KPAD + kb;
    f32x4 acc[2][4];
    #pragma unroll
    for (int i = 0; i < 2; i++)
        #pragma unroll
        for (int j = 0; j < 4; j++) acc[i][j] = (f32x4){0.f, 0.f, 0.f, 0.f};
    for (int kt = 0; kt < 7; kt++) {
        int ko = kt * 32;
        bf16x8 ah0 = *(const bf16x8*)(a0h + ko);
        bf16x8 al0 = *(const bf16x8*)(a0l + ko);
        bf16x8 ah1 = *(const bf16x8*)(a0h + 16 * KPAD + ko);
        bf16x8 al1 = *(const bf16x8*)(a0l + 16 * KPAD + ko);
        #pragma unroll
        for (int nt = 0; nt < 4; nt++) {
            bf16x8 bh = *(const bf16x8*)(bph + (long)nt * 16 * KPAD + ko);
            bf16x8 bl = *(const bf16x8*)(bpl + (long)nt * 16 * KPAD + ko);
            acc[0][nt] = __builtin_amdgcn_mfma_f32_16x16x32_bf16(ah0, bh, acc[0][nt], 0, 0, 0);
            acc[0][nt] = __builtin_amdgcn_mfma_f32_16x16x32_bf16(ah0, bl, acc[0][nt], 0, 0, 0);
            acc[0][nt] = __builtin_amdgcn_mfma_f32_16x16x32_bf16(al0, bh, acc[0][nt], 0, 0, 0);
            acc[1][nt] = __builtin_amdgcn_mfma_f32_16x16x32_bf16(ah1, bh, acc[1][nt], 0, 0, 0);
            acc[1][nt] = __builtin_amdgcn_mfma_f32_16x16x32_bf16(ah1, bl, acc[1][nt], 0, 0, 0);
            acc[1][nt] = __builtin_amdgcn_mfma_f32_16x16x32_bf16(al1, bh, acc[1][nt], 0, 0, 0);
        }
    }
    int colb = n0 + (l & 15);
    int rowb = m0 + (l >> 4) * 4;
    #pragma unroll
    for (int mt = 0; mt < 2; mt++)
        #pragma unroll
        for (int r = 0; r < 4; r++) {
            long row = rowb + mt * 16 + r;
            #pragma unroll
            for (int nt = 0; nt < 4; nt++) {
                float v = acc[mt][nt][r];
                out[row * NENT + colb + nt * 16] = 1.f / (1.f + __expf(-v));
            }
        }
}

extern "C" void kernel_launch(void* const* d_in, const int* in_sizes, int n_in,
                              void* d_out, int out_size, void* d_ws, size_t ws_size,
                              hipStream_t stream) {
    (void)in_sizes; (void)n_in; (void)out_size; (void)ws_size;
    const int* src      = (const int*)d_in[0];
    const int* dst      = (const int*)d_in[1];
    const int* aet      = (const int*)d_in[2];
    const int* e1       = (const int*)d_in[3];
    const int* rel      = (const int*)d_in[4];
    const int* entity   = (const int*)d_in[5];
    const float* emb_e  = (const float*)d_in[6];
    const float* embrel = (const float*)d_in[7];
    const float* w2     = (const float*)d_in[8];
    const float* b2     = (const float*)d_in[9];
    const float* alpha2 = (const float*)d_in[10];
    const float* w3     = (const float*)d_in[11];
    const float* b3     = (const float*)d_in[12];
    const float* alpha3 = (const float*)d_in[13];
    const float* bn3    = (const float*)d_in[14];
    const float* bn4    = (const float*)d_in[15];
    const float* bn0    = (const float*)d_in[16];
    const float* bn1    = (const float*)d_in[17];
    const float* bn2    = (const float*)d_in[18];
    const float* convw  = (const float*)d_in[19];
    const float* convb  = (const float*)d_in[20];
    const float* fcw    = (const float*)d_in[21];
    const float* fcb    = (const float*)d_in[22];
    float* out = (float*)d_out;
    float* ws = (float*)d_ws;

    // ---- workspace layout (float offsets, lifetime-based reuse) ----
    // [0,8M)      feats (layer gemm out / agg src); later e_hi [0,4.48M)
    // [4.5M,8.98M) e_lo (after feats dead)
    // [8M,16M)    acc (agg1 dst, dead after bntanh_pack); later hc_h [9M,15.56M)
    // [16M,24M)   xbuf (e_all fp32; dead after k_hq/pack_e); later hc_l [16M,22.56M)
    // [24M,29.12M) a1 planes (dead after gemm1); later fcw planes [24M,29.35M)
    // [29.12M,38.08M) a2 planes (dead after gemm2)
    // [38.1M,39.89M) CSR: deg/rowptr/cursor/ssrc/sa1/sa2
    // [39.9M,40.31M) fcsum ; [40.35M,41.17M) hq ; [41.2M,41.67M) h3 planes
    // [41.70M,41.80M) w2t/w3t planes (NEVER overlapped — R4 bug was here)
    float* feats  = ws;
    float* acc    = ws + 8000000;
    float* xbuf   = ws + 16000000;
    unsigned short* e_hi  = (unsigned short*)ws;
    unsigned short* e_lo  = (unsigned short*)(ws + 4500000);
    unsigned short* hc_h  = (unsigned short*)(ws + 9000000);
    unsigned short* hc_l  = (unsigned short*)(ws + 16000000);
    unsigned short* a1_h  = (unsigned short*)(ws + 24000000);
    unsigned short* a1_l  = (unsigned short*)(ws + 26560000);
    unsigned short* a2_h  = (unsigned short*)(ws + 29120000);
    unsigned short* a2_l  = (unsigned short*)(ws + 33600000);
    unsigned short* fcw_h = (unsigned short*)(ws + 24000000);
    unsigned short* fcw_l = (unsigned short*)(ws + 26680000);
    int*   deg    = (int*)(ws + 38100000);
    int*   rowptr = (int*)(ws + 38150000);
    int*   cursor = (int*)(ws + 38200000);
    int*   ssrc   = (int*)(ws + 38250000);
    float* sa1    = ws + 38800000;
    float* sa2    = ws + 39350000;
    float* fcsum  = ws + 39900000;
    float* hq     = ws + 40350000;
    unsigned short* h3_h = (unsigned short*)(ws + 41200000);
    unsigned short* h3_l = (unsigned short*)(ws + 41440000);
    unsigned short* w2t_h = (unsigned short*)(ws + 41700000);  // 26624 shorts
    unsigned short* w2t_l = (unsigned short*)(ws + 41720000);
    unsigned short* w3t_h = (unsigned short*)(ws + 41740000);  // 46592 shorts
    unsigned short* w3t_l = (unsigned short*)(ws + 41770000);  // ends ~41.794M floats

    // ---- CSR build (shared by both layers) ----
    hipMemsetAsync(deg, 0, NENT * 4, stream);
    k_hist<<<(NE + 255) / 256, 256, 0, stream>>>(dst, deg);
    k_scan<<<1, 1024, 0, stream>>>(deg, rowptr, cursor);
    k_scatter<<<(NE + 255) / 256, 256, 0, stream>>>(src, dst, aet, alpha2, alpha3,
                                                    cursor, ssrc, sa1, sa2);

    // ---- pack inputs ----
    k_pack_A1<<<(NENT * 128) / 256, 256, 0, stream>>>(emb_e, entity, a1_h, a1_l);
    k_pack_B<<<(208 * 128 + 255) / 256, 256, 0, stream>>>(w2, w2t_h, w2t_l, DIM0, 128);
    k_pack_B<<<(208 * KPAD + 255) / 256, 256, 0, stream>>>(w3, w3t_h, w3t_l, DIM, KPAD);

    // ---- GCN layer 1 ----
    k_gemm_mfma<<<NENT / 64, 256, 0, stream>>>(a1_h, a1_l, w2t_h, w2t_l, feats, 128);
    k_agg_csr<<<NENT / 4, 256, 0, stream>>>(rowptr, ssrc, sa1, feats, acc);
    k_bntanh_pack<<<(NENT * KPAD + 255) / 256, 256, 0, stream>>>(acc, b2, bn3, a2_h, a2_l);

    // ---- GCN layer 2 ----
    k_gemm_mfma<<<NENT / 64, 256, 0, stream>>>(a2_h, a2_l, w3t_h, w3t_l, feats, KPAD);
    k_agg_csr<<<NENT / 4, 256, 0, stream>>>(rowptr, ssrc, sa2, feats, xbuf);
    k_bntanh<<<(NENT * DIM + 255) / 256, 256, 0, stream>>>(xbuf, b3, bn4);

    // ---- decoder input + packs ----
    k_hq<<<(BQ * 2 * DIM + 255) / 256, 256, 0, stream>>>(e1, rel, xbuf, embrel, bn0, hq);
    k_pack_e<<<(NENT * KPAD + 255) / 256, 256, 0, stream>>>(xbuf, e_hi, e_lo);
    k_pack_fcw<<<(int)(((long)208 * FCK + 255) / 256), 256, 0, stream>>>(fcw, fcw_h, fcw_l);

    // ---- conv + FC in 4 chunks of 512 rows ----
    hipMemsetAsync(fcsum, 0, (size_t)BQ * DIM * 4, stream);
    for (int ch = 0; ch < BQ / QCH; ch++) {
        int rowoff = ch * QCH;
        k_conv2<<<QCH, 256, 0, stream>>>(hq, convw, convb, bn1, hc_h, hc_l, rowoff);
        k_fc2<<<dim3(NSPLIT, QCH / 64), 256, 0, stream>>>(hc_h, hc_l, fcw_h, fcw_l,
                                                          fcsum, rowoff);
    }
    k_fcreduce<<<(BQ * KPAD + 255) / 256, 256, 0, stream>>>(fcsum, fcb, bn2, h3_h, h3_l);

    // ---- final scoring ----
    k_mfma_final<<<dim3(NENT / 64, BQ / 128), 256, 0, stream>>>(h3_h, h3_l, e_hi, e_lo, out);
}

// Round 6
// 1121.659 us; speedup vs baseline: 4.0530x; 1.0841x over previous
//
#include <hip/hip_runtime.h>
#include <math.h>

#define NENT 40000
#define NTE  250000
#define NE   540000      // 2*NTE + NENT
#define DIM0 100
#define DIM  200
#define CCH  128
#define BQ   2048
#define FCK  25600       // CCH*DIM
#define EPSB 1e-5f
#define KPAD 224         // 200 padded to 7*32
#define NSPLIT 32        // split-K for FC
#define KSEG 800         // FCK / NSPLIT
#define QCH  512         // query rows per conv/fc chunk

typedef short bf16x8 __attribute__((ext_vector_type(8)));
typedef float f32x4 __attribute__((ext_vector_type(4)));

__device__ __forceinline__ void split_bf16(float x, unsigned short& hi, unsigned short& lo) {
    unsigned u = __float_as_uint(x);
    unsigned r = (u + 0x7fffu + ((u >> 16) & 1u)) >> 16;
    hi = (unsigned short)r;
    float rem = x - __uint_as_float(r << 16);
    unsigned u2 = __float_as_uint(rem);
    unsigned r2 = (u2 + 0x7fffu + ((u2 >> 16) & 1u)) >> 16;
    lo = (unsigned short)r2;
}

#if defined(__has_builtin)
#if __has_builtin(__builtin_amdgcn_global_load_lds)
#define HAVE_GLL 1
#endif
#endif

__device__ __forceinline__ void gload_lds16(const void* g, void* l) {
#ifdef HAVE_GLL
    __builtin_amdgcn_global_load_lds((const __attribute__((address_space(1))) unsigned int*)g,
                                     (__attribute__((address_space(3))) unsigned int*)l, 16, 0, 0);
#else
    *(uint4*)l = *(const uint4*)g;
#endif
}

// =================== CSR build ===================
__global__ void k_hist(const int* __restrict__ dst, int* __restrict__ deg) {
    int e = blockIdx.x * 256 + threadIdx.x;
    if (e < NE) atomicAdd(&deg[dst[e]], 1);
}

// 1024 threads, 40 entities per thread: local scan + one LDS scan (20 barriers)
__global__ __launch_bounds__(1024) void k_scan(const int* __restrict__ deg,
        int* __restrict__ rowptr, int* __restrict__ cursor) {
    __shared__ int sums[1024];
    int t = threadIdx.x;
    int base = t * 40;
    int local[40];
    int s = 0;
    #pragma unroll
    for (int i = 0; i < 40; i++) {
        int idx = base + i;
        int v = (idx < NENT) ? deg[idx] : 0;
        local[i] = s;
        s += v;
    }
    sums[t] = s;
    __syncthreads();
    #pragma unroll
    for (int off = 1; off < 1024; off <<= 1) {
        int add = (t >= off) ? sums[t - off] : 0;
        __syncthreads();
        sums[t] += add;
        __syncthreads();
    }
    int prefix = (t == 0) ? 0 : sums[t - 1];
    #pragma unroll
    for (int i = 0; i < 40; i++) {
        int idx = base + i;
        if (idx < NENT) {
            int p = prefix + local[i];
            rowptr[idx] = p;
            cursor[idx] = p;
        }
    }
    if (t == 1023) rowptr[NENT] = prefix + s;
}

__global__ void k_scatter(const int* __restrict__ src, const int* __restrict__ dst,
                          const int* __restrict__ aet, const float* __restrict__ a2t,
                          const float* __restrict__ a3t, int* __restrict__ cursor,
                          int* __restrict__ ssrc, float* __restrict__ sa1,
                          float* __restrict__ sa2) {
    int e = blockIdx.x * 256 + threadIdx.x;
    if (e >= NE) return;
    int tt = (e < NTE) ? e + NTE : (e < 2 * NTE ? e - NTE : e);
    int t0 = aet[e], t1 = aet[tt];
    int pos = atomicAdd(&cursor[dst[e]], 1);
    ssrc[pos] = src[e];
    sa1[pos] = a2t[t0] + a2t[t1];
    sa2[pos] = a3t[t0] + a3t[t1];
}

// =================== CSR aggregation: one wave per dst row ===================
__global__ __launch_bounds__(256) void k_agg_csr(const int* __restrict__ rowptr,
        const int* __restrict__ ssrc, const float* __restrict__ sa,
        const float* __restrict__ feats, float* __restrict__ outb) {
    int w = threadIdx.x >> 6, l = threadIdx.x & 63;
    int row = blockIdx.x * 4 + w;
    int beg = rowptr[row], end = rowptr[row + 1];
    float s0 = 0.f, s1 = 0.f, s2 = 0.f, s3 = 0.f;
    for (int i = beg; i < end; i++) {
        int sidx = ssrc[i];
        float a = sa[i];
        const float* f = feats + (long)sidx * DIM;
        s0 += a * f[l];
        s1 += a * f[l + 64];
        s2 += a * f[l + 128];
        if (l < 8) s3 += a * f[l + 192];
    }
    float* o = outb + (long)row * DIM;
    o[l] = s0; o[l + 64] = s1; o[l + 128] = s2;
    if (l < 8) o[l + 192] = s3;
}

// =================== packing kernels ===================
__global__ void k_bntanh(float* __restrict__ x, const float* __restrict__ bias,
                         const float* __restrict__ bn) {
    long i = (long)blockIdx.x * blockDim.x + threadIdx.x;
    if (i >= (long)NENT * DIM) return;
    int j = (int)(i % DIM);
    float g = bn[j], be = bn[DIM + j], m = bn[2 * DIM + j], v = bn[3 * DIM + j];
    float val = x[i] + bias[j];
    val = g * (val - m) * rsqrtf(v + EPSB) + be;
    x[i] = tanhf(val);
}

__global__ void k_bntanh_pack(const float* __restrict__ x, const float* __restrict__ bias,
                              const float* __restrict__ bn, unsigned short* __restrict__ oh,
                              unsigned short* __restrict__ ol) {
    long i = (long)blockIdx.x * 256 + threadIdx.x;
    if (i >= (long)NENT * KPAD) return;
    int j = (int)(i % KPAD);
    long row = i / KPAD;
    unsigned short hi = 0, lo = 0;
    if (j < DIM) {
        float g = bn[j], be = bn[DIM + j], m = bn[2 * DIM + j], v = bn[3 * DIM + j];
        float val = x[row * DIM + j] + bias[j];
        val = g * (val - m) * rsqrtf(v + EPSB) + be;
        val = tanhf(val);
        split_bf16(val, hi, lo);
    }
    oh[i] = hi; ol[i] = lo;
}

__global__ void k_pack_A1(const float* __restrict__ emb, const int* __restrict__ ent,
                          unsigned short* __restrict__ ah, unsigned short* __restrict__ al) {
    long i = (long)blockIdx.x * 256 + threadIdx.x;
    if (i >= (long)NENT * 128) return;
    int k = (int)(i & 127);
    long m = i >> 7;
    unsigned short hi = 0, lo = 0;
    if (k < DIM0) split_bf16(emb[(long)ent[m] * DIM0 + k], hi, lo);
    ah[i] = hi; al[i] = lo;
}

__global__ void k_pack_B(const float* __restrict__ w, unsigned short* __restrict__ bh,
                         unsigned short* __restrict__ bl, int kin, int kpad) {
    int i = blockIdx.x * 256 + threadIdx.x;
    if (i >= 208 * kpad) return;
    int k = i % kpad, n = i / kpad;
    unsigned short hi = 0, lo = 0;
    if (k < kin && n < DIM) split_bf16(w[(long)k * DIM + n], hi, lo);
    bh[i] = hi; bl[i] = lo;
}

__global__ void k_hq(const int* __restrict__ e1, const int* __restrict__ rel,
                     const float* __restrict__ eall, const float* __restrict__ embrel,
                     const float* __restrict__ bn0, float* __restrict__ hq) {
    int i = blockIdx.x * 256 + threadIdx.x;
    if (i >= BQ * 2 * DIM) return;
    int d = i % DIM, c = (i / DIM) & 1, b = i / (2 * DIM);
    float val = (c == 0) ? eall[(long)e1[b] * DIM + d]
                         : embrel[(long)rel[b] * DIM + d];
    float g = bn0[c], be = bn0[2 + c], m = bn0[4 + c], v = bn0[6 + c];
    hq[i] = g * (val - m) * rsqrtf(v + EPSB) + be;
}

__global__ void k_pack_e(const float* __restrict__ x, unsigned short* __restrict__ eh,
                         unsigned short* __restrict__ el) {
    long i = (long)blockIdx.x * 256 + threadIdx.x;
    if (i >= (long)NENT * KPAD) return;
    int j = (int)(i % KPAD);
    long m = i / KPAD;
    unsigned short hi = 0, lo = 0;
    if (j < DIM) split_bf16(x[m * DIM + j], hi, lo);
    eh[i] = hi; el[i] = lo;
}

__global__ void k_pack_fcw(const float* __restrict__ w, unsigned short* __restrict__ wh,
                           unsigned short* __restrict__ wl) {
    long i = (long)blockIdx.x * 256 + threadIdx.x;
    if (i >= (long)208 * FCK) return;
    int k = (int)(i % FCK);
    int n = (int)(i / FCK);
    unsigned short hi = 0, lo = 0;
    if (n < DIM) split_bf16(w[(long)n * FCK + k], hi, lo);
    wh[i] = hi; wl[i] = lo;
}

// =================== layer GEMM (direct-B, small K) ===================
__global__ __launch_bounds__(256) void k_gemm_mfma(
        const unsigned short* __restrict__ Ah, const unsigned short* __restrict__ Al,
        const unsigned short* __restrict__ Bh, const unsigned short* __restrict__ Bl,
        float* __restrict__ C, int kpad) {
    int w = threadIdx.x >> 6, l = threadIdx.x & 63;
    long m0 = (long)blockIdx.x * 64 + w * 16;
    long arow = m0 + (l & 15);
    int kg = (l >> 4) * 8;
    const unsigned short* ahp = Ah + arow * kpad + kg;
    const unsigned short* alp = Al + arow * kpad + kg;
    f32x4 acc[13];
    #pragma unroll
    for (int i = 0; i < 13; i++) acc[i] = (f32x4){0.f, 0.f, 0.f, 0.f};
    for (int kb = 0; kb < kpad; kb += 32) {
        bf16x8 a_h = *(const bf16x8*)(ahp + kb);
        bf16x8 a_l = *(const bf16x8*)(alp + kb);
        #pragma unroll
        for (int nt = 0; nt < 13; nt++) {
            long boff = (long)(nt * 16 + (l & 15)) * kpad + kb + kg;
            bf16x8 b_h = *(const bf16x8*)(Bh + boff);
            bf16x8 b_l = *(const bf16x8*)(Bl + boff);
            acc[nt] = __builtin_amdgcn_mfma_f32_16x16x32_bf16(a_h, b_h, acc[nt], 0, 0, 0);
            acc[nt] = __builtin_amdgcn_mfma_f32_16x16x32_bf16(a_h, b_l, acc[nt], 0, 0, 0);
            acc[nt] = __builtin_amdgcn_mfma_f32_16x16x32_bf16(a_l, b_h, acc[nt], 0, 0, 0);
        }
    }
    long rowo = m0 + (l >> 4) * 4;
    #pragma unroll
    for (int nt = 0; nt < 13; nt++) {
        int col = nt * 16 + (l & 15);
        if (col < DIM) {
            #pragma unroll
            for (int rr = 0; rr < 4; rr++)
                C[(rowo + rr) * DIM + col] = acc[nt][rr];
        }
    }
}

// =================== conv1d + bn1 + relu -> hconv bf16 planes (chunk) =========
__global__ __launch_bounds__(256) void k_conv2(const float* __restrict__ hq,
        const float* __restrict__ convw, const float* __restrict__ convb,
        const float* __restrict__ bn1, unsigned short* __restrict__ hch,
        unsigned short* __restrict__ hcl, int rowoff) {
    __shared__ float hql[400];
    __shared__ float cwl[1280];
    __shared__ float scs[128], shs[128];
    int bl = blockIdx.x;
    int t = threadIdx.x;
    long b = rowoff + bl;
    for (int i = t; i < 400; i += 256) hql[i] = hq[b * 400 + i];
    for (int i = t; i < 1280; i += 256) cwl[i] = convw[i];
    if (t < 128) {
        float g = bn1[t], be = bn1[CCH + t], m = bn1[2 * CCH + t], v = bn1[3 * CCH + t];
        float s = g * rsqrtf(v + EPSB);
        scs[t] = s;
        shs[t] = be - m * s + s * convb[t];
    }
    __syncthreads();
    int c = t >> 1, half = t & 1, p0 = half * 100;
    float cw[10];
    #pragma unroll
    for (int k = 0; k < 10; k++) cw[k] = cwl[c * 10 + k];
    float sc_ = scs[c], sh_ = shs[c];
    long obase = (long)bl * FCK + c * DIM + p0;
    for (int pc = 0; pc < 100; pc += 4) {
        float w0[8], w1[8];
        #pragma unroll
        for (int j = 0; j < 8; j++) {
            int pp = p0 + pc - 2 + j;
            bool ok = (pp >= 0 && pp < DIM);
            w0[j] = ok ? hql[pp] : 0.f;
            w1[j] = ok ? hql[DIM + pp] : 0.f;
        }
        unsigned short h4[4], l4[4];
        #pragma unroll
        for (int j = 0; j < 4; j++) {
            float s = 0.f;
            #pragma unroll
            for (int k = 0; k < 5; k++) s += w0[j + k] * cw[k] + w1[j + k] * cw[5 + k];
            float val = fmaxf(sc_ * s + sh_, 0.f);
            split_bf16(val, h4[j], l4[j]);
        }
        *(ushort4*)&hch[obase + pc] = make_ushort4(h4[0], h4[1], h4[2], h4[3]);
        *(ushort4*)&hcl[obase + pc] = make_ushort4(l4[0], l4[1], l4[2], l4[3]);
    }
}

// =================== FC GEMM: LDS-staged B, split-K, atomic accumulate ========
// grid (QCH/64, NSPLIT): x = m-block (fastest) so blocks sharing a B-seg are
// dispatch-adjacent -> L2 reuse of the staged fcw segment.
__global__ __launch_bounds__(256) void k_fc2(
        const unsigned short* __restrict__ Ah, const unsigned short* __restrict__ Al,
        const unsigned short* __restrict__ Bh, const unsigned short* __restrict__ Bl,
        float* __restrict__ fcsum, int rowoff) {
    __shared__ __align__(16) unsigned short ldsB[2][13312];  // [buf][plane(6656) x2]
    int mb = blockIdx.x, split = blockIdx.y;
    int t = threadIdx.x;
    int w = t >> 6, l = t & 63;
    int kbase = split * KSEG;
    long arow = mb * 64 + w * 16 + (l & 15);
    int kg = (l >> 4) * 8;
    const unsigned short* ahp = Ah + arow * FCK + kbase + kg;
    const unsigned short* alp = Al + arow * FCK + kbase + kg;

    // stage k-step 0 into buf 0
    #pragma unroll
    for (int i = 0; i < 7; i++) {
        int u = i * 256 + t;
        if (u < 1664) {
            int pl = (u >= 832) ? 1 : 0;
            int s2 = u - pl * 832;
            int r = s2 >> 2, kc = s2 & 3;
            const unsigned short* g = (pl ? Bl : Bh) + (long)r * FCK + kbase + kc * 8;
            gload_lds16(g, &ldsB[0][u * 8]);
        }
    }
    bf16x8 aNh = *(const bf16x8*)(ahp);
    bf16x8 aNl = *(const bf16x8*)(alp);

    f32x4 acc[13];
    #pragma unroll
    for (int i = 0; i < 13; i++) acc[i] = (f32x4){0.f, 0.f, 0.f, 0.f};

    int buf = 0;
    for (int ks = 0; ks < 25; ks++) {
        __syncthreads();   // drains staged loads; readers of other buf done
        if (ks + 1 < 25) {
            int knext = kbase + (ks + 1) * 32;
            #pragma unroll
            for (int i = 0; i < 7; i++) {
                int u = i * 256 + t;
                if (u < 1664) {
                    int pl = (u >= 832) ? 1 : 0;
                    int s2 = u - pl * 832;
                    int r = s2 >> 2, kc = s2 & 3;
                    const unsigned short* g = (pl ? Bl : Bh) + (long)r * FCK + knext + kc * 8;
                    gload_lds16(g, &ldsB[buf ^ 1][u * 8]);
                }
            }
        }
        bf16x8 aCh = aNh, aCl = aNl;
        if (ks + 1 < 25) {
            aNh = *(const bf16x8*)(ahp + (ks + 1) * 32);
            aNl = *(const bf16x8*)(alp + (ks + 1) * 32);
        }
        const unsigned short* bh_base = &ldsB[buf][(l & 15) * 32 + kg];
        const unsigned short* bl_base = bh_base + 6656;
        #pragma unroll
        for (int nt = 0; nt < 13; nt++) {
            bf16x8 b_h = *(const bf16x8*)(bh_base + nt * 512);
            bf16x8 b_l = *(const bf16x8*)(bl_base + nt * 512);
            acc[nt] = __builtin_amdgcn_mfma_f32_16x16x32_bf16(aCh, b_h, acc[nt], 0, 0, 0);
            acc[nt] = __builtin_amdgcn_mfma_f32_16x16x32_bf16(aCh, b_l, acc[nt], 0, 0, 0);
            acc[nt] = __builtin_amdgcn_mfma_f32_16x16x32_bf16(aCl, b_h, acc[nt], 0, 0, 0);
        }
        buf ^= 1;
    }
    long rowo = rowoff + mb * 64 + w * 16 + (l >> 4) * 4;
    #pragma unroll
    for (int nt = 0; nt < 13; nt++) {
        int col = nt * 16 + (l & 15);
        if (col < DIM) {
            #pragma unroll
            for (int rr = 0; rr < 4; rr++)
                unsafeAtomicAdd(&fcsum[(rowo + rr) * DIM + col], acc[nt][rr]);
        }
    }
}

// =================== fcsum + bias + bn2 + relu -> h3 planes ===================
__global__ void k_fcreduce(const float* __restrict__ fcsum, const float* __restrict__ fcb,
                           const float* __restrict__ bn2, unsigned short* __restrict__ h3h,
                           unsigned short* __restrict__ h3l) {
    int i = blockIdx.x * 256 + threadIdx.x;
    if (i >= BQ * KPAD) return;
    int j = i % KPAD, b = i / KPAD;
    unsigned short hi = 0, lo = 0;
    if (j < DIM) {
        float s = fcsum[(long)b * DIM + j] + fcb[j];
        float g = bn2[j], be = bn2[DIM + j], m = bn2[2 * DIM + j], v = bn2[3 * DIM + j];
        s = g * (s - m) * rsqrtf(v + EPSB) + be;
        s = fmaxf(s, 0.f);
        split_bf16(s, hi, lo);
    }
    h3h[i] = hi; h3l[i] = lo;
}

// =================== final: sigmoid(h3 @ e_all^T) ===================
// grid (BQ/256, NENT/64): x = m-block fastest so the 8 blocks sharing one
// 64-col B tile are dispatch-adjacent. Wave = 64 rows x 64 cols (4x4 tiles).
__global__ __launch_bounds__(256) void k_mfma_final(
        const unsigned short* __restrict__ Ahi, const unsigned short* __restrict__ Alo,
        const unsigned short* __restrict__ Bhi, const unsigned short* __restrict__ Blo,
        float* __restrict__ out) {
    int w = threadIdx.x >> 6, l = threadIdx.x & 63;
    int n0 = blockIdx.y * 64;
    int m0 = blockIdx.x * 256 + w * 64;
    int lr = l & 15;
    int kb = (l >> 4) * 8;
    const unsigned short* aph = Ahi + (long)(m0 + lr) * KPAD + kb;
    const unsigned short* apl = Alo + (long)(m0 + lr) * KPAD + kb;
    const unsigned short* bph = Bhi + (long)(n0 + lr) * KPAD + kb;
    const unsigned short* bpl = Blo + (long)(n0 + lr) * KPAD + kb;
    f32x4 acc[4][4];
    #pragma unroll
    for (int i = 0; i < 4; i++)
        #pragma unroll
        for (int j = 0; j < 4; j++) acc[i][j] = (f32x4){0.f, 0.f, 0.f, 0.f};
    for (int kt = 0; kt < 7; kt++) {
        int ko = kt * 32;
        bf16x8 bh[4], bl[4];
        #pragma unroll
        for (int nt = 0; nt < 4; nt++) {
            bh[nt] = *(const bf16x8*)(bph + (long)nt * 16 * KPAD + ko);
            bl[nt] = *(const bf16x8*)(bpl + (long)nt * 16 * KPAD + ko);
        }
        #pragma unroll
        for (int mt = 0; mt < 4; mt++) {
            bf16x8 a_h = *(const bf16x8*)(aph + (long)mt * 16 * KPAD + ko);
            bf16x8 a_l = *(const bf16x8*)(apl + (long)mt * 16 * KPAD + ko);
            #pragma unroll
            for (int nt = 0; nt < 4; nt++) {
                acc[mt][nt] = __builtin_amdgcn_mfma_f32_16x16x32_bf16(a_h, bh[nt], acc[mt][nt], 0, 0, 0);
                acc[mt][nt] = __builtin_amdgcn_mfma_f32_16x16x32_bf16(a_h, bl[nt], acc[mt][nt], 0, 0, 0);
                acc[mt][nt] = __builtin_amdgcn_mfma_f32_16x16x32_bf16(a_l, bh[nt], acc[mt][nt], 0, 0, 0);
            }
        }
    }
    int rowb = m0 + (l >> 4) * 4;
    #pragma unroll
    for (int mt = 0; mt < 4; mt++)
        #pragma unroll
        for (int r = 0; r < 4; r++) {
            long row = rowb + mt * 16 + r;
            #pragma unroll
            for (int nt = 0; nt < 4; nt++) {
                float v = acc[mt][nt][r];
                __builtin_nontemporal_store(1.f / (1.f + __expf(-v)),
                                            &out[row * NENT + n0 + nt * 16 + lr]);
            }
        }
}

extern "C" void kernel_launch(void* const* d_in, const int* in_sizes, int n_in,
                              void* d_out, int out_size, void* d_ws, size_t ws_size,
                              hipStream_t stream) {
    (void)in_sizes; (void)n_in; (void)out_size; (void)ws_size;
    const int* src      = (const int*)d_in[0];
    const int* dst      = (const int*)d_in[1];
    const int* aet      = (const int*)d_in[2];
    const int* e1       = (const int*)d_in[3];
    const int* rel      = (const int*)d_in[4];
    const int* entity   = (const int*)d_in[5];
    const float* emb_e  = (const float*)d_in[6];
    const float* embrel = (const float*)d_in[7];
    const float* w2     = (const float*)d_in[8];
    const float* b2     = (const float*)d_in[9];
    const float* alpha2 = (const float*)d_in[10];
    const float* w3     = (const float*)d_in[11];
    const float* b3     = (const float*)d_in[12];
    const float* alpha3 = (const float*)d_in[13];
    const float* bn3    = (const float*)d_in[14];
    const float* bn4    = (const float*)d_in[15];
    const float* bn0    = (const float*)d_in[16];
    const float* bn1    = (const float*)d_in[17];
    const float* bn2    = (const float*)d_in[18];
    const float* convw  = (const float*)d_in[19];
    const float* convb  = (const float*)d_in[20];
    const float* fcw    = (const float*)d_in[21];
    const float* fcb    = (const float*)d_in[22];
    float* out = (float*)d_out;
    float* ws = (float*)d_ws;

    // ---- workspace layout (float offsets, lifetime-based reuse) ----
    float* feats  = ws;
    float* acc    = ws + 8000000;
    float* xbuf   = ws + 16000000;
    unsigned short* e_hi  = (unsigned short*)ws;
    unsigned short* e_lo  = (unsigned short*)(ws + 4500000);
    unsigned short* hc_h  = (unsigned short*)(ws + 9000000);
    unsigned short* hc_l  = (unsigned short*)(ws + 16000000);
    unsigned short* a1_h  = (unsigned short*)(ws + 24000000);
    unsigned short* a1_l  = (unsigned short*)(ws + 26560000);
    unsigned short* a2_h  = (unsigned short*)(ws + 29120000);
    unsigned short* a2_l  = (unsigned short*)(ws + 33600000);
    unsigned short* fcw_h = (unsigned short*)(ws + 24000000);
    unsigned short* fcw_l = (unsigned short*)(ws + 26680000);
    int*   deg    = (int*)(ws + 38100000);
    int*   rowptr = (int*)(ws + 38150000);
    int*   cursor = (int*)(ws + 38200000);
    int*   ssrc   = (int*)(ws + 38250000);
    float* sa1    = ws + 38800000;
    float* sa2    = ws + 39350000;
    float* fcsum  = ws + 39900000;
    float* hq     = ws + 40350000;
    unsigned short* h3_h = (unsigned short*)(ws + 41200000);
    unsigned short* h3_l = (unsigned short*)(ws + 41440000);
    unsigned short* w2t_h = (unsigned short*)(ws + 41700000);
    unsigned short* w2t_l = (unsigned short*)(ws + 41720000);
    unsigned short* w3t_h = (unsigned short*)(ws + 41740000);
    unsigned short* w3t_l = (unsigned short*)(ws + 41770000);

    // ---- CSR build (shared by both layers) ----
    hipMemsetAsync(deg, 0, NENT * 4, stream);
    k_hist<<<(NE + 255) / 256, 256, 0, stream>>>(dst, deg);
    k_scan<<<1, 1024, 0, stream>>>(deg, rowptr, cursor);
    k_scatter<<<(NE + 255) / 256, 256, 0, stream>>>(src, dst, aet, alpha2, alpha3,
                                                    cursor, ssrc, sa1, sa2);

    // ---- pack inputs ----
    k_pack_A1<<<(NENT * 128) / 256, 256, 0, stream>>>(emb_e, entity, a1_h, a1_l);
    k_pack_B<<<(208 * 128 + 255) / 256, 256, 0, stream>>>(w2, w2t_h, w2t_l, DIM0, 128);
    k_pack_B<<<(208 * KPAD + 255) / 256, 256, 0, stream>>>(w3, w3t_h, w3t_l, DIM, KPAD);

    // ---- GCN layer 1 ----
    k_gemm_mfma<<<NENT / 64, 256, 0, stream>>>(a1_h, a1_l, w2t_h, w2t_l, feats, 128);
    k_agg_csr<<<NENT / 4, 256, 0, stream>>>(rowptr, ssrc, sa1, feats, acc);
    k_bntanh_pack<<<(NENT * KPAD + 255) / 256, 256, 0, stream>>>(acc, b2, bn3, a2_h, a2_l);

    // ---- GCN layer 2 ----
    k_gemm_mfma<<<NENT / 64, 256, 0, stream>>>(a2_h, a2_l, w3t_h, w3t_l, feats, KPAD);
    k_agg_csr<<<NENT / 4, 256, 0, stream>>>(rowptr, ssrc, sa2, feats, xbuf);
    k_bntanh<<<(NENT * DIM + 255) / 256, 256, 0, stream>>>(xbuf, b3, bn4);

    // ---- decoder input + packs ----
    k_hq<<<(BQ * 2 * DIM + 255) / 256, 256, 0, stream>>>(e1, rel, xbuf, embrel, bn0, hq);
    k_pack_e<<<(NENT * KPAD + 255) / 256, 256, 0, stream>>>(xbuf, e_hi, e_lo);
    k_pack_fcw<<<(int)(((long)208 * FCK + 255) / 256), 256, 0, stream>>>(fcw, fcw_h, fcw_l);

    // ---- conv + FC in 4 chunks of 512 rows ----
    hipMemsetAsync(fcsum, 0, (size_t)BQ * DIM * 4, stream);
    for (int ch = 0; ch < BQ / QCH; ch++) {
        int rowoff = ch * QCH;
        k_conv2<<<QCH, 256, 0, stream>>>(hq, convw, convb, bn1, hc_h, hc_l, rowoff);
        k_fc2<<<dim3(QCH / 64, NSPLIT), 256, 0, stream>>>(hc_h, hc_l, fcw_h, fcw_l,
                                                          fcsum, rowoff);
    }
    k_fcreduce<<<(BQ * KPAD + 255) / 256, 256, 0, stream>>>(fcsum, fcb, bn2, h3_h, h3_l);

    // ---- final scoring ----
    k_mfma_final<<<dim3(BQ / 256, NENT / 64), 256, 0, stream>>>(h3_h, h3_l, e_hi, e_lo, out);
}

// Round 7
// 1095.331 us; speedup vs baseline: 4.1504x; 1.0240x over previous
//
#include <hip/hip_runtime.h>
#include <math.h>

#define NENT 40000
#define NTE  250000
#define NE   540000      // 2*NTE + NENT
#define DIM0 100
#define DIM  200
#define CCH  128
#define BQ   2048
#define FCK  25600       // CCH*DIM
#define EPSB 1e-5f
#define KPAD 224         // 200 padded to 7*32
#define NSPLIT 32        // split-K for FC
#define KSEG 800         // FCK / NSPLIT
#define QCH  512         // query rows per conv/fc chunk

typedef short bf16x8 __attribute__((ext_vector_type(8)));
typedef float f32x4 __attribute__((ext_vector_type(4)));
typedef unsigned short us8 __attribute__((ext_vector_type(8)));

__device__ __forceinline__ void split_bf16(float x, unsigned short& hi, unsigned short& lo) {
    unsigned u = __float_as_uint(x);
    unsigned r = (u + 0x7fffu + ((u >> 16) & 1u)) >> 16;
    hi = (unsigned short)r;
    float rem = x - __uint_as_float(r << 16);
    unsigned u2 = __float_as_uint(rem);
    unsigned r2 = (u2 + 0x7fffu + ((u2 >> 16) & 1u)) >> 16;
    lo = (unsigned short)r2;
}

#if defined(__has_builtin)
#if __has_builtin(__builtin_amdgcn_global_load_lds)
#define HAVE_GLL 1
#endif
#endif

__device__ __forceinline__ void gload_lds16(const void* g, void* l) {
#ifdef HAVE_GLL
    __builtin_amdgcn_global_load_lds((const __attribute__((address_space(1))) unsigned int*)g,
                                     (__attribute__((address_space(3))) unsigned int*)l, 16, 0, 0);
#else
    *(uint4*)l = *(const uint4*)g;
#endif
}

// =================== CSR build ===================
__global__ void k_hist(const int* __restrict__ dst, int* __restrict__ deg) {
    int e = blockIdx.x * 256 + threadIdx.x;
    if (e < NE) atomicAdd(&deg[dst[e]], 1);
}

__global__ __launch_bounds__(1024) void k_scan(const int* __restrict__ deg,
        int* __restrict__ rowptr, int* __restrict__ cursor) {
    __shared__ int sums[1024];
    int t = threadIdx.x;
    int base = t * 40;
    int local[40];
    int s = 0;
    #pragma unroll
    for (int i = 0; i < 40; i++) {
        int idx = base + i;
        int v = (idx < NENT) ? deg[idx] : 0;
        local[i] = s;
        s += v;
    }
    sums[t] = s;
    __syncthreads();
    #pragma unroll
    for (int off = 1; off < 1024; off <<= 1) {
        int add = (t >= off) ? sums[t - off] : 0;
        __syncthreads();
        sums[t] += add;
        __syncthreads();
    }
    int prefix = (t == 0) ? 0 : sums[t - 1];
    #pragma unroll
    for (int i = 0; i < 40; i++) {
        int idx = base + i;
        if (idx < NENT) {
            int p = prefix + local[i];
            rowptr[idx] = p;
            cursor[idx] = p;
        }
    }
    if (t == 1023) rowptr[NENT] = prefix + s;
}

__global__ void k_scatter(const int* __restrict__ src, const int* __restrict__ dst,
                          const int* __restrict__ aet, const float* __restrict__ a2t,
                          const float* __restrict__ a3t, int* __restrict__ cursor,
                          int* __restrict__ ssrc, float* __restrict__ sa1,
                          float* __restrict__ sa2) {
    int e = blockIdx.x * 256 + threadIdx.x;
    if (e >= NE) return;
    int tt = (e < NTE) ? e + NTE : (e < 2 * NTE ? e - NTE : e);
    int t0 = aet[e], t1 = aet[tt];
    int pos = atomicAdd(&cursor[dst[e]], 1);
    ssrc[pos] = src[e];
    sa1[pos] = a2t[t0] + a2t[t1];
    sa2[pos] = a3t[t0] + a3t[t1];
}

// =================== CSR aggregation, fused epilogues =========================
// One wave per dst row; lanes 0..49 hold float4 (200 cols). EPI=1: bn+tanh ->
// packed bf16 hi/lo planes [row][KPAD] (zero pads). EPI=2: bn+tanh -> fp32
// out32 AND packed planes (zero pads).
template<int EPI>
__global__ __launch_bounds__(256) void k_agg_csr(const int* __restrict__ rowptr,
        const int* __restrict__ ssrc, const float* __restrict__ sa,
        const float* __restrict__ feats, float* __restrict__ out32,
        const float* __restrict__ bias, const float* __restrict__ bn,
        unsigned short* __restrict__ oh, unsigned short* __restrict__ ol) {
    int w = threadIdx.x >> 6, l = threadIdx.x & 63;
    int row = blockIdx.x * 4 + w;
    int beg = rowptr[row], end = rowptr[row + 1];
    bool act = l < 50;
    int col = l * 4;
    float sx = 0.f, sy = 0.f, sz = 0.f, sw = 0.f;
    int i = beg;
    for (; i + 2 <= end; i += 2) {
        int i0 = ssrc[i], i1 = ssrc[i + 1];
        float a0 = sa[i], a1 = sa[i + 1];
        if (act) {
            float4 v0 = *(const float4*)(feats + (long)i0 * DIM + col);
            float4 v1 = *(const float4*)(feats + (long)i1 * DIM + col);
            sx += a0 * v0.x + a1 * v1.x;
            sy += a0 * v0.y + a1 * v1.y;
            sz += a0 * v0.z + a1 * v1.z;
            sw += a0 * v0.w + a1 * v1.w;
        }
    }
    if (i < end) {
        int i0 = ssrc[i];
        float a0 = sa[i];
        if (act) {
            float4 v0 = *(const float4*)(feats + (long)i0 * DIM + col);
            sx += a0 * v0.x; sy += a0 * v0.y; sz += a0 * v0.z; sw += a0 * v0.w;
        }
    }
    if (act) {
        float4 g  = *(const float4*)(bn + col);
        float4 be = *(const float4*)(bn + DIM + col);
        float4 m  = *(const float4*)(bn + 2 * DIM + col);
        float4 v  = *(const float4*)(bn + 3 * DIM + col);
        float4 bb = *(const float4*)(bias + col);
        float4 t;
        t.x = tanhf(g.x * (sx + bb.x - m.x) * rsqrtf(v.x + EPSB) + be.x);
        t.y = tanhf(g.y * (sy + bb.y - m.y) * rsqrtf(v.y + EPSB) + be.y);
        t.z = tanhf(g.z * (sz + bb.z - m.z) * rsqrtf(v.z + EPSB) + be.z);
        t.w = tanhf(g.w * (sw + bb.w - m.w) * rsqrtf(v.w + EPSB) + be.w);
        if (EPI == 2) *(float4*)(out32 + (long)row * DIM + col) = t;
        ushort4 h4, l4;
        split_bf16(t.x, h4.x, l4.x);
        split_bf16(t.y, h4.y, l4.y);
        split_bf16(t.z, h4.z, l4.z);
        split_bf16(t.w, h4.w, l4.w);
        *(ushort4*)(oh + (long)row * KPAD + col) = h4;
        *(ushort4*)(ol + (long)row * KPAD + col) = l4;
    } else if (l < 56) {
        // zero the k-pad [200,224): poison bytes can decode as bf16 NaN and
        // NaN*0 = NaN in the downstream MFMA k-padding.
        ushort4 z = make_ushort4(0, 0, 0, 0);
        *(ushort4*)(oh + (long)row * KPAD + col) = z;
        *(ushort4*)(ol + (long)row * KPAD + col) = z;
    }
}

// =================== packing kernels ===================
__global__ void k_pack_A1(const float* __restrict__ emb, const int* __restrict__ ent,
                          unsigned short* __restrict__ ah, unsigned short* __restrict__ al) {
    long i = (long)blockIdx.x * 256 + threadIdx.x;
    if (i >= (long)NENT * 128) return;
    int k = (int)(i & 127);
    long m = i >> 7;
    unsigned short hi = 0, lo = 0;
    if (k < DIM0) split_bf16(emb[(long)ent[m] * DIM0 + k], hi, lo);
    ah[i] = hi; al[i] = lo;
}

__global__ void k_pack_B(const float* __restrict__ w, unsigned short* __restrict__ bh,
                         unsigned short* __restrict__ bl, int kin, int kpad) {
    int i = blockIdx.x * 256 + threadIdx.x;
    if (i >= 208 * kpad) return;
    int k = i % kpad, n = i / kpad;
    unsigned short hi = 0, lo = 0;
    if (k < kin && n < DIM) split_bf16(w[(long)k * DIM + n], hi, lo);
    bh[i] = hi; bl[i] = lo;
}

__global__ void k_hq(const int* __restrict__ e1, const int* __restrict__ rel,
                     const float* __restrict__ eall, const float* __restrict__ embrel,
                     const float* __restrict__ bn0, float* __restrict__ hq) {
    int i = blockIdx.x * 256 + threadIdx.x;
    if (i >= BQ * 2 * DIM) return;
    int d = i % DIM, c = (i / DIM) & 1, b = i / (2 * DIM);
    float val = (c == 0) ? eall[(long)e1[b] * DIM + d]
                         : embrel[(long)rel[b] * DIM + d];
    float g = bn0[c], be = bn0[2 + c], m = bn0[4 + c], v = bn0[6 + c];
    hq[i] = g * (val - m) * rsqrtf(v + EPSB) + be;
}

// vectorized: each thread packs 8 consecutive k of one n-row (ushort8 stores)
__global__ void k_pack_fcw(const float* __restrict__ w, unsigned short* __restrict__ wh,
                           unsigned short* __restrict__ wl) {
    long i = (long)blockIdx.x * 256 + threadIdx.x;
    if (i >= (long)208 * (FCK / 8)) return;
    int n = (int)(i / (FCK / 8));
    long k0 = (i % (FCK / 8)) * 8;
    us8 h = {0, 0, 0, 0, 0, 0, 0, 0};
    us8 lo = {0, 0, 0, 0, 0, 0, 0, 0};
    if (n < DIM) {
        const float* p = w + (long)n * FCK + k0;
        #pragma unroll
        for (int j = 0; j < 8; j++) {
            unsigned short hh, ll;
            split_bf16(p[j], hh, ll);
            h[j] = hh; lo[j] = ll;
        }
    }
    *(us8*)(wh + (long)n * FCK + k0) = h;
    *(us8*)(wl + (long)n * FCK + k0) = lo;
}

// =================== layer GEMM (direct-B, small K) ===================
__global__ __launch_bounds__(256) void k_gemm_mfma(
        const unsigned short* __restrict__ Ah, const unsigned short* __restrict__ Al,
        const unsigned short* __restrict__ Bh, const unsigned short* __restrict__ Bl,
        float* __restrict__ C, int kpad) {
    int w = threadIdx.x >> 6, l = threadIdx.x & 63;
    long m0 = (long)blockIdx.x * 64 + w * 16;
    long arow = m0 + (l & 15);
    int kg = (l >> 4) * 8;
    const unsigned short* ahp = Ah + arow * kpad + kg;
    const unsigned short* alp = Al + arow * kpad + kg;
    f32x4 acc[13];
    #pragma unroll
    for (int i = 0; i < 13; i++) acc[i] = (f32x4){0.f, 0.f, 0.f, 0.f};
    for (int kb = 0; kb < kpad; kb += 32) {
        bf16x8 a_h = *(const bf16x8*)(ahp + kb);
        bf16x8 a_l = *(const bf16x8*)(alp + kb);
        #pragma unroll
        for (int nt = 0; nt < 13; nt++) {
            long boff = (long)(nt * 16 + (l & 15)) * kpad + kb + kg;
            bf16x8 b_h = *(const bf16x8*)(Bh + boff);
            bf16x8 b_l = *(const bf16x8*)(Bl + boff);
            acc[nt] = __builtin_amdgcn_mfma_f32_16x16x32_bf16(a_h, b_h, acc[nt], 0, 0, 0);
            acc[nt] = __builtin_amdgcn_mfma_f32_16x16x32_bf16(a_h, b_l, acc[nt], 0, 0, 0);
            acc[nt] = __builtin_amdgcn_mfma_f32_16x16x32_bf16(a_l, b_h, acc[nt], 0, 0, 0);
        }
    }
    long rowo = m0 + (l >> 4) * 4;
    #pragma unroll
    for (int nt = 0; nt < 13; nt++) {
        int col = nt * 16 + (l & 15);
        if (col < DIM) {
            #pragma unroll
            for (int rr = 0; rr < 4; rr++)
                C[(rowo + rr) * DIM + col] = acc[nt][rr];
        }
    }
}

// =================== conv1d + bn1 + relu -> hconv bf16 planes (chunk) =========
__global__ __launch_bounds__(256) void k_conv2(const float* __restrict__ hq,
        const float* __restrict__ convw, const float* __restrict__ convb,
        const float* __restrict__ bn1, unsigned short* __restrict__ hch,
        unsigned short* __restrict__ hcl, int rowoff) {
    __shared__ float hql[400];
    __shared__ float cwl[1280];
    __shared__ float scs[128], shs[128];
    int bl = blockIdx.x;
    int t = threadIdx.x;
    long b = rowoff + bl;
    for (int i = t; i < 400; i += 256) hql[i] = hq[b * 400 + i];
    for (int i = t; i < 1280; i += 256) cwl[i] = convw[i];
    if (t < 128) {
        float g = bn1[t], be = bn1[CCH + t], m = bn1[2 * CCH + t], v = bn1[3 * CCH + t];
        float s = g * rsqrtf(v + EPSB);
        scs[t] = s;
        shs[t] = be - m * s + s * convb[t];
    }
    __syncthreads();
    int c = t >> 1, half = t & 1, p0 = half * 100;
    float cw[10];
    #pragma unroll
    for (int k = 0; k < 10; k++) cw[k] = cwl[c * 10 + k];
    float sc_ = scs[c], sh_ = shs[c];
    long obase = (long)bl * FCK + c * DIM + p0;
    for (int pc = 0; pc < 100; pc += 4) {
        float w0[8], w1[8];
        #pragma unroll
        for (int j = 0; j < 8; j++) {
            int pp = p0 + pc - 2 + j;
            bool ok = (pp >= 0 && pp < DIM);
            w0[j] = ok ? hql[pp] : 0.f;
            w1[j] = ok ? hql[DIM + pp] : 0.f;
        }
        unsigned short h4[4], l4[4];
        #pragma unroll
        for (int j = 0; j < 4; j++) {
            float s = 0.f;
            #pragma unroll
            for (int k = 0; k < 5; k++) s += w0[j + k] * cw[k] + w1[j + k] * cw[5 + k];
            float val = fmaxf(sc_ * s + sh_, 0.f);
            split_bf16(val, h4[j], l4[j]);
        }
        *(ushort4*)&hch[obase + pc] = make_ushort4(h4[0], h4[1], h4[2], h4[3]);
        *(ushort4*)&hcl[obase + pc] = make_ushort4(l4[0], l4[1], l4[2], l4[3]);
    }
}

// =================== FC GEMM: LDS-staged B, split-K, atomic accumulate ========
__global__ __launch_bounds__(256) void k_fc2(
        const unsigned short* __restrict__ Ah, const unsigned short* __restrict__ Al,
        const unsigned short* __restrict__ Bh, const unsigned short* __restrict__ Bl,
        float* __restrict__ fcsum, int rowoff) {
    __shared__ __align__(16) unsigned short ldsB[2][13312];  // [buf][plane(6656) x2]
    int mb = blockIdx.x, split = blockIdx.y;
    int t = threadIdx.x;
    int w = t >> 6, l = t & 63;
    int kbase = split * KSEG;
    long arow = mb * 64 + w * 16 + (l & 15);
    int kg = (l >> 4) * 8;
    const unsigned short* ahp = Ah + arow * FCK + kbase + kg;
    const unsigned short* alp = Al + arow * FCK + kbase + kg;

    #pragma unroll
    for (int i = 0; i < 7; i++) {
        int u = i * 256 + t;
        if (u < 1664) {
            int pl = (u >= 832) ? 1 : 0;
            int s2 = u - pl * 832;
            int r = s2 >> 2, kc = s2 & 3;
            const unsigned short* g = (pl ? Bl : Bh) + (long)r * FCK + kbase + kc * 8;
            gload_lds16(g, &ldsB[0][u * 8]);
        }
    }
    bf16x8 aNh = *(const bf16x8*)(ahp);
    bf16x8 aNl = *(const bf16x8*)(alp);

    f32x4 acc[13];
    #pragma unroll
    for (int i = 0; i < 13; i++) acc[i] = (f32x4){0.f, 0.f, 0.f, 0.f};

    int buf = 0;
    for (int ks = 0; ks < 25; ks++) {
        __syncthreads();
        if (ks + 1 < 25) {
            int knext = kbase + (ks + 1) * 32;
            #pragma unroll
            for (int i = 0; i < 7; i++) {
                int u = i * 256 + t;
                if (u < 1664) {
                    int pl = (u >= 832) ? 1 : 0;
                    int s2 = u - pl * 832;
                    int r = s2 >> 2, kc = s2 & 3;
                    const unsigned short* g = (pl ? Bl : Bh) + (long)r * FCK + knext + kc * 8;
                    gload_lds16(g, &ldsB[buf ^ 1][u * 8]);
                }
            }
        }
        bf16x8 aCh = aNh, aCl = aNl;
        if (ks + 1 < 25) {
            aNh = *(const bf16x8*)(ahp + (ks + 1) * 32);
            aNl = *(const bf16x8*)(alp + (ks + 1) * 32);
        }
        const unsigned short* bh_base = &ldsB[buf][(l & 15) * 32 + kg];
        const unsigned short* bl_base = bh_base + 6656;
        #pragma unroll
        for (int nt = 0; nt < 13; nt++) {
            bf16x8 b_h = *(const bf16x8*)(bh_base + nt * 512);
            bf16x8 b_l = *(const bf16x8*)(bl_base + nt * 512);
            acc[nt] = __builtin_amdgcn_mfma_f32_16x16x32_bf16(aCh, b_h, acc[nt], 0, 0, 0);
            acc[nt] = __builtin_amdgcn_mfma_f32_16x16x32_bf16(aCh, b_l, acc[nt], 0, 0, 0);
            acc[nt] = __builtin_amdgcn_mfma_f32_16x16x32_bf16(aCl, b_h, acc[nt], 0, 0, 0);
        }
        buf ^= 1;
    }
    long rowo = rowoff + mb * 64 + w * 16 + (l >> 4) * 4;
    #pragma unroll
    for (int nt = 0; nt < 13; nt++) {
        int col = nt * 16 + (l & 15);
        if (col < DIM) {
            #pragma unroll
            for (int rr = 0; rr < 4; rr++)
                unsafeAtomicAdd(&fcsum[(rowo + rr) * DIM + col], acc[nt][rr]);
        }
    }
}

// =================== fcsum + bias + bn2 + relu -> h3 planes ===================
__global__ void k_fcreduce(const float* __restrict__ fcsum, const float* __restrict__ fcb,
                           const float* __restrict__ bn2, unsigned short* __restrict__ h3h,
                           unsigned short* __restrict__ h3l) {
    int i = blockIdx.x * 256 + threadIdx.x;
    if (i >= BQ * KPAD) return;
    int j = i % KPAD, b = i / KPAD;
    unsigned short hi = 0, lo = 0;
    if (j < DIM) {
        float s = fcsum[(long)b * DIM + j] + fcb[j];
        float g = bn2[j], be = bn2[DIM + j], m = bn2[2 * DIM + j], v = bn2[3 * DIM + j];
        s = g * (s - m) * rsqrtf(v + EPSB) + be;
        s = fmaxf(s, 0.f);
        split_bf16(s, hi, lo);
    }
    h3h[i] = hi; h3l[i] = lo;
}

// =================== final: sigmoid(h3 @ e_all^T) ===================
// grid (BQ/256, NENT/64), m fastest. Wave = 64 rows x 64 cols. B tile loads
// are double-buffered in registers (prefetch kt+1 before MFMA on kt).
__global__ __launch_bounds__(256) void k_mfma_final(
        const unsigned short* __restrict__ Ahi, const unsigned short* __restrict__ Alo,
        const unsigned short* __restrict__ Bhi, const unsigned short* __restrict__ Blo,
        float* __restrict__ out) {
    int w = threadIdx.x >> 6, l = threadIdx.x & 63;
    int n0 = blockIdx.y * 64;
    int m0 = blockIdx.x * 256 + w * 64;
    int lr = l & 15;
    int kb = (l >> 4) * 8;
    const unsigned short* aph = Ahi + (long)(m0 + lr) * KPAD + kb;
    const unsigned short* apl = Alo + (long)(m0 + lr) * KPAD + kb;
    const unsigned short* bph = Bhi + (long)(n0 + lr) * KPAD + kb;
    const unsigned short* bpl = Blo + (long)(n0 + lr) * KPAD + kb;
    bf16x8 cbh[4], cbl[4];
    #pragma unroll
    for (int nt = 0; nt < 4; nt++) {
        cbh[nt] = *(const bf16x8*)(bph + (long)nt * 16 * KPAD);
        cbl[nt] = *(const bf16x8*)(bpl + (long)nt * 16 * KPAD);
    }
    f32x4 acc[4][4];
    #pragma unroll
    for (int i = 0; i < 4; i++)
        #pragma unroll
        for (int j = 0; j < 4; j++) acc[i][j] = (f32x4){0.f, 0.f, 0.f, 0.f};
    for (int kt = 0; kt < 7; kt++) {
        int ko = kt * 32;
        bf16x8 nbh[4], nbl[4];
        if (kt < 6) {
            #pragma unroll
            for (int nt = 0; nt < 4; nt++) {
                nbh[nt] = *(const bf16x8*)(bph + (long)nt * 16 * KPAD + ko + 32);
                nbl[nt] = *(const bf16x8*)(bpl + (long)nt * 16 * KPAD + ko + 32);
            }
        }
        #pragma unroll
        for (int mt = 0; mt < 4; mt++) {
            bf16x8 a_h = *(const bf16x8*)(aph + (long)mt * 16 * KPAD + ko);
            bf16x8 a_l = *(const bf16x8*)(apl + (long)mt * 16 * KPAD + ko);
            #pragma unroll
            for (int nt = 0; nt < 4; nt++) {
                acc[mt][nt] = __builtin_amdgcn_mfma_f32_16x16x32_bf16(a_h, cbh[nt], acc[mt][nt], 0, 0, 0);
                acc[mt][nt] = __builtin_amdgcn_mfma_f32_16x16x32_bf16(a_h, cbl[nt], acc[mt][nt], 0, 0, 0);
                acc[mt][nt] = __builtin_amdgcn_mfma_f32_16x16x32_bf16(a_l, cbh[nt], acc[mt][nt], 0, 0, 0);
            }
        }
        if (kt < 6) {
            #pragma unroll
            for (int nt = 0; nt < 4; nt++) { cbh[nt] = nbh[nt]; cbl[nt] = nbl[nt]; }
        }
    }
    int rowb = m0 + (l >> 4) * 4;
    #pragma unroll
    for (int mt = 0; mt < 4; mt++)
        #pragma unroll
        for (int r = 0; r < 4; r++) {
            long row = rowb + mt * 16 + r;
            #pragma unroll
            for (int nt = 0; nt < 4; nt++) {
                float v = acc[mt][nt][r];
                out[row * NENT + n0 + nt * 16 + lr] = 1.f / (1.f + __expf(-v));
            }
        }
}

extern "C" void kernel_launch(void* const* d_in, const int* in_sizes, int n_in,
                              void* d_out, int out_size, void* d_ws, size_t ws_size,
                              hipStream_t stream) {
    (void)in_sizes; (void)n_in; (void)out_size; (void)ws_size;
    const int* src      = (const int*)d_in[0];
    const int* dst      = (const int*)d_in[1];
    const int* aet      = (const int*)d_in[2];
    const int* e1       = (const int*)d_in[3];
    const int* rel      = (const int*)d_in[4];
    const int* entity   = (const int*)d_in[5];
    const float* emb_e  = (const float*)d_in[6];
    const float* embrel = (const float*)d_in[7];
    const float* w2     = (const float*)d_in[8];
    const float* b2     = (const float*)d_in[9];
    const float* alpha2 = (const float*)d_in[10];
    const float* w3     = (const float*)d_in[11];
    const float* b3     = (const float*)d_in[12];
    const float* alpha3 = (const float*)d_in[13];
    const float* bn3    = (const float*)d_in[14];
    const float* bn4    = (const float*)d_in[15];
    const float* bn0    = (const float*)d_in[16];
    const float* bn1    = (const float*)d_in[17];
    const float* bn2    = (const float*)d_in[18];
    const float* convw  = (const float*)d_in[19];
    const float* convb  = (const float*)d_in[20];
    const float* fcw    = (const float*)d_in[21];
    const float* fcb    = (const float*)d_in[22];
    float* out = (float*)d_out;
    float* ws = (float*)d_ws;

    // ---- workspace layout (float offsets, lifetime-based reuse) ----
    // [0,8M)        feats (gemm out / agg src; dead after agg2)
    //               then fcw planes [0,5.34M) (written by pack_fcw, after agg2)
    // [9M,15.56M)   hc_h ; [16M,22.56M) hc_l (xbuf region reused after hq)
    // [16M,24M)     xbuf (agg2 fp32 out; dead after hq)
    // [24M,29.12M)  a1 planes (dead after gemm1)
    // [29.12M,38.08M) a2 planes (dead after gemm2) -> then e planes (agg2 out)
    // [38.1M,39.89M) CSR: deg/rowptr/cursor/ssrc/sa1/sa2
    // [39.9M)       fcsum ; [40.35M) hq ; [41.2M) h3 planes ; [41.7M) w2t/w3t
    float* feats  = ws;
    float* xbuf   = ws + 16000000;
    unsigned short* fcw_h = (unsigned short*)ws;
    unsigned short* fcw_l = (unsigned short*)(ws + 2670000);
    unsigned short* hc_h  = (unsigned short*)(ws + 9000000);
    unsigned short* hc_l  = (unsigned short*)(ws + 16000000);
    unsigned short* a1_h  = (unsigned short*)(ws + 24000000);
    unsigned short* a1_l  = (unsigned short*)(ws + 26560000);
    unsigned short* a2_h  = (unsigned short*)(ws + 29120000);
    unsigned short* a2_l  = (unsigned short*)(ws + 33600000);
    unsigned short* e_hi  = (unsigned short*)(ws + 29120000);  // reuses a2 (dead)
    unsigned short* e_lo  = (unsigned short*)(ws + 33600000);
    int*   deg    = (int*)(ws + 38100000);
    int*   rowptr = (int*)(ws + 38150000);
    int*   cursor = (int*)(ws + 38200000);
    int*   ssrc   = (int*)(ws + 38250000);
    float* sa1    = ws + 38800000;
    float* sa2    = ws + 39350000;
    float* fcsum  = ws + 39900000;
    float* hq     = ws + 40350000;
    unsigned short* h3_h = (unsigned short*)(ws + 41200000);
    unsigned short* h3_l = (unsigned short*)(ws + 41440000);
    unsigned short* w2t_h = (unsigned short*)(ws + 41700000);
    unsigned short* w2t_l = (unsigned short*)(ws + 41720000);
    unsigned short* w3t_h = (unsigned short*)(ws + 41740000);
    unsigned short* w3t_l = (unsigned short*)(ws + 41770000);

    // ---- CSR build (shared by both layers) ----
    hipMemsetAsync(deg, 0, NENT * 4, stream);
    k_hist<<<(NE + 255) / 256, 256, 0, stream>>>(dst, deg);
    k_scan<<<1, 1024, 0, stream>>>(deg, rowptr, cursor);
    k_scatter<<<(NE + 255) / 256, 256, 0, stream>>>(src, dst, aet, alpha2, alpha3,
                                                    cursor, ssrc, sa1, sa2);

    // ---- pack inputs ----
    k_pack_A1<<<(NENT * 128) / 256, 256, 0, stream>>>(emb_e, entity, a1_h, a1_l);
    k_pack_B<<<(208 * 128 + 255) / 256, 256, 0, stream>>>(w2, w2t_h, w2t_l, DIM0, 128);
    k_pack_B<<<(208 * KPAD + 255) / 256, 256, 0, stream>>>(w3, w3t_h, w3t_l, DIM, KPAD);

    // ---- GCN layer 1 (agg fuses bn3+tanh+bf16-pack) ----
    k_gemm_mfma<<<NENT / 64, 256, 0, stream>>>(a1_h, a1_l, w2t_h, w2t_l, feats, 128);
    k_agg_csr<1><<<NENT / 4, 256, 0, stream>>>(rowptr, ssrc, sa1, feats, nullptr,
                                               b2, bn3, a2_h, a2_l);

    // ---- GCN layer 2 (agg fuses bn4+tanh, writes xbuf fp32 + e planes) ----
    k_gemm_mfma<<<NENT / 64, 256, 0, stream>>>(a2_h, a2_l, w3t_h, w3t_l, feats, KPAD);
    k_agg_csr<2><<<NENT / 4, 256, 0, stream>>>(rowptr, ssrc, sa2, feats, xbuf,
                                               b3, bn4, e_hi, e_lo);

    // ---- decoder input + fcw pack ----
    k_hq<<<(BQ * 2 * DIM + 255) / 256, 256, 0, stream>>>(e1, rel, xbuf, embrel, bn0, hq);
    k_pack_fcw<<<(int)(((long)208 * (FCK / 8) + 255) / 256), 256, 0, stream>>>(fcw, fcw_h, fcw_l);

    // ---- conv + FC in 4 chunks of 512 rows ----
    hipMemsetAsync(fcsum, 0, (size_t)BQ * DIM * 4, stream);
    for (int ch = 0; ch < BQ / QCH; ch++) {
        int rowoff = ch * QCH;
        k_conv2<<<QCH, 256, 0, stream>>>(hq, convw, convb, bn1, hc_h, hc_l, rowoff);
        k_fc2<<<dim3(QCH / 64, NSPLIT), 256, 0, stream>>>(hc_h, hc_l, fcw_h, fcw_l,
                                                          fcsum, rowoff);
    }
    k_fcreduce<<<(BQ * KPAD + 255) / 256, 256, 0, stream>>>(fcsum, fcb, bn2, h3_h, h3_l);

    // ---- final scoring ----
    k_mfma_final<<<dim3(BQ / 256, NENT / 64), 256, 0, stream>>>(h3_h, h3_l, e_hi, e_lo, out);
}

// Round 8
// 1079.055 us; speedup vs baseline: 4.2130x; 1.0151x over previous
//
#include <hip/hip_runtime.h>
#include <math.h>

#define NENT 40000
#define NTE  250000
#define NE   540000      // 2*NTE + NENT
#define DIM0 100
#define DIM  200
#define CCH  128
#define BQ   2048
#define FCK  25600       // CCH*DIM
#define EPSB 1e-5f
#define KPAD 224         // 200 padded to 7*32
#define NSPLIT 32        // split-K for FC
#define KSEG 800         // FCK / NSPLIT
#define QCH  512         // query rows per conv/fc chunk

typedef short bf16x8 __attribute__((ext_vector_type(8)));
typedef float f32x4 __attribute__((ext_vector_type(4)));
typedef unsigned short us8 __attribute__((ext_vector_type(8)));

__device__ __forceinline__ void split_bf16(float x, unsigned short& hi, unsigned short& lo) {
    unsigned u = __float_as_uint(x);
    unsigned r = (u + 0x7fffu + ((u >> 16) & 1u)) >> 16;
    hi = (unsigned short)r;
    float rem = x - __uint_as_float(r << 16);
    unsigned u2 = __float_as_uint(rem);
    unsigned r2 = (u2 + 0x7fffu + ((u2 >> 16) & 1u)) >> 16;
    lo = (unsigned short)r2;
}

#if defined(__has_builtin)
#if __has_builtin(__builtin_amdgcn_global_load_lds)
#define HAVE_GLL 1
#endif
#endif

__device__ __forceinline__ void gload_lds16(const void* g, void* l) {
#ifdef HAVE_GLL
    __builtin_amdgcn_global_load_lds((const __attribute__((address_space(1))) unsigned int*)g,
                                     (__attribute__((address_space(3))) unsigned int*)l, 16, 0, 0);
#else
    *(uint4*)l = *(const uint4*)g;
#endif
}

// =================== CSR build ===================
__global__ void k_hist(const int* __restrict__ dst, int* __restrict__ deg) {
    int e = blockIdx.x * 256 + threadIdx.x;
    if (e < NE) atomicAdd(&deg[dst[e]], 1);
}

__global__ __launch_bounds__(1024) void k_scan(const int* __restrict__ deg,
        int* __restrict__ rowptr, int* __restrict__ cursor) {
    __shared__ int sums[1024];
    int t = threadIdx.x;
    int base = t * 40;
    int local[40];
    int s = 0;
    #pragma unroll
    for (int i = 0; i < 40; i++) {
        int idx = base + i;
        int v = (idx < NENT) ? deg[idx] : 0;
        local[i] = s;
        s += v;
    }
    sums[t] = s;
    __syncthreads();
    #pragma unroll
    for (int off = 1; off < 1024; off <<= 1) {
        int add = (t >= off) ? sums[t - off] : 0;
        __syncthreads();
        sums[t] += add;
        __syncthreads();
    }
    int prefix = (t == 0) ? 0 : sums[t - 1];
    #pragma unroll
    for (int i = 0; i < 40; i++) {
        int idx = base + i;
        if (idx < NENT) {
            int p = prefix + local[i];
            rowptr[idx] = p;
            cursor[idx] = p;
        }
    }
    if (t == 1023) rowptr[NENT] = prefix + s;
}

__global__ void k_scatter(const int* __restrict__ src, const int* __restrict__ dst,
                          const int* __restrict__ aet, const float* __restrict__ a2t,
                          const float* __restrict__ a3t, int* __restrict__ cursor,
                          int* __restrict__ ssrc, float* __restrict__ sa1,
                          float* __restrict__ sa2) {
    int e = blockIdx.x * 256 + threadIdx.x;
    if (e >= NE) return;
    int tt = (e < NTE) ? e + NTE : (e < 2 * NTE ? e - NTE : e);
    int t0 = aet[e], t1 = aet[tt];
    int pos = atomicAdd(&cursor[dst[e]], 1);
    ssrc[pos] = src[e];
    sa1[pos] = a2t[t0] + a2t[t1];
    sa2[pos] = a3t[t0] + a3t[t1];
}

// =================== CSR aggregation, fused epilogues =========================
template<int EPI>
__global__ __launch_bounds__(256) void k_agg_csr(const int* __restrict__ rowptr,
        const int* __restrict__ ssrc, const float* __restrict__ sa,
        const float* __restrict__ feats, float* __restrict__ out32,
        const float* __restrict__ bias, const float* __restrict__ bn,
        unsigned short* __restrict__ oh, unsigned short* __restrict__ ol) {
    int w = threadIdx.x >> 6, l = threadIdx.x & 63;
    int row = blockIdx.x * 4 + w;
    int beg = rowptr[row], end = rowptr[row + 1];
    bool act = l < 50;
    int col = l * 4;
    float sx = 0.f, sy = 0.f, sz = 0.f, sw = 0.f;
    int i = beg;
    for (; i + 2 <= end; i += 2) {
        int i0 = ssrc[i], i1 = ssrc[i + 1];
        float a0 = sa[i], a1 = sa[i + 1];
        if (act) {
            float4 v0 = *(const float4*)(feats + (long)i0 * DIM + col);
            float4 v1 = *(const float4*)(feats + (long)i1 * DIM + col);
            sx += a0 * v0.x + a1 * v1.x;
            sy += a0 * v0.y + a1 * v1.y;
            sz += a0 * v0.z + a1 * v1.z;
            sw += a0 * v0.w + a1 * v1.w;
        }
    }
    if (i < end) {
        int i0 = ssrc[i];
        float a0 = sa[i];
        if (act) {
            float4 v0 = *(const float4*)(feats + (long)i0 * DIM + col);
            sx += a0 * v0.x; sy += a0 * v0.y; sz += a0 * v0.z; sw += a0 * v0.w;
        }
    }
    if (act) {
        float4 g  = *(const float4*)(bn + col);
        float4 be = *(const float4*)(bn + DIM + col);
        float4 m  = *(const float4*)(bn + 2 * DIM + col);
        float4 v  = *(const float4*)(bn + 3 * DIM + col);
        float4 bb = *(const float4*)(bias + col);
        float4 t;
        t.x = tanhf(g.x * (sx + bb.x - m.x) * rsqrtf(v.x + EPSB) + be.x);
        t.y = tanhf(g.y * (sy + bb.y - m.y) * rsqrtf(v.y + EPSB) + be.y);
        t.z = tanhf(g.z * (sz + bb.z - m.z) * rsqrtf(v.z + EPSB) + be.z);
        t.w = tanhf(g.w * (sw + bb.w - m.w) * rsqrtf(v.w + EPSB) + be.w);
        if (EPI == 2) *(float4*)(out32 + (long)row * DIM + col) = t;
        ushort4 h4, l4;
        split_bf16(t.x, h4.x, l4.x);
        split_bf16(t.y, h4.y, l4.y);
        split_bf16(t.z, h4.z, l4.z);
        split_bf16(t.w, h4.w, l4.w);
        *(ushort4*)(oh + (long)row * KPAD + col) = h4;
        *(ushort4*)(ol + (long)row * KPAD + col) = l4;
    } else if (l < 56) {
        // zero the k-pad [200,224): poison bytes can decode as bf16 NaN
        ushort4 z = make_ushort4(0, 0, 0, 0);
        *(ushort4*)(oh + (long)row * KPAD + col) = z;
        *(ushort4*)(ol + (long)row * KPAD + col) = z;
    }
}

// =================== packing kernels ===================
// vectorized: thread packs 8 consecutive k of one gathered row (ushort8 stores)
__global__ void k_pack_A1(const float* __restrict__ emb, const int* __restrict__ ent,
                          unsigned short* __restrict__ ah, unsigned short* __restrict__ al) {
    long i = (long)blockIdx.x * 256 + threadIdx.x;
    if (i >= (long)NENT * 16) return;
    long m = i >> 4;
    int k0 = (int)(i & 15) << 3;
    us8 h = {0, 0, 0, 0, 0, 0, 0, 0};
    us8 lo = {0, 0, 0, 0, 0, 0, 0, 0};
    const float* p = emb + (long)ent[m] * DIM0 + k0;
    #pragma unroll
    for (int j = 0; j < 8; j++) {
        if (k0 + j < DIM0) {
            unsigned short hh, ll;
            split_bf16(p[j], hh, ll);
            h[j] = hh; lo[j] = ll;
        }
    }
    *(us8*)(ah + m * 128 + k0) = h;
    *(us8*)(al + m * 128 + k0) = lo;
}

__global__ void k_pack_B(const float* __restrict__ w, unsigned short* __restrict__ bh,
                         unsigned short* __restrict__ bl, int kin, int kpad) {
    int i = blockIdx.x * 256 + threadIdx.x;
    if (i >= 208 * kpad) return;
    int k = i % kpad, n = i / kpad;
    unsigned short hi = 0, lo = 0;
    if (k < kin && n < DIM) split_bf16(w[(long)k * DIM + n], hi, lo);
    bh[i] = hi; bl[i] = lo;
}

__global__ void k_hq(const int* __restrict__ e1, const int* __restrict__ rel,
                     const float* __restrict__ eall, const float* __restrict__ embrel,
                     const float* __restrict__ bn0, float* __restrict__ hq) {
    int i = blockIdx.x * 256 + threadIdx.x;
    if (i >= BQ * 2 * DIM) return;
    int d = i % DIM, c = (i / DIM) & 1, b = i / (2 * DIM);
    float val = (c == 0) ? eall[(long)e1[b] * DIM + d]
                         : embrel[(long)rel[b] * DIM + d];
    float g = bn0[c], be = bn0[2 + c], m = bn0[4 + c], v = bn0[6 + c];
    hq[i] = g * (val - m) * rsqrtf(v + EPSB) + be;
}

__global__ void k_pack_fcw(const float* __restrict__ w, unsigned short* __restrict__ wh,
                           unsigned short* __restrict__ wl) {
    long i = (long)blockIdx.x * 256 + threadIdx.x;
    if (i >= (long)208 * (FCK / 8)) return;
    int n = (int)(i / (FCK / 8));
    long k0 = (i % (FCK / 8)) * 8;
    us8 h = {0, 0, 0, 0, 0, 0, 0, 0};
    us8 lo = {0, 0, 0, 0, 0, 0, 0, 0};
    if (n < DIM) {
        const float* p = w + (long)n * FCK + k0;
        #pragma unroll
        for (int j = 0; j < 8; j++) {
            unsigned short hh, ll;
            split_bf16(p[j], hh, ll);
            h[j] = hh; lo[j] = ll;
        }
    }
    *(us8*)(wh + (long)n * FCK + k0) = h;
    *(us8*)(wl + (long)n * FCK + k0) = lo;
}

// =================== layer GEMM (direct-B, small K) ===================
__global__ __launch_bounds__(256) void k_gemm_mfma(
        const unsigned short* __restrict__ Ah, const unsigned short* __restrict__ Al,
        const unsigned short* __restrict__ Bh, const unsigned short* __restrict__ Bl,
        float* __restrict__ C, int kpad) {
    int w = threadIdx.x >> 6, l = threadIdx.x & 63;
    long m0 = (long)blockIdx.x * 64 + w * 16;
    long arow = m0 + (l & 15);
    int kg = (l >> 4) * 8;
    const unsigned short* ahp = Ah + arow * kpad + kg;
    const unsigned short* alp = Al + arow * kpad + kg;
    f32x4 acc[13];
    #pragma unroll
    for (int i = 0; i < 13; i++) acc[i] = (f32x4){0.f, 0.f, 0.f, 0.f};
    for (int kb = 0; kb < kpad; kb += 32) {
        bf16x8 a_h = *(const bf16x8*)(ahp + kb);
        bf16x8 a_l = *(const bf16x8*)(alp + kb);
        #pragma unroll
        for (int nt = 0; nt < 13; nt++) {
            long boff = (long)(nt * 16 + (l & 15)) * kpad + kb + kg;
            bf16x8 b_h = *(const bf16x8*)(Bh + boff);
            bf16x8 b_l = *(const bf16x8*)(Bl + boff);
            acc[nt] = __builtin_amdgcn_mfma_f32_16x16x32_bf16(a_h, b_h, acc[nt], 0, 0, 0);
            acc[nt] = __builtin_amdgcn_mfma_f32_16x16x32_bf16(a_h, b_l, acc[nt], 0, 0, 0);
            acc[nt] = __builtin_amdgcn_mfma_f32_16x16x32_bf16(a_l, b_h, acc[nt], 0, 0, 0);
        }
    }
    long rowo = m0 + (l >> 4) * 4;
    #pragma unroll
    for (int nt = 0; nt < 13; nt++) {
        int col = nt * 16 + (l & 15);
        if (col < DIM) {
            #pragma unroll
            for (int rr = 0; rr < 4; rr++)
                C[(rowo + rr) * DIM + col] = acc[nt][rr];
        }
    }
}

// =================== conv1d + bn1 + relu -> hconv bf16 planes (chunk) =========
__global__ __launch_bounds__(256) void k_conv2(const float* __restrict__ hq,
        const float* __restrict__ convw, const float* __restrict__ convb,
        const float* __restrict__ bn1, unsigned short* __restrict__ hch,
        unsigned short* __restrict__ hcl, int rowoff) {
    __shared__ float hql[400];
    __shared__ float cwl[1280];
    __shared__ float scs[128], shs[128];
    int bl = blockIdx.x;
    int t = threadIdx.x;
    long b = rowoff + bl;
    for (int i = t; i < 400; i += 256) hql[i] = hq[b * 400 + i];
    for (int i = t; i < 1280; i += 256) cwl[i] = convw[i];
    if (t < 128) {
        float g = bn1[t], be = bn1[CCH + t], m = bn1[2 * CCH + t], v = bn1[3 * CCH + t];
        float s = g * rsqrtf(v + EPSB);
        scs[t] = s;
        shs[t] = be - m * s + s * convb[t];
    }
    __syncthreads();
    int c = t >> 1, half = t & 1, p0 = half * 100;
    float cw[10];
    #pragma unroll
    for (int k = 0; k < 10; k++) cw[k] = cwl[c * 10 + k];
    float sc_ = scs[c], sh_ = shs[c];
    long obase = (long)bl * FCK + c * DIM + p0;
    for (int pc = 0; pc < 100; pc += 4) {
        float w0[8], w1[8];
        #pragma unroll
        for (int j = 0; j < 8; j++) {
            int pp = p0 + pc - 2 + j;
            bool ok = (pp >= 0 && pp < DIM);
            w0[j] = ok ? hql[pp] : 0.f;
            w1[j] = ok ? hql[DIM + pp] : 0.f;
        }
        unsigned short h4[4], l4[4];
        #pragma unroll
        for (int j = 0; j < 4; j++) {
            float s = 0.f;
            #pragma unroll
            for (int k = 0; k < 5; k++) s += w0[j + k] * cw[k] + w1[j + k] * cw[5 + k];
            float val = fmaxf(sc_ * s + sh_, 0.f);
            split_bf16(val, h4[j], l4[j]);
        }
        *(ushort4*)&hch[obase + pc] = make_ushort4(h4[0], h4[1], h4[2], h4[3]);
        *(ushort4*)&hcl[obase + pc] = make_ushort4(l4[0], l4[1], l4[2], l4[3]);
    }
}

// =================== FC GEMM: LDS-staged B, split-K, atomic accumulate ========
// grid (8, NSPLIT). XCD swizzle: all 8 m-blocks of one split run on ONE XCD
// (bid%8 = XCD on MI355X), so the 640KB fcw segment is fetched once per XCD.
__global__ __launch_bounds__(256) void k_fc2(
        const unsigned short* __restrict__ Ah, const unsigned short* __restrict__ Al,
        const unsigned short* __restrict__ Bh, const unsigned short* __restrict__ Bl,
        float* __restrict__ fcsum, int rowoff) {
    __shared__ __align__(16) unsigned short ldsB[2][13312];  // [buf][plane(6656) x2]
    int bid = blockIdx.y * 8 + blockIdx.x;
    int wsw = (bid & 7) * 32 + (bid >> 3);
    int mb = wsw & 7, split = wsw >> 3;
    int t = threadIdx.x;
    int w = t >> 6, l = t & 63;
    int kbase = split * KSEG;
    long arow = mb * 64 + w * 16 + (l & 15);
    int kg = (l >> 4) * 8;
    const unsigned short* ahp = Ah + arow * FCK + kbase + kg;
    const unsigned short* alp = Al + arow * FCK + kbase + kg;

    #pragma unroll
    for (int i = 0; i < 7; i++) {
        int u = i * 256 + t;
        if (u < 1664) {
            int pl = (u >= 832) ? 1 : 0;
            int s2 = u - pl * 832;
            int r = s2 >> 2, kc = s2 & 3;
            const unsigned short* g = (pl ? Bl : Bh) + (long)r * FCK + kbase + kc * 8;
            gload_lds16(g, &ldsB[0][u * 8]);
        }
    }
    bf16x8 aNh = *(const bf16x8*)(ahp);
    bf16x8 aNl = *(const bf16x8*)(alp);

    f32x4 acc[13];
    #pragma unroll
    for (int i = 0; i < 13; i++) acc[i] = (f32x4){0.f, 0.f, 0.f, 0.f};

    int buf = 0;
    for (int ks = 0; ks < 25; ks++) {
        __syncthreads();
        if (ks + 1 < 25) {
            int knext = kbase + (ks + 1) * 32;
            #pragma unroll
            for (int i = 0; i < 7; i++) {
                int u = i * 256 + t;
                if (u < 1664) {
                    int pl = (u >= 832) ? 1 : 0;
                    int s2 = u - pl * 832;
                    int r = s2 >> 2, kc = s2 & 3;
                    const unsigned short* g = (pl ? Bl : Bh) + (long)r * FCK + knext + kc * 8;
                    gload_lds16(g, &ldsB[buf ^ 1][u * 8]);
                }
            }
        }
        bf16x8 aCh = aNh, aCl = aNl;
        if (ks + 1 < 25) {
            aNh = *(const bf16x8*)(ahp + (ks + 1) * 32);
            aNl = *(const bf16x8*)(alp + (ks + 1) * 32);
        }
        const unsigned short* bh_base = &ldsB[buf][(l & 15) * 32 + kg];
        const unsigned short* bl_base = bh_base + 6656;
        #pragma unroll
        for (int nt = 0; nt < 13; nt++) {
            bf16x8 b_h = *(const bf16x8*)(bh_base + nt * 512);
            bf16x8 b_l = *(const bf16x8*)(bl_base + nt * 512);
            acc[nt] = __builtin_amdgcn_mfma_f32_16x16x32_bf16(aCh, b_h, acc[nt], 0, 0, 0);
            acc[nt] = __builtin_amdgcn_mfma_f32_16x16x32_bf16(aCh, b_l, acc[nt], 0, 0, 0);
            acc[nt] = __builtin_amdgcn_mfma_f32_16x16x32_bf16(aCl, b_h, acc[nt], 0, 0, 0);
        }
        buf ^= 1;
    }
    long rowo = rowoff + mb * 64 + w * 16 + (l >> 4) * 4;
    #pragma unroll
    for (int nt = 0; nt < 13; nt++) {
        int col = nt * 16 + (l & 15);
        if (col < DIM) {
            #pragma unroll
            for (int rr = 0; rr < 4; rr++)
                unsafeAtomicAdd(&fcsum[(rowo + rr) * DIM + col], acc[nt][rr]);
        }
    }
}

// =================== fcsum + bias + bn2 + relu -> h3 planes ===================
__global__ void k_fcreduce(const float* __restrict__ fcsum, const float* __restrict__ fcb,
                           const float* __restrict__ bn2, unsigned short* __restrict__ h3h,
                           unsigned short* __restrict__ h3l) {
    int i = blockIdx.x * 256 + threadIdx.x;
    if (i >= BQ * KPAD) return;
    int j = i % KPAD, b = i / KPAD;
    unsigned short hi = 0, lo = 0;
    if (j < DIM) {
        float s = fcsum[(long)b * DIM + j] + fcb[j];
        float g = bn2[j], be = bn2[DIM + j], m = bn2[2 * DIM + j], v = bn2[3 * DIM + j];
        s = g * (s - m) * rsqrtf(v + EPSB) + be;
        s = fmaxf(s, 0.f);
        split_bf16(s, hi, lo);
    }
    h3h[i] = hi; h3l[i] = lo;
}

// =================== final: sigmoid(h3 @ e_all^T) ===================
// grid (8, 625). XCD swizzle: w = (bid%8)*625 + bid/8 -> m = w%8, n = w/8.
// XCD k owns n-tiles [~78k,...): all 8 m-blocks of an n-tile run consecutively
// on ONE XCD -> B tile served from that XCD's L2 after first fetch.
__global__ __launch_bounds__(256) void k_mfma_final(
        const unsigned short* __restrict__ Ahi, const unsigned short* __restrict__ Alo,
        const unsigned short* __restrict__ Bhi, const unsigned short* __restrict__ Blo,
        float* __restrict__ out) {
    int bid = blockIdx.y * 8 + blockIdx.x;
    int wsw = (bid & 7) * 625 + (bid >> 3);
    int mbb = wsw & 7, nbb = wsw >> 3;
    int w = threadIdx.x >> 6, l = threadIdx.x & 63;
    int n0 = nbb * 64;
    int m0 = mbb * 256 + w * 64;
    int lr = l & 15;
    int kb = (l >> 4) * 8;
    const unsigned short* aph = Ahi + (long)(m0 + lr) * KPAD + kb;
    const unsigned short* apl = Alo + (long)(m0 + lr) * KPAD + kb;
    const unsigned short* bph = Bhi + (long)(n0 + lr) * KPAD + kb;
    const unsigned short* bpl = Blo + (long)(n0 + lr) * KPAD + kb;
    bf16x8 cbh[4], cbl[4];
    #pragma unroll
    for (int nt = 0; nt < 4; nt++) {
        cbh[nt] = *(const bf16x8*)(bph + (long)nt * 16 * KPAD);
        cbl[nt] = *(const bf16x8*)(bpl + (long)nt * 16 * KPAD);
    }
    f32x4 acc[4][4];
    #pragma unroll
    for (int i = 0; i < 4; i++)
        #pragma unroll
        for (int j = 0; j < 4; j++) acc[i][j] = (f32x4){0.f, 0.f, 0.f, 0.f};
    for (int kt = 0; kt < 7; kt++) {
        int ko = kt * 32;
        bf16x8 nbh[4], nbl[4];
        if (kt < 6) {
            #pragma unroll
            for (int nt = 0; nt < 4; nt++) {
                nbh[nt] = *(const bf16x8*)(bph + (long)nt * 16 * KPAD + ko + 32);
                nbl[nt] = *(const bf16x8*)(bpl + (long)nt * 16 * KPAD + ko + 32);
            }
        }
        #pragma unroll
        for (int mt = 0; mt < 4; mt++) {
            bf16x8 a_h = *(const bf16x8*)(aph + (long)mt * 16 * KPAD + ko);
            bf16x8 a_l = *(const bf16x8*)(apl + (long)mt * 16 * KPAD + ko);
            #pragma unroll
            for (int nt = 0; nt < 4; nt++) {
                acc[mt][nt] = __builtin_amdgcn_mfma_f32_16x16x32_bf16(a_h, cbh[nt], acc[mt][nt], 0, 0, 0);
                acc[mt][nt] = __builtin_amdgcn_mfma_f32_16x16x32_bf16(a_h, cbl[nt], acc[mt][nt], 0, 0, 0);
                acc[mt][nt] = __builtin_amdgcn_mfma_f32_16x16x32_bf16(a_l, cbh[nt], acc[mt][nt], 0, 0, 0);
            }
        }
        if (kt < 6) {
            #pragma unroll
            for (int nt = 0; nt < 4; nt++) { cbh[nt] = nbh[nt]; cbl[nt] = nbl[nt]; }
        }
    }
    int rowb = m0 + (l >> 4) * 4;
    #pragma unroll
    for (int mt = 0; mt < 4; mt++)
        #pragma unroll
        for (int r = 0; r < 4; r++) {
            long row = rowb + mt * 16 + r;
            #pragma unroll
            for (int nt = 0; nt < 4; nt++) {
                float v = acc[mt][nt][r];
                out[row * NENT + n0 + nt * 16 + lr] = 1.f / (1.f + __expf(-v));
            }
        }
}

extern "C" void kernel_launch(void* const* d_in, const int* in_sizes, int n_in,
                              void* d_out, int out_size, void* d_ws, size_t ws_size,
                              hipStream_t stream) {
    (void)in_sizes; (void)n_in; (void)out_size; (void)ws_size;
    const int* src      = (const int*)d_in[0];
    const int* dst      = (const int*)d_in[1];
    const int* aet      = (const int*)d_in[2];
    const int* e1       = (const int*)d_in[3];
    const int* rel      = (const int*)d_in[4];
    const int* entity   = (const int*)d_in[5];
    const float* emb_e  = (const float*)d_in[6];
    const float* embrel = (const float*)d_in[7];
    const float* w2     = (const float*)d_in[8];
    const float* b2     = (const float*)d_in[9];
    const float* alpha2 = (const float*)d_in[10];
    const float* w3     = (const float*)d_in[11];
    const float* b3     = (const float*)d_in[12];
    const float* alpha3 = (const float*)d_in[13];
    const float* bn3    = (const float*)d_in[14];
    const float* bn4    = (const float*)d_in[15];
    const float* bn0    = (const float*)d_in[16];
    const float* bn1    = (const float*)d_in[17];
    const float* bn2    = (const float*)d_in[18];
    const float* convw  = (const float*)d_in[19];
    const float* convb  = (const float*)d_in[20];
    const float* fcw    = (const float*)d_in[21];
    const float* fcb    = (const float*)d_in[22];
    float* out = (float*)d_out;
    float* ws = (float*)d_ws;

    float* feats  = ws;
    float* xbuf   = ws + 16000000;
    unsigned short* fcw_h = (unsigned short*)ws;
    unsigned short* fcw_l = (unsigned short*)(ws + 2670000);
    unsigned short* hc_h  = (unsigned short*)(ws + 9000000);
    unsigned short* hc_l  = (unsigned short*)(ws + 16000000);
    unsigned short* a1_h  = (unsigned short*)(ws + 24000000);
    unsigned short* a1_l  = (unsigned short*)(ws + 26560000);
    unsigned short* a2_h  = (unsigned short*)(ws + 29120000);
    unsigned short* a2_l  = (unsigned short*)(ws + 33600000);
    unsigned short* e_hi  = (unsigned short*)(ws + 29120000);  // reuses a2 (dead)
    unsigned short* e_lo  = (unsigned short*)(ws + 33600000);
    int*   deg    = (int*)(ws + 38100000);
    int*   rowptr = (int*)(ws + 38150000);
    int*   cursor = (int*)(ws + 38200000);
    int*   ssrc   = (int*)(ws + 38250000);
    float* sa1    = ws + 38800000;
    float* sa2    = ws + 39350000;
    float* fcsum  = ws + 39900000;
    float* hq     = ws + 40350000;
    unsigned short* h3_h = (unsigned short*)(ws + 41200000);
    unsigned short* h3_l = (unsigned short*)(ws + 41440000);
    unsigned short* w2t_h = (unsigned short*)(ws + 41700000);
    unsigned short* w2t_l = (unsigned short*)(ws + 41720000);
    unsigned short* w3t_h = (unsigned short*)(ws + 41740000);
    unsigned short* w3t_l = (unsigned short*)(ws + 41770000);

    // ---- CSR build (shared by both layers) ----
    hipMemsetAsync(deg, 0, NENT * 4, stream);
    k_hist<<<(NE + 255) / 256, 256, 0, stream>>>(dst, deg);
    k_scan<<<1, 1024, 0, stream>>>(deg, rowptr, cursor);
    k_scatter<<<(NE + 255) / 256, 256, 0, stream>>>(src, dst, aet, alpha2, alpha3,
                                                    cursor, ssrc, sa1, sa2);

    // ---- pack inputs ----
    k_pack_A1<<<(NENT * 16 + 255) / 256, 256, 0, stream>>>(emb_e, entity, a1_h, a1_l);
    k_pack_B<<<(208 * 128 + 255) / 256, 256, 0, stream>>>(w2, w2t_h, w2t_l, DIM0, 128);
    k_pack_B<<<(208 * KPAD + 255) / 256, 256, 0, stream>>>(w3, w3t_h, w3t_l, DIM, KPAD);

    // ---- GCN layer 1 (agg fuses bn3+tanh+bf16-pack) ----
    k_gemm_mfma<<<NENT / 64, 256, 0, stream>>>(a1_h, a1_l, w2t_h, w2t_l, feats, 128);
    k_agg_csr<1><<<NENT / 4, 256, 0, stream>>>(rowptr, ssrc, sa1, feats, nullptr,
                                               b2, bn3, a2_h, a2_l);

    // ---- GCN layer 2 (agg fuses bn4+tanh, writes xbuf fp32 + e planes) ----
    k_gemm_mfma<<<NENT / 64, 256, 0, stream>>>(a2_h, a2_l, w3t_h, w3t_l, feats, KPAD);
    k_agg_csr<2><<<NENT / 4, 256, 0, stream>>>(rowptr, ssrc, sa2, feats, xbuf,
                                               b3, bn4, e_hi, e_lo);

    // ---- decoder input + fcw pack ----
    k_hq<<<(BQ * 2 * DIM + 255) / 256, 256, 0, stream>>>(e1, rel, xbuf, embrel, bn0, hq);
    k_pack_fcw<<<(int)(((long)208 * (FCK / 8) + 255) / 256), 256, 0, stream>>>(fcw, fcw_h, fcw_l);

    // ---- conv + FC in 4 chunks of 512 rows ----
    hipMemsetAsync(fcsum, 0, (size_t)BQ * DIM * 4, stream);
    for (int ch = 0; ch < BQ / QCH; ch++) {
        int rowoff = ch * QCH;
        k_conv2<<<QCH, 256, 0, stream>>>(hq, convw, convb, bn1, hc_h, hc_l, rowoff);
        k_fc2<<<dim3(8, NSPLIT), 256, 0, stream>>>(hc_h, hc_l, fcw_h, fcw_l,
                                                   fcsum, rowoff);
    }
    k_fcreduce<<<(BQ * KPAD + 255) / 256, 256, 0, stream>>>(fcsum, fcb, bn2, h3_h, h3_l);

    // ---- final scoring ----
    k_mfma_final<<<dim3(8, NENT / 64), 256, 0, stream>>>(h3_h, h3_l, e_hi, e_lo, out);
}

// Round 9
// 744.769 us; speedup vs baseline: 6.1040x; 1.4488x over previous
//
#include <hip/hip_runtime.h>
#include <math.h>

#define NENT 40000
#define NTE  250000
#define NE   540000      // 2*NTE + NENT
#define DIM0 100
#define DIM  200
#define CCH  128
#define BQ   2048
#define FCK  25600       // CCH*DIM
#define EPSB 1e-5f
#define KPAD 224         // 200 padded to 7*32
#define NSPLIT 32        // split-K for FC
#define KSEG 800         // FCK / NSPLIT
#define QCH  512         // query rows per conv/fc chunk

typedef short bf16x8 __attribute__((ext_vector_type(8)));
typedef float f32x4 __attribute__((ext_vector_type(4)));
typedef unsigned short us8 __attribute__((ext_vector_type(8)));
typedef _Float16 h8 __attribute__((ext_vector_type(8)));
typedef _Float16 h4 __attribute__((ext_vector_type(4)));

__device__ __forceinline__ void split_bf16(float x, unsigned short& hi, unsigned short& lo) {
    unsigned u = __float_as_uint(x);
    unsigned r = (u + 0x7fffu + ((u >> 16) & 1u)) >> 16;
    hi = (unsigned short)r;
    float rem = x - __uint_as_float(r << 16);
    unsigned u2 = __float_as_uint(rem);
    unsigned r2 = (u2 + 0x7fffu + ((u2 >> 16) & 1u)) >> 16;
    lo = (unsigned short)r2;
}

#if defined(__has_builtin)
#if __has_builtin(__builtin_amdgcn_global_load_lds)
#define HAVE_GLL 1
#endif
#endif

__device__ __forceinline__ void gload_lds16(const void* g, void* l) {
#ifdef HAVE_GLL
    __builtin_amdgcn_global_load_lds((const __attribute__((address_space(1))) unsigned int*)g,
                                     (__attribute__((address_space(3))) unsigned int*)l, 16, 0, 0);
#else
    *(uint4*)l = *(const uint4*)g;
#endif
}

// =================== CSR build ===================
__global__ void k_hist(const int* __restrict__ dst, int* __restrict__ deg) {
    int e = blockIdx.x * 256 + threadIdx.x;
    if (e < NE) atomicAdd(&deg[dst[e]], 1);
}

__global__ __launch_bounds__(1024) void k_scan(const int* __restrict__ deg,
        int* __restrict__ rowptr, int* __restrict__ cursor) {
    __shared__ int sums[1024];
    int t = threadIdx.x;
    int base = t * 40;
    int local[40];
    int s = 0;
    #pragma unroll
    for (int i = 0; i < 40; i++) {
        int idx = base + i;
        int v = (idx < NENT) ? deg[idx] : 0;
        local[i] = s;
        s += v;
    }
    sums[t] = s;
    __syncthreads();
    #pragma unroll
    for (int off = 1; off < 1024; off <<= 1) {
        int add = (t >= off) ? sums[t - off] : 0;
        __syncthreads();
        sums[t] += add;
        __syncthreads();
    }
    int prefix = (t == 0) ? 0 : sums[t - 1];
    #pragma unroll
    for (int i = 0; i < 40; i++) {
        int idx = base + i;
        if (idx < NENT) {
            int p = prefix + local[i];
            rowptr[idx] = p;
            cursor[idx] = p;
        }
    }
    if (t == 1023) rowptr[NENT] = prefix + s;
}

__global__ void k_scatter(const int* __restrict__ src, const int* __restrict__ dst,
                          const int* __restrict__ aet, const float* __restrict__ a2t,
                          const float* __restrict__ a3t, int* __restrict__ cursor,
                          int* __restrict__ ssrc, float* __restrict__ sa1,
                          float* __restrict__ sa2) {
    int e = blockIdx.x * 256 + threadIdx.x;
    if (e >= NE) return;
    int tt = (e < NTE) ? e + NTE : (e < 2 * NTE ? e - NTE : e);
    int t0 = aet[e], t1 = aet[tt];
    int pos = atomicAdd(&cursor[dst[e]], 1);
    ssrc[pos] = src[e];
    sa1[pos] = a2t[t0] + a2t[t1];
    sa2[pos] = a3t[t0] + a3t[t1];
}

// =================== CSR aggregation, fused epilogues =========================
// EPI=1: bn+tanh -> bf16 hi/lo planes (layer-2 GEMM A operand).
// EPI=2: bn+tanh -> fp32 out32 AND fp16 e plane [row][KPAD] (zero pads).
template<int EPI>
__global__ __launch_bounds__(256) void k_agg_csr(const int* __restrict__ rowptr,
        const int* __restrict__ ssrc, const float* __restrict__ sa,
        const float* __restrict__ feats, float* __restrict__ out32,
        const float* __restrict__ bias, const float* __restrict__ bn,
        unsigned short* __restrict__ oh, unsigned short* __restrict__ ol,
        _Float16* __restrict__ eh) {
    int w = threadIdx.x >> 6, l = threadIdx.x & 63;
    int row = blockIdx.x * 4 + w;
    int beg = rowptr[row], end = rowptr[row + 1];
    bool act = l < 50;
    int col = l * 4;
    float sx = 0.f, sy = 0.f, sz = 0.f, sw = 0.f;
    int i = beg;
    for (; i + 2 <= end; i += 2) {
        int i0 = ssrc[i], i1 = ssrc[i + 1];
        float a0 = sa[i], a1 = sa[i + 1];
        if (act) {
            float4 v0 = *(const float4*)(feats + (long)i0 * DIM + col);
            float4 v1 = *(const float4*)(feats + (long)i1 * DIM + col);
            sx += a0 * v0.x + a1 * v1.x;
            sy += a0 * v0.y + a1 * v1.y;
            sz += a0 * v0.z + a1 * v1.z;
            sw += a0 * v0.w + a1 * v1.w;
        }
    }
    if (i < end) {
        int i0 = ssrc[i];
        float a0 = sa[i];
        if (act) {
            float4 v0 = *(const float4*)(feats + (long)i0 * DIM + col);
            sx += a0 * v0.x; sy += a0 * v0.y; sz += a0 * v0.z; sw += a0 * v0.w;
        }
    }
    if (act) {
        float4 g  = *(const float4*)(bn + col);
        float4 be = *(const float4*)(bn + DIM + col);
        float4 m  = *(const float4*)(bn + 2 * DIM + col);
        float4 v  = *(const float4*)(bn + 3 * DIM + col);
        float4 bb = *(const float4*)(bias + col);
        float4 t;
        t.x = tanhf(g.x * (sx + bb.x - m.x) * rsqrtf(v.x + EPSB) + be.x);
        t.y = tanhf(g.y * (sy + bb.y - m.y) * rsqrtf(v.y + EPSB) + be.y);
        t.z = tanhf(g.z * (sz + bb.z - m.z) * rsqrtf(v.z + EPSB) + be.z);
        t.w = tanhf(g.w * (sw + bb.w - m.w) * rsqrtf(v.w + EPSB) + be.w);
        if (EPI == 1) {
            ushort4 h4v, l4v;
            split_bf16(t.x, h4v.x, l4v.x);
            split_bf16(t.y, h4v.y, l4v.y);
            split_bf16(t.z, h4v.z, l4v.z);
            split_bf16(t.w, h4v.w, l4v.w);
            *(ushort4*)(oh + (long)row * KPAD + col) = h4v;
            *(ushort4*)(ol + (long)row * KPAD + col) = l4v;
        } else {
            *(float4*)(out32 + (long)row * DIM + col) = t;
            h4 e4 = { (_Float16)t.x, (_Float16)t.y, (_Float16)t.z, (_Float16)t.w };
            *(h4*)(eh + (long)row * KPAD + col) = e4;
        }
    } else if (l < 56) {
        // zero the k-pad [200,224): poison bytes can decode as NaN
        if (EPI == 1) {
            ushort4 z = make_ushort4(0, 0, 0, 0);
            *(ushort4*)(oh + (long)row * KPAD + col) = z;
            *(ushort4*)(ol + (long)row * KPAD + col) = z;
        } else {
            h4 z = { (_Float16)0.f, (_Float16)0.f, (_Float16)0.f, (_Float16)0.f };
            *(h4*)(eh + (long)row * KPAD + col) = z;
        }
    }
}

// =================== packing kernels ===================
__global__ void k_pack_A1(const float* __restrict__ emb, const int* __restrict__ ent,
                          unsigned short* __restrict__ ah, unsigned short* __restrict__ al) {
    long i = (long)blockIdx.x * 256 + threadIdx.x;
    if (i >= (long)NENT * 16) return;
    long m = i >> 4;
    int k0 = (int)(i & 15) << 3;
    us8 h = {0, 0, 0, 0, 0, 0, 0, 0};
    us8 lo = {0, 0, 0, 0, 0, 0, 0, 0};
    const float* p = emb + (long)ent[m] * DIM0 + k0;
    #pragma unroll
    for (int j = 0; j < 8; j++) {
        if (k0 + j < DIM0) {
            unsigned short hh, ll;
            split_bf16(p[j], hh, ll);
            h[j] = hh; lo[j] = ll;
        }
    }
    *(us8*)(ah + m * 128 + k0) = h;
    *(us8*)(al + m * 128 + k0) = lo;
}

__global__ void k_pack_B(const float* __restrict__ w, unsigned short* __restrict__ bh,
                         unsigned short* __restrict__ bl, int kin, int kpad) {
    int i = blockIdx.x * 256 + threadIdx.x;
    if (i >= 208 * kpad) return;
    int k = i % kpad, n = i / kpad;
    unsigned short hi = 0, lo = 0;
    if (k < kin && n < DIM) split_bf16(w[(long)k * DIM + n], hi, lo);
    bh[i] = hi; bl[i] = lo;
}

__global__ void k_hq(const int* __restrict__ e1, const int* __restrict__ rel,
                     const float* __restrict__ eall, const float* __restrict__ embrel,
                     const float* __restrict__ bn0, float* __restrict__ hq) {
    int i = blockIdx.x * 256 + threadIdx.x;
    if (i >= BQ * 2 * DIM) return;
    int d = i % DIM, c = (i / DIM) & 1, b = i / (2 * DIM);
    float val = (c == 0) ? eall[(long)e1[b] * DIM + d]
                         : embrel[(long)rel[b] * DIM + d];
    float g = bn0[c], be = bn0[2 + c], m = bn0[4 + c], v = bn0[6 + c];
    hq[i] = g * (val - m) * rsqrtf(v + EPSB) + be;
}

// fcw [200][25600] -> fp16 plane [208][FCK] (rows >=200 zero)
__global__ void k_pack_fcw(const float* __restrict__ w, _Float16* __restrict__ wf) {
    long i = (long)blockIdx.x * 256 + threadIdx.x;
    if (i >= (long)208 * (FCK / 8)) return;
    int n = (int)(i / (FCK / 8));
    long k0 = (i % (FCK / 8)) * 8;
    h8 h = {};
    if (n < DIM) {
        const float* p = w + (long)n * FCK + k0;
        #pragma unroll
        for (int j = 0; j < 8; j++) h[j] = (_Float16)p[j];
    }
    *(h8*)(wf + (long)n * FCK + k0) = h;
}

// =================== layer GEMM (direct-B, small K, bf16 hi/lo) ==============
__global__ __launch_bounds__(256) void k_gemm_mfma(
        const unsigned short* __restrict__ Ah, const unsigned short* __restrict__ Al,
        const unsigned short* __restrict__ Bh, const unsigned short* __restrict__ Bl,
        float* __restrict__ C, int kpad) {
    int w = threadIdx.x >> 6, l = threadIdx.x & 63;
    long m0 = (long)blockIdx.x * 64 + w * 16;
    long arow = m0 + (l & 15);
    int kg = (l >> 4) * 8;
    const unsigned short* ahp = Ah + arow * kpad + kg;
    const unsigned short* alp = Al + arow * kpad + kg;
    f32x4 acc[13];
    #pragma unroll
    for (int i = 0; i < 13; i++) acc[i] = (f32x4){0.f, 0.f, 0.f, 0.f};
    for (int kb = 0; kb < kpad; kb += 32) {
        bf16x8 a_h = *(const bf16x8*)(ahp + kb);
        bf16x8 a_l = *(const bf16x8*)(alp + kb);
        #pragma unroll
        for (int nt = 0; nt < 13; nt++) {
            long boff = (long)(nt * 16 + (l & 15)) * kpad + kb + kg;
            bf16x8 b_h = *(const bf16x8*)(Bh + boff);
            bf16x8 b_l = *(const bf16x8*)(Bl + boff);
            acc[nt] = __builtin_amdgcn_mfma_f32_16x16x32_bf16(a_h, b_h, acc[nt], 0, 0, 0);
            acc[nt] = __builtin_amdgcn_mfma_f32_16x16x32_bf16(a_h, b_l, acc[nt], 0, 0, 0);
            acc[nt] = __builtin_amdgcn_mfma_f32_16x16x32_bf16(a_l, b_h, acc[nt], 0, 0, 0);
        }
    }
    long rowo = m0 + (l >> 4) * 4;
    #pragma unroll
    for (int nt = 0; nt < 13; nt++) {
        int col = nt * 16 + (l & 15);
        if (col < DIM) {
            #pragma unroll
            for (int rr = 0; rr < 4; rr++)
                C[(rowo + rr) * DIM + col] = acc[nt][rr];
        }
    }
}

// =================== conv1d + bn1 + relu -> hconv fp16 plane (chunk) =========
__global__ __launch_bounds__(256) void k_conv2(const float* __restrict__ hq,
        const float* __restrict__ convw, const float* __restrict__ convb,
        const float* __restrict__ bn1, _Float16* __restrict__ hc, int rowoff) {
    __shared__ float hql[400];
    __shared__ float cwl[1280];
    __shared__ float scs[128], shs[128];
    int bl = blockIdx.x;
    int t = threadIdx.x;
    long b = rowoff + bl;
    for (int i = t; i < 400; i += 256) hql[i] = hq[b * 400 + i];
    for (int i = t; i < 1280; i += 256) cwl[i] = convw[i];
    if (t < 128) {
        float g = bn1[t], be = bn1[CCH + t], m = bn1[2 * CCH + t], v = bn1[3 * CCH + t];
        float s = g * rsqrtf(v + EPSB);
        scs[t] = s;
        shs[t] = be - m * s + s * convb[t];
    }
    __syncthreads();
    int c = t >> 1, half = t & 1, p0 = half * 100;
    float cw[10];
    #pragma unroll
    for (int k = 0; k < 10; k++) cw[k] = cwl[c * 10 + k];
    float sc_ = scs[c], sh_ = shs[c];
    long obase = (long)bl * FCK + c * DIM + p0;
    for (int pc = 0; pc < 100; pc += 4) {
        float w0[8], w1[8];
        #pragma unroll
        for (int j = 0; j < 8; j++) {
            int pp = p0 + pc - 2 + j;
            bool ok = (pp >= 0 && pp < DIM);
            w0[j] = ok ? hql[pp] : 0.f;
            w1[j] = ok ? hql[DIM + pp] : 0.f;
        }
        h4 o;
        #pragma unroll
        for (int j = 0; j < 4; j++) {
            float s = 0.f;
            #pragma unroll
            for (int k = 0; k < 5; k++) s += w0[j + k] * cw[k] + w1[j + k] * cw[5 + k];
            o[j] = (_Float16)fmaxf(sc_ * s + sh_, 0.f);
        }
        *(h4*)&hc[obase + pc] = o;
    }
}

// =================== FC GEMM: fp16, LDS-staged B, split-K, atomics ===========
// grid (8, NSPLIT), XCD swizzle: all 8 m-blocks of one split on ONE XCD.
__global__ __launch_bounds__(256) void k_fc2(
        const _Float16* __restrict__ A, const _Float16* __restrict__ B,
        float* __restrict__ fcsum, int rowoff) {
    __shared__ __align__(16) _Float16 ldsB[2][6656];   // 208 rows x 32 k
    int bid = blockIdx.y * 8 + blockIdx.x;
    int wsw = (bid & 7) * 32 + (bid >> 3);
    int mb = wsw & 7, split = wsw >> 3;
    int t = threadIdx.x;
    int w = t >> 6, l = t & 63;
    int kbase = split * KSEG;
    long arow = mb * 64 + w * 16 + (l & 15);
    int kg = (l >> 4) * 8;
    const _Float16* ahp = A + arow * FCK + kbase + kg;

    #pragma unroll
    for (int i = 0; i < 4; i++) {
        int u = i * 256 + t;
        if (u < 832) {
            int r = u >> 2, kc = u & 3;
            gload_lds16(B + (long)r * FCK + kbase + kc * 8, &ldsB[0][u * 8]);
        }
    }
    h8 aN = *(const h8*)(ahp);

    f32x4 acc[13];
    #pragma unroll
    for (int i = 0; i < 13; i++) acc[i] = (f32x4){0.f, 0.f, 0.f, 0.f};

    int buf = 0;
    for (int ks = 0; ks < 25; ks++) {
        __syncthreads();
        if (ks + 1 < 25) {
            int knext = kbase + (ks + 1) * 32;
            #pragma unroll
            for (int i = 0; i < 4; i++) {
                int u = i * 256 + t;
                if (u < 832) {
                    int r = u >> 2, kc = u & 3;
                    gload_lds16(B + (long)r * FCK + knext + kc * 8, &ldsB[buf ^ 1][u * 8]);
                }
            }
        }
        h8 aC = aN;
        if (ks + 1 < 25) aN = *(const h8*)(ahp + (ks + 1) * 32);
        const _Float16* b_base = &ldsB[buf][(l & 15) * 32 + kg];
        #pragma unroll
        for (int nt = 0; nt < 13; nt++) {
            h8 b = *(const h8*)(b_base + nt * 512);
            acc[nt] = __builtin_amdgcn_mfma_f32_16x16x32_f16(aC, b, acc[nt], 0, 0, 0);
        }
        buf ^= 1;
    }
    long rowo = rowoff + mb * 64 + w * 16 + (l >> 4) * 4;
    #pragma unroll
    for (int nt = 0; nt < 13; nt++) {
        int col = nt * 16 + (l & 15);
        if (col < DIM) {
            #pragma unroll
            for (int rr = 0; rr < 4; rr++)
                unsafeAtomicAdd(&fcsum[(rowo + rr) * DIM + col], acc[nt][rr]);
        }
    }
}

// =================== fcsum + bias + bn2 + relu -> h3 fp16 plane ===============
__global__ void k_fcreduce(const float* __restrict__ fcsum, const float* __restrict__ fcb,
                           const float* __restrict__ bn2, _Float16* __restrict__ h3) {
    int i = blockIdx.x * 256 + threadIdx.x;
    if (i >= BQ * KPAD) return;
    int j = i % KPAD, b = i / KPAD;
    _Float16 o = (_Float16)0.f;
    if (j < DIM) {
        float s = fcsum[(long)b * DIM + j] + fcb[j];
        float g = bn2[j], be = bn2[DIM + j], m = bn2[2 * DIM + j], v = bn2[3 * DIM + j];
        s = g * (s - m) * rsqrtf(v + EPSB) + be;
        o = (_Float16)fmaxf(s, 0.f);
    }
    h3[i] = o;
}

// =================== final: sigmoid(h3 @ e_all^T), fp16 single MFMA ==========
// grid (8, 625), XCD swizzle; wave = 64 rows x 64 cols; B reg double-buffer.
__global__ __launch_bounds__(256) void k_mfma_final(
        const _Float16* __restrict__ A, const _Float16* __restrict__ B,
        float* __restrict__ out) {
    int bid = blockIdx.y * 8 + blockIdx.x;
    int wsw = (bid & 7) * 625 + (bid >> 3);
    int mbb = wsw & 7, nbb = wsw >> 3;
    int w = threadIdx.x >> 6, l = threadIdx.x & 63;
    int n0 = nbb * 64;
    int m0 = mbb * 256 + w * 64;
    int lr = l & 15;
    int kb = (l >> 4) * 8;
    const _Float16* aph = A + (long)(m0 + lr) * KPAD + kb;
    const _Float16* bph = B + (long)(n0 + lr) * KPAD + kb;
    h8 cb[4];
    #pragma unroll
    for (int nt = 0; nt < 4; nt++)
        cb[nt] = *(const h8*)(bph + (long)nt * 16 * KPAD);
    f32x4 acc[4][4];
    #pragma unroll
    for (int i = 0; i < 4; i++)
        #pragma unroll
        for (int j = 0; j < 4; j++) acc[i][j] = (f32x4){0.f, 0.f, 0.f, 0.f};
    for (int kt = 0; kt < 7; kt++) {
        int ko = kt * 32;
        h8 nb[4];
        if (kt < 6) {
            #pragma unroll
            for (int nt = 0; nt < 4; nt++)
                nb[nt] = *(const h8*)(bph + (long)nt * 16 * KPAD + ko + 32);
        }
        #pragma unroll
        for (int mt = 0; mt < 4; mt++) {
            h8 a = *(const h8*)(aph + (long)mt * 16 * KPAD + ko);
            #pragma unroll
            for (int nt = 0; nt < 4; nt++)
                acc[mt][nt] = __builtin_amdgcn_mfma_f32_16x16x32_f16(a, cb[nt], acc[mt][nt], 0, 0, 0);
        }
        if (kt < 6) {
            #pragma unroll
            for (int nt = 0; nt < 4; nt++) cb[nt] = nb[nt];
        }
    }
    int rowb = m0 + (l >> 4) * 4;
    #pragma unroll
    for (int mt = 0; mt < 4; mt++)
        #pragma unroll
        for (int r = 0; r < 4; r++) {
            long row = rowb + mt * 16 + r;
            #pragma unroll
            for (int nt = 0; nt < 4; nt++) {
                float v = acc[mt][nt][r];
                out[row * NENT + n0 + nt * 16 + lr] = 1.f / (1.f + __expf(-v));
            }
        }
}

extern "C" void kernel_launch(void* const* d_in, const int* in_sizes, int n_in,
                              void* d_out, int out_size, void* d_ws, size_t ws_size,
                              hipStream_t stream) {
    (void)in_sizes; (void)n_in; (void)out_size; (void)ws_size;
    const int* src      = (const int*)d_in[0];
    const int* dst      = (const int*)d_in[1];
    const int* aet      = (const int*)d_in[2];
    const int* e1       = (const int*)d_in[3];
    const int* rel      = (const int*)d_in[4];
    const int* entity   = (const int*)d_in[5];
    const float* emb_e  = (const float*)d_in[6];
    const float* embrel = (const float*)d_in[7];
    const float* w2     = (const float*)d_in[8];
    const float* b2     = (const float*)d_in[9];
    const float* alpha2 = (const float*)d_in[10];
    const float* w3     = (const float*)d_in[11];
    const float* b3     = (const float*)d_in[12];
    const float* alpha3 = (const float*)d_in[13];
    const float* bn3    = (const float*)d_in[14];
    const float* bn4    = (const float*)d_in[15];
    const float* bn0    = (const float*)d_in[16];
    const float* bn1    = (const float*)d_in[17];
    const float* bn2    = (const float*)d_in[18];
    const float* convw  = (const float*)d_in[19];
    const float* convb  = (const float*)d_in[20];
    const float* fcw    = (const float*)d_in[21];
    const float* fcb    = (const float*)d_in[22];
    float* out = (float*)d_out;
    float* ws = (float*)d_ws;

    // ---- workspace layout (float offsets, lifetime-based reuse) ----
    // [0,8M)       feats (gemm out / agg src; dead after agg2) -> fcw fp16 [0,2.67M)
    // [9M,15.56M)  hc fp16 (chunk)
    // [16M,24M)    xbuf (agg2 fp32 out; dead after hq)
    // [24M,29.12M) a1 planes (dead after gemm1)
    // [29.12M,38.08M) a2 planes (dead after gemm2) -> e fp16 plane [29.12M,33.6M)
    // [38.1M,...)  CSR; fcsum; hq; h3 fp16; w2t/w3t planes
    float* feats  = ws;
    float* xbuf   = ws + 16000000;
    _Float16* fcw_f = (_Float16*)ws;
    _Float16* hc_f  = (_Float16*)(ws + 9000000);
    unsigned short* a1_h  = (unsigned short*)(ws + 24000000);
    unsigned short* a1_l  = (unsigned short*)(ws + 26560000);
    unsigned short* a2_h  = (unsigned short*)(ws + 29120000);
    unsigned short* a2_l  = (unsigned short*)(ws + 33600000);
    _Float16* e_f   = (_Float16*)(ws + 29120000);  // reuses a2 (dead after gemm2)
    int*   deg    = (int*)(ws + 38100000);
    int*   rowptr = (int*)(ws + 38150000);
    int*   cursor = (int*)(ws + 38200000);
    int*   ssrc   = (int*)(ws + 38250000);
    float* sa1    = ws + 38800000;
    float* sa2    = ws + 39350000;
    float* fcsum  = ws + 39900000;
    float* hq     = ws + 40350000;
    _Float16* h3_f = (_Float16*)(ws + 41200000);
    unsigned short* w2t_h = (unsigned short*)(ws + 41700000);
    unsigned short* w2t_l = (unsigned short*)(ws + 41720000);
    unsigned short* w3t_h = (unsigned short*)(ws + 41740000);
    unsigned short* w3t_l = (unsigned short*)(ws + 41770000);

    // ---- CSR build (shared by both layers) ----
    hipMemsetAsync(deg, 0, NENT * 4, stream);
    k_hist<<<(NE + 255) / 256, 256, 0, stream>>>(dst, deg);
    k_scan<<<1, 1024, 0, stream>>>(deg, rowptr, cursor);
    k_scatter<<<(NE + 255) / 256, 256, 0, stream>>>(src, dst, aet, alpha2, alpha3,
                                                    cursor, ssrc, sa1, sa2);

    // ---- pack inputs ----
    k_pack_A1<<<(NENT * 16 + 255) / 256, 256, 0, stream>>>(emb_e, entity, a1_h, a1_l);
    k_pack_B<<<(208 * 128 + 255) / 256, 256, 0, stream>>>(w2, w2t_h, w2t_l, DIM0, 128);
    k_pack_B<<<(208 * KPAD + 255) / 256, 256, 0, stream>>>(w3, w3t_h, w3t_l, DIM, KPAD);

    // ---- GCN layer 1 (agg fuses bn3+tanh+bf16-pack) ----
    k_gemm_mfma<<<NENT / 64, 256, 0, stream>>>(a1_h, a1_l, w2t_h, w2t_l, feats, 128);
    k_agg_csr<1><<<NENT / 4, 256, 0, stream>>>(rowptr, ssrc, sa1, feats, nullptr,
                                               b2, bn3, a2_h, a2_l, nullptr);

    // ---- GCN layer 2 (agg fuses bn4+tanh, writes xbuf fp32 + e fp16 plane) ----
    k_gemm_mfma<<<NENT / 64, 256, 0, stream>>>(a2_h, a2_l, w3t_h, w3t_l, feats, KPAD);
    k_agg_csr<2><<<NENT / 4, 256, 0, stream>>>(rowptr, ssrc, sa2, feats, xbuf,
                                               b3, bn4, nullptr, nullptr, e_f);

    // ---- decoder input + fcw pack ----
    k_hq<<<(BQ * 2 * DIM + 255) / 256, 256, 0, stream>>>(e1, rel, xbuf, embrel, bn0, hq);
    k_pack_fcw<<<(int)(((long)208 * (FCK / 8) + 255) / 256), 256, 0, stream>>>(fcw, fcw_f);

    // ---- conv + FC in 4 chunks of 512 rows ----
    hipMemsetAsync(fcsum, 0, (size_t)BQ * DIM * 4, stream);
    for (int ch = 0; ch < BQ / QCH; ch++) {
        int rowoff = ch * QCH;
        k_conv2<<<QCH, 256, 0, stream>>>(hq, convw, convb, bn1, hc_f, rowoff);
        k_fc2<<<dim3(8, NSPLIT), 256, 0, stream>>>(hc_f, fcw_f, fcsum, rowoff);
    }
    k_fcreduce<<<(BQ * KPAD + 255) / 256, 256, 0, stream>>>(fcsum, fcb, bn2, h3_f);

    // ---- final scoring ----
    k_mfma_final<<<dim3(8, NENT / 64), 256, 0, stream>>>(h3_f, e_f, out);
}

// Round 10
// 651.841 us; speedup vs baseline: 6.9742x; 1.1426x over previous
//
#include <hip/hip_runtime.h>
#include <math.h>

#define NENT 40000
#define NTE  250000
#define NE   540000      // 2*NTE + NENT
#define DIM0 100
#define DIM  200
#define CCH  128
#define BQ   2048
#define FCK  25600       // CCH*DIM
#define EPSB 1e-5f
#define KPAD 224         // 200 padded to 7*32
#define NSPLIT 32        // split-K for FC
#define KSEG 800         // FCK / NSPLIT
#define QCH  1024        // query rows per conv/fc chunk

typedef short bf16x8 __attribute__((ext_vector_type(8)));
typedef float f32x4 __attribute__((ext_vector_type(4)));
typedef unsigned short us8 __attribute__((ext_vector_type(8)));
typedef _Float16 h8 __attribute__((ext_vector_type(8)));
typedef _Float16 h4 __attribute__((ext_vector_type(4)));

__device__ __forceinline__ void split_bf16(float x, unsigned short& hi, unsigned short& lo) {
    unsigned u = __float_as_uint(x);
    unsigned r = (u + 0x7fffu + ((u >> 16) & 1u)) >> 16;
    hi = (unsigned short)r;
    float rem = x - __uint_as_float(r << 16);
    unsigned u2 = __float_as_uint(rem);
    unsigned r2 = (u2 + 0x7fffu + ((u2 >> 16) & 1u)) >> 16;
    lo = (unsigned short)r2;
}

#if defined(__has_builtin)
#if __has_builtin(__builtin_amdgcn_global_load_lds)
#define HAVE_GLL 1
#endif
#endif

__device__ __forceinline__ void gload_lds16(const void* g, void* l) {
#ifdef HAVE_GLL
    __builtin_amdgcn_global_load_lds((const __attribute__((address_space(1))) unsigned int*)g,
                                     (__attribute__((address_space(3))) unsigned int*)l, 16, 0, 0);
#else
    *(uint4*)l = *(const uint4*)g;
#endif
}

// =================== CSR build ===================
__global__ void k_hist(const int* __restrict__ dst, int* __restrict__ deg) {
    int e = blockIdx.x * 256 + threadIdx.x;
    if (e < NE) atomicAdd(&deg[dst[e]], 1);
}

__global__ __launch_bounds__(1024) void k_scan(const int* __restrict__ deg,
        int* __restrict__ rowptr, int* __restrict__ cursor) {
    __shared__ int sums[1024];
    int t = threadIdx.x;
    int base = t * 40;
    int local[40];
    int s = 0;
    #pragma unroll
    for (int i = 0; i < 40; i++) {
        int idx = base + i;
        int v = (idx < NENT) ? deg[idx] : 0;
        local[i] = s;
        s += v;
    }
    sums[t] = s;
    __syncthreads();
    #pragma unroll
    for (int off = 1; off < 1024; off <<= 1) {
        int add = (t >= off) ? sums[t - off] : 0;
        __syncthreads();
        sums[t] += add;
        __syncthreads();
    }
    int prefix = (t == 0) ? 0 : sums[t - 1];
    #pragma unroll
    for (int i = 0; i < 40; i++) {
        int idx = base + i;
        if (idx < NENT) {
            int p = prefix + local[i];
            rowptr[idx] = p;
            cursor[idx] = p;
        }
    }
    if (t == 1023) rowptr[NENT] = prefix + s;
}

__global__ void k_scatter(const int* __restrict__ src, const int* __restrict__ dst,
                          const int* __restrict__ aet, const float* __restrict__ a2t,
                          const float* __restrict__ a3t, int* __restrict__ cursor,
                          int* __restrict__ ssrc, float* __restrict__ sa1,
                          float* __restrict__ sa2) {
    int e = blockIdx.x * 256 + threadIdx.x;
    if (e >= NE) return;
    int tt = (e < NTE) ? e + NTE : (e < 2 * NTE ? e - NTE : e);
    int t0 = aet[e], t1 = aet[tt];
    int pos = atomicAdd(&cursor[dst[e]], 1);
    ssrc[pos] = src[e];
    sa1[pos] = a2t[t0] + a2t[t1];
    sa2[pos] = a3t[t0] + a3t[t1];
}

// =================== CSR aggregation (fp16 feats), fused epilogues ===========
// EPI=1: bn+tanh -> bf16 hi/lo planes (layer-2 GEMM A operand).
// EPI=2: bn+tanh -> fp32 out32 AND fp16 e plane [row][KPAD] (zero pads).
template<int EPI>
__global__ __launch_bounds__(256) void k_agg_csr(const int* __restrict__ rowptr,
        const int* __restrict__ ssrc, const float* __restrict__ sa,
        const _Float16* __restrict__ feats, float* __restrict__ out32,
        const float* __restrict__ bias, const float* __restrict__ bn,
        unsigned short* __restrict__ oh, unsigned short* __restrict__ ol,
        _Float16* __restrict__ eh) {
    int w = threadIdx.x >> 6, l = threadIdx.x & 63;
    int row = blockIdx.x * 4 + w;
    int beg = rowptr[row], end = rowptr[row + 1];
    bool act = l < 50;
    int col = l * 4;
    float sx = 0.f, sy = 0.f, sz = 0.f, sw = 0.f;
    int i = beg;
    for (; i + 2 <= end; i += 2) {
        int i0 = ssrc[i], i1 = ssrc[i + 1];
        float a0 = sa[i], a1 = sa[i + 1];
        if (act) {
            h4 v0 = *(const h4*)(feats + (long)i0 * DIM + col);
            h4 v1 = *(const h4*)(feats + (long)i1 * DIM + col);
            sx += a0 * (float)v0[0] + a1 * (float)v1[0];
            sy += a0 * (float)v0[1] + a1 * (float)v1[1];
            sz += a0 * (float)v0[2] + a1 * (float)v1[2];
            sw += a0 * (float)v0[3] + a1 * (float)v1[3];
        }
    }
    if (i < end) {
        int i0 = ssrc[i];
        float a0 = sa[i];
        if (act) {
            h4 v0 = *(const h4*)(feats + (long)i0 * DIM + col);
            sx += a0 * (float)v0[0]; sy += a0 * (float)v0[1];
            sz += a0 * (float)v0[2]; sw += a0 * (float)v0[3];
        }
    }
    if (act) {
        float4 g  = *(const float4*)(bn + col);
        float4 be = *(const float4*)(bn + DIM + col);
        float4 m  = *(const float4*)(bn + 2 * DIM + col);
        float4 v  = *(const float4*)(bn + 3 * DIM + col);
        float4 bb = *(const float4*)(bias + col);
        float4 t;
        t.x = tanhf(g.x * (sx + bb.x - m.x) * rsqrtf(v.x + EPSB) + be.x);
        t.y = tanhf(g.y * (sy + bb.y - m.y) * rsqrtf(v.y + EPSB) + be.y);
        t.z = tanhf(g.z * (sz + bb.z - m.z) * rsqrtf(v.z + EPSB) + be.z);
        t.w = tanhf(g.w * (sw + bb.w - m.w) * rsqrtf(v.w + EPSB) + be.w);
        if (EPI == 1) {
            ushort4 h4v, l4v;
            split_bf16(t.x, h4v.x, l4v.x);
            split_bf16(t.y, h4v.y, l4v.y);
            split_bf16(t.z, h4v.z, l4v.z);
            split_bf16(t.w, h4v.w, l4v.w);
            *(ushort4*)(oh + (long)row * KPAD + col) = h4v;
            *(ushort4*)(ol + (long)row * KPAD + col) = l4v;
        } else {
            *(float4*)(out32 + (long)row * DIM + col) = t;
            h4 e4 = { (_Float16)t.x, (_Float16)t.y, (_Float16)t.z, (_Float16)t.w };
            *(h4*)(eh + (long)row * KPAD + col) = e4;
        }
    } else if (l < 56) {
        // zero the k-pad [200,224): poison bytes can decode as NaN
        if (EPI == 1) {
            ushort4 z = make_ushort4(0, 0, 0, 0);
            *(ushort4*)(oh + (long)row * KPAD + col) = z;
            *(ushort4*)(ol + (long)row * KPAD + col) = z;
        } else {
            h4 z = { (_Float16)0.f, (_Float16)0.f, (_Float16)0.f, (_Float16)0.f };
            *(h4*)(eh + (long)row * KPAD + col) = z;
        }
    }
}

// =================== packing kernels ===================
__global__ void k_pack_A1(const float* __restrict__ emb, const int* __restrict__ ent,
                          unsigned short* __restrict__ ah, unsigned short* __restrict__ al) {
    long i = (long)blockIdx.x * 256 + threadIdx.x;
    if (i >= (long)NENT * 16) return;
    long m = i >> 4;
    int k0 = (int)(i & 15) << 3;
    us8 h = {0, 0, 0, 0, 0, 0, 0, 0};
    us8 lo = {0, 0, 0, 0, 0, 0, 0, 0};
    const float* p = emb + (long)ent[m] * DIM0 + k0;
    #pragma unroll
    for (int j = 0; j < 8; j++) {
        if (k0 + j < DIM0) {
            unsigned short hh, ll;
            split_bf16(p[j], hh, ll);
            h[j] = hh; lo[j] = ll;
        }
    }
    *(us8*)(ah + m * 128 + k0) = h;
    *(us8*)(al + m * 128 + k0) = lo;
}

__global__ void k_pack_B(const float* __restrict__ w, unsigned short* __restrict__ bh,
                         unsigned short* __restrict__ bl, int kin, int kpad) {
    int i = blockIdx.x * 256 + threadIdx.x;
    if (i >= 208 * kpad) return;
    int k = i % kpad, n = i / kpad;
    unsigned short hi = 0, lo = 0;
    if (k < kin && n < DIM) split_bf16(w[(long)k * DIM + n], hi, lo);
    bh[i] = hi; bl[i] = lo;
}

__global__ void k_hq(const int* __restrict__ e1, const int* __restrict__ rel,
                     const float* __restrict__ eall, const float* __restrict__ embrel,
                     const float* __restrict__ bn0, float* __restrict__ hq) {
    int i = blockIdx.x * 256 + threadIdx.x;
    if (i >= BQ * 2 * DIM) return;
    int d = i % DIM, c = (i / DIM) & 1, b = i / (2 * DIM);
    float val = (c == 0) ? eall[(long)e1[b] * DIM + d]
                         : embrel[(long)rel[b] * DIM + d];
    float g = bn0[c], be = bn0[2 + c], m = bn0[4 + c], v = bn0[6 + c];
    hq[i] = g * (val - m) * rsqrtf(v + EPSB) + be;
}

// fcw [200][25600] -> fp16 plane [208][FCK] (rows >=200 zero)
__global__ void k_pack_fcw(const float* __restrict__ w, _Float16* __restrict__ wf) {
    long i = (long)blockIdx.x * 256 + threadIdx.x;
    if (i >= (long)208 * (FCK / 8)) return;
    int n = (int)(i / (FCK / 8));
    long k0 = (i % (FCK / 8)) * 8;
    h8 h = {};
    if (n < DIM) {
        const float* p = w + (long)n * FCK + k0;
        #pragma unroll
        for (int j = 0; j < 8; j++) h[j] = (_Float16)p[j];
    }
    *(h8*)(wf + (long)n * FCK + k0) = h;
}

// =================== layer GEMM (direct-B, small K, bf16 hi/lo, fp16 out) ====
__global__ __launch_bounds__(256) void k_gemm_mfma(
        const unsigned short* __restrict__ Ah, const unsigned short* __restrict__ Al,
        const unsigned short* __restrict__ Bh, const unsigned short* __restrict__ Bl,
        _Float16* __restrict__ C, int kpad) {
    int w = threadIdx.x >> 6, l = threadIdx.x & 63;
    long m0 = (long)blockIdx.x * 64 + w * 16;
    long arow = m0 + (l & 15);
    int kg = (l >> 4) * 8;
    const unsigned short* ahp = Ah + arow * kpad + kg;
    const unsigned short* alp = Al + arow * kpad + kg;
    f32x4 acc[13];
    #pragma unroll
    for (int i = 0; i < 13; i++) acc[i] = (f32x4){0.f, 0.f, 0.f, 0.f};
    for (int kb = 0; kb < kpad; kb += 32) {
        bf16x8 a_h = *(const bf16x8*)(ahp + kb);
        bf16x8 a_l = *(const bf16x8*)(alp + kb);
        #pragma unroll
        for (int nt = 0; nt < 13; nt++) {
            long boff = (long)(nt * 16 + (l & 15)) * kpad + kb + kg;
            bf16x8 b_h = *(const bf16x8*)(Bh + boff);
            bf16x8 b_l = *(const bf16x8*)(Bl + boff);
            acc[nt] = __builtin_amdgcn_mfma_f32_16x16x32_bf16(a_h, b_h, acc[nt], 0, 0, 0);
            acc[nt] = __builtin_amdgcn_mfma_f32_16x16x32_bf16(a_h, b_l, acc[nt], 0, 0, 0);
            acc[nt] = __builtin_amdgcn_mfma_f32_16x16x32_bf16(a_l, b_h, acc[nt], 0, 0, 0);
        }
    }
    long rowo = m0 + (l >> 4) * 4;
    #pragma unroll
    for (int nt = 0; nt < 13; nt++) {
        int col = nt * 16 + (l & 15);
        if (col < DIM) {
            #pragma unroll
            for (int rr = 0; rr < 4; rr++)
                C[(rowo + rr) * DIM + col] = (_Float16)acc[nt][rr];
        }
    }
}

// =================== conv1d + bn1 + relu -> hconv fp16 plane (chunk) =========
__global__ __launch_bounds__(256) void k_conv2(const float* __restrict__ hq,
        const float* __restrict__ convw, const float* __restrict__ convb,
        const float* __restrict__ bn1, _Float16* __restrict__ hc, int rowoff) {
    __shared__ float hql[400];
    __shared__ float cwl[1280];
    __shared__ float scs[128], shs[128];
    int bl = blockIdx.x;
    int t = threadIdx.x;
    long b = rowoff + bl;
    for (int i = t; i < 400; i += 256) hql[i] = hq[b * 400 + i];
    for (int i = t; i < 1280; i += 256) cwl[i] = convw[i];
    if (t < 128) {
        float g = bn1[t], be = bn1[CCH + t], m = bn1[2 * CCH + t], v = bn1[3 * CCH + t];
        float s = g * rsqrtf(v + EPSB);
        scs[t] = s;
        shs[t] = be - m * s + s * convb[t];
    }
    __syncthreads();
    int c = t >> 1, half = t & 1, p0 = half * 100;
    float cw[10];
    #pragma unroll
    for (int k = 0; k < 10; k++) cw[k] = cwl[c * 10 + k];
    float sc_ = scs[c], sh_ = shs[c];
    long obase = (long)bl * FCK + c * DIM + p0;
    for (int pc = 0; pc < 100; pc += 4) {
        float w0[8], w1[8];
        #pragma unroll
        for (int j = 0; j < 8; j++) {
            int pp = p0 + pc - 2 + j;
            bool ok = (pp >= 0 && pp < DIM);
            w0[j] = ok ? hql[pp] : 0.f;
            w1[j] = ok ? hql[DIM + pp] : 0.f;
        }
        h4 o;
        #pragma unroll
        for (int j = 0; j < 4; j++) {
            float s = 0.f;
            #pragma unroll
            for (int k = 0; k < 5; k++) s += w0[j + k] * cw[k] + w1[j + k] * cw[5 + k];
            o[j] = (_Float16)fmaxf(sc_ * s + sh_, 0.f);
        }
        *(h4*)&hc[obase + pc] = o;
    }
}

// =================== FC GEMM: fp16, LDS-staged B, split-K, atomics ===========
// grid (8, 64): 16 m-blocks x 32 splits, XCD swizzle (split-major per XCD).
__global__ __launch_bounds__(256) void k_fc2(
        const _Float16* __restrict__ A, const _Float16* __restrict__ B,
        float* __restrict__ fcsum, int rowoff) {
    __shared__ __align__(16) _Float16 ldsB[2][6656];   // 208 rows x 32 k
    int bid = blockIdx.y * 8 + blockIdx.x;
    int wsw = (bid & 7) * 64 + (bid >> 3);
    int mb = wsw & 15, split = wsw >> 4;
    int t = threadIdx.x;
    int w = t >> 6, l = t & 63;
    int kbase = split * KSEG;
    long arow = mb * 64 + w * 16 + (l & 15);
    int kg = (l >> 4) * 8;
    const _Float16* ahp = A + arow * FCK + kbase + kg;

    #pragma unroll
    for (int i = 0; i < 4; i++) {
        int u = i * 256 + t;
        if (u < 832) {
            int r = u >> 2, kc = u & 3;
            gload_lds16(B + (long)r * FCK + kbase + kc * 8, &ldsB[0][u * 8]);
        }
    }
    h8 aN = *(const h8*)(ahp);

    f32x4 acc[13];
    #pragma unroll
    for (int i = 0; i < 13; i++) acc[i] = (f32x4){0.f, 0.f, 0.f, 0.f};

    int buf = 0;
    for (int ks = 0; ks < 25; ks++) {
        __syncthreads();
        if (ks + 1 < 25) {
            int knext = kbase + (ks + 1) * 32;
            #pragma unroll
            for (int i = 0; i < 4; i++) {
                int u = i * 256 + t;
                if (u < 832) {
                    int r = u >> 2, kc = u & 3;
                    gload_lds16(B + (long)r * FCK + knext + kc * 8, &ldsB[buf ^ 1][u * 8]);
                }
            }
        }
        h8 aC = aN;
        if (ks + 1 < 25) aN = *(const h8*)(ahp + (ks + 1) * 32);
        const _Float16* b_base = &ldsB[buf][(l & 15) * 32 + kg];
        #pragma unroll
        for (int nt = 0; nt < 13; nt++) {
            h8 b = *(const h8*)(b_base + nt * 512);
            acc[nt] = __builtin_amdgcn_mfma_f32_16x16x32_f16(aC, b, acc[nt], 0, 0, 0);
        }
        buf ^= 1;
    }
    long rowo = rowoff + mb * 64 + w * 16 + (l >> 4) * 4;
    #pragma unroll
    for (int nt = 0; nt < 13; nt++) {
        int col = nt * 16 + (l & 15);
        if (col < DIM) {
            #pragma unroll
            for (int rr = 0; rr < 4; rr++)
                unsafeAtomicAdd(&fcsum[(rowo + rr) * DIM + col], acc[nt][rr]);
        }
    }
}

// =================== fcsum + bias + bn2 + relu -> h3 fp16 plane ===============
__global__ void k_fcreduce(const float* __restrict__ fcsum, const float* __restrict__ fcb,
                           const float* __restrict__ bn2, _Float16* __restrict__ h3) {
    int i = blockIdx.x * 256 + threadIdx.x;
    if (i >= BQ * KPAD) return;
    int j = i % KPAD, b = i / KPAD;
    _Float16 o = (_Float16)0.f;
    if (j < DIM) {
        float s = fcsum[(long)b * DIM + j] + fcb[j];
        float g = bn2[j], be = bn2[DIM + j], m = bn2[2 * DIM + j], v = bn2[3 * DIM + j];
        s = g * (s - m) * rsqrtf(v + EPSB) + be;
        o = (_Float16)fmaxf(s, 0.f);
    }
    h3[i] = o;
}

// =================== final: sigmoid(h3 @ e_all^T), fp16 single MFMA ==========
// grid (8, 625), XCD swizzle; wave = 64 rows x 64 cols; B reg double-buffer.
__global__ __launch_bounds__(256) void k_mfma_final(
        const _Float16* __restrict__ A, const _Float16* __restrict__ B,
        float* __restrict__ out) {
    int bid = blockIdx.y * 8 + blockIdx.x;
    int wsw = (bid & 7) * 625 + (bid >> 3);
    int mbb = wsw & 7, nbb = wsw >> 3;
    int w = threadIdx.x >> 6, l = threadIdx.x & 63;
    int n0 = nbb * 64;
    int m0 = mbb * 256 + w * 64;
    int lr = l & 15;
    int kb = (l >> 4) * 8;
    const _Float16* aph = A + (long)(m0 + lr) * KPAD + kb;
    const _Float16* bph = B + (long)(n0 + lr) * KPAD + kb;
    h8 cb[4];
    #pragma unroll
    for (int nt = 0; nt < 4; nt++)
        cb[nt] = *(const h8*)(bph + (long)nt * 16 * KPAD);
    f32x4 acc[4][4];
    #pragma unroll
    for (int i = 0; i < 4; i++)
        #pragma unroll
        for (int j = 0; j < 4; j++) acc[i][j] = (f32x4){0.f, 0.f, 0.f, 0.f};
    for (int kt = 0; kt < 7; kt++) {
        int ko = kt * 32;
        h8 nb[4];
        if (kt < 6) {
            #pragma unroll
            for (int nt = 0; nt < 4; nt++)
                nb[nt] = *(const h8*)(bph + (long)nt * 16 * KPAD + ko + 32);
        }
        #pragma unroll
        for (int mt = 0; mt < 4; mt++) {
            h8 a = *(const h8*)(aph + (long)mt * 16 * KPAD + ko);
            #pragma unroll
            for (int nt = 0; nt < 4; nt++)
                acc[mt][nt] = __builtin_amdgcn_mfma_f32_16x16x32_f16(a, cb[nt], acc[mt][nt], 0, 0, 0);
        }
        if (kt < 6) {
            #pragma unroll
            for (int nt = 0; nt < 4; nt++) cb[nt] = nb[nt];
        }
    }
    int rowb = m0 + (l >> 4) * 4;
    #pragma unroll
    for (int mt = 0; mt < 4; mt++)
        #pragma unroll
        for (int r = 0; r < 4; r++) {
            long row = rowb + mt * 16 + r;
            #pragma unroll
            for (int nt = 0; nt < 4; nt++) {
                float v = acc[mt][nt][r];
                // sigmoid with fast rcp (v_rcp_f32, ~1ulp): avoids precise-div seq
                float e = __expf(-v);
                out[row * NENT + n0 + nt * 16 + lr] = __builtin_amdgcn_rcpf(1.f + e);
            }
        }
}

extern "C" void kernel_launch(void* const* d_in, const int* in_sizes, int n_in,
                              void* d_out, int out_size, void* d_ws, size_t ws_size,
                              hipStream_t stream) {
    (void)in_sizes; (void)n_in; (void)out_size; (void)ws_size;
    const int* src      = (const int*)d_in[0];
    const int* dst      = (const int*)d_in[1];
    const int* aet      = (const int*)d_in[2];
    const int* e1       = (const int*)d_in[3];
    const int* rel      = (const int*)d_in[4];
    const int* entity   = (const int*)d_in[5];
    const float* emb_e  = (const float*)d_in[6];
    const float* embrel = (const float*)d_in[7];
    const float* w2     = (const float*)d_in[8];
    const float* b2     = (const float*)d_in[9];
    const float* alpha2 = (const float*)d_in[10];
    const float* w3     = (const float*)d_in[11];
    const float* b3     = (const float*)d_in[12];
    const float* alpha3 = (const float*)d_in[13];
    const float* bn3    = (const float*)d_in[14];
    const float* bn4    = (const float*)d_in[15];
    const float* bn0    = (const float*)d_in[16];
    const float* bn1    = (const float*)d_in[17];
    const float* bn2    = (const float*)d_in[18];
    const float* convw  = (const float*)d_in[19];
    const float* convb  = (const float*)d_in[20];
    const float* fcw    = (const float*)d_in[21];
    const float* fcb    = (const float*)d_in[22];
    float* out = (float*)d_out;
    float* ws = (float*)d_ws;

    // ---- workspace layout (float offsets, lifetime-based reuse; <=167MB) ----
    // [0,4M)       feats fp16 [40000][200] (gemm out / agg src; dead after agg2)
    // [4.5M,7.17M) fcw fp16 plane [208][25600]
    // [16M,24M)    xbuf fp32 (agg2 out; dead after hq)
    // [16M,29.12M) hc fp16 chunk [1024][25600] (written after hq; over xbuf+a1)
    // [24M,29.12M) a1 planes (dead after gemm1)
    // [29.12M,38.08M) a2 planes (dead after gemm2) -> e fp16 plane [29.12M,33.6M)
    // [38.1M,...)  CSR; fcsum; hq; h3 fp16; w2t/w3t planes
    _Float16* feats_f = (_Float16*)ws;
    _Float16* fcw_f   = (_Float16*)(ws + 4500000);
    float* xbuf   = ws + 16000000;
    _Float16* hc_f  = (_Float16*)(ws + 16000000);
    unsigned short* a1_h  = (unsigned short*)(ws + 24000000);
    unsigned short* a1_l  = (unsigned short*)(ws + 26560000);
    unsigned short* a2_h  = (unsigned short*)(ws + 29120000);
    unsigned short* a2_l  = (unsigned short*)(ws + 33600000);
    _Float16* e_f   = (_Float16*)(ws + 29120000);  // reuses a2 (dead after gemm2)
    int*   deg    = (int*)(ws + 38100000);
    int*   rowptr = (int*)(ws + 38150000);
    int*   cursor = (int*)(ws + 38200000);
    int*   ssrc   = (int*)(ws + 38250000);
    float* sa1    = ws + 38800000;
    float* sa2    = ws + 39350000;
    float* fcsum  = ws + 39900000;
    float* hq     = ws + 40350000;
    _Float16* h3_f = (_Float16*)(ws + 41200000);
    unsigned short* w2t_h = (unsigned short*)(ws + 41700000);
    unsigned short* w2t_l = (unsigned short*)(ws + 41720000);
    unsigned short* w3t_h = (unsigned short*)(ws + 41740000);
    unsigned short* w3t_l = (unsigned short*)(ws + 41770000);

    // ---- CSR build (shared by both layers) ----
    hipMemsetAsync(deg, 0, NENT * 4, stream);
    k_hist<<<(NE + 255) / 256, 256, 0, stream>>>(dst, deg);
    k_scan<<<1, 1024, 0, stream>>>(deg, rowptr, cursor);
    k_scatter<<<(NE + 255) / 256, 256, 0, stream>>>(src, dst, aet, alpha2, alpha3,
                                                    cursor, ssrc, sa1, sa2);

    // ---- pack inputs ----
    k_pack_A1<<<(NENT * 16 + 255) / 256, 256, 0, stream>>>(emb_e, entity, a1_h, a1_l);
    k_pack_B<<<(208 * 128 + 255) / 256, 256, 0, stream>>>(w2, w2t_h, w2t_l, DIM0, 128);
    k_pack_B<<<(208 * KPAD + 255) / 256, 256, 0, stream>>>(w3, w3t_h, w3t_l, DIM, KPAD);

    // ---- GCN layer 1 (agg fuses bn3+tanh+bf16-pack) ----
    k_gemm_mfma<<<NENT / 64, 256, 0, stream>>>(a1_h, a1_l, w2t_h, w2t_l, feats_f, 128);
    k_agg_csr<1><<<NENT / 4, 256, 0, stream>>>(rowptr, ssrc, sa1, feats_f, nullptr,
                                               b2, bn3, a2_h, a2_l, nullptr);

    // ---- GCN layer 2 (agg fuses bn4+tanh, writes xbuf fp32 + e fp16 plane) ----
    k_gemm_mfma<<<NENT / 64, 256, 0, stream>>>(a2_h, a2_l, w3t_h, w3t_l, feats_f, KPAD);
    k_agg_csr<2><<<NENT / 4, 256, 0, stream>>>(rowptr, ssrc, sa2, feats_f, xbuf,
                                               b3, bn4, nullptr, nullptr, e_f);

    // ---- decoder input + fcw pack ----
    k_hq<<<(BQ * 2 * DIM + 255) / 256, 256, 0, stream>>>(e1, rel, xbuf, embrel, bn0, hq);
    k_pack_fcw<<<(int)(((long)208 * (FCK / 8) + 255) / 256), 256, 0, stream>>>(fcw, fcw_f);

    // ---- conv + FC in 2 chunks of 1024 rows ----
    hipMemsetAsync(fcsum, 0, (size_t)BQ * DIM * 4, stream);
    for (int ch = 0; ch < BQ / QCH; ch++) {
        int rowoff = ch * QCH;
        k_conv2<<<QCH, 256, 0, stream>>>(hq, convw, convb, bn1, hc_f, rowoff);
        k_fc2<<<dim3(8, 64), 256, 0, stream>>>(hc_f, fcw_f, fcsum, rowoff);
    }
    k_fcreduce<<<(BQ * KPAD + 255) / 256, 256, 0, stream>>>(fcsum, fcb, bn2, h3_f);

    // ---- final scoring ----
    k_mfma_final<<<dim3(8, NENT / 64), 256, 0, stream>>>(h3_f, e_f, out);
}

// Round 11
// 635.209 us; speedup vs baseline: 7.1568x; 1.0262x over previous
//
#include <hip/hip_runtime.h>
#include <math.h>

#define NENT 40000
#define NTE  250000
#define NE   540000      // 2*NTE + NENT
#define DIM0 100
#define DIM  200
#define CCH  128
#define BQ   2048
#define FCK  25600       // CCH*DIM
#define EPSB 1e-5f
#define KPAD 224         // 200 padded to 7*32
#define NSPLIT 32        // split-K for FC
#define KSEG 800         // FCK / NSPLIT
#define QCH  1024        // query rows per conv/fc chunk

typedef short bf16x8 __attribute__((ext_vector_type(8)));
typedef float f32x4 __attribute__((ext_vector_type(4)));
typedef unsigned short us8 __attribute__((ext_vector_type(8)));
typedef _Float16 h8 __attribute__((ext_vector_type(8)));
typedef _Float16 h4 __attribute__((ext_vector_type(4)));

__device__ __forceinline__ void split_bf16(float x, unsigned short& hi, unsigned short& lo) {
    unsigned u = __float_as_uint(x);
    unsigned r = (u + 0x7fffu + ((u >> 16) & 1u)) >> 16;
    hi = (unsigned short)r;
    float rem = x - __uint_as_float(r << 16);
    unsigned u2 = __float_as_uint(rem);
    unsigned r2 = (u2 + 0x7fffu + ((u2 >> 16) & 1u)) >> 16;
    lo = (unsigned short)r2;
}

#if defined(__has_builtin)
#if __has_builtin(__builtin_amdgcn_global_load_lds)
#define HAVE_GLL 1
#endif
#endif

__device__ __forceinline__ void gload_lds16(const void* g, void* l) {
#ifdef HAVE_GLL
    __builtin_amdgcn_global_load_lds((const __attribute__((address_space(1))) unsigned int*)g,
                                     (__attribute__((address_space(3))) unsigned int*)l, 16, 0, 0);
#else
    *(uint4*)l = *(const uint4*)g;
#endif
}

// =================== CSR build ===================
__global__ void k_hist(const int* __restrict__ dst, int* __restrict__ deg) {
    int e = blockIdx.x * 256 + threadIdx.x;
    if (e < NE) atomicAdd(&deg[dst[e]], 1);
}

__global__ __launch_bounds__(1024) void k_scan(const int* __restrict__ deg,
        int* __restrict__ rowptr, int* __restrict__ cursor) {
    __shared__ int sums[1024];
    int t = threadIdx.x;
    int base = t * 40;
    int local[40];
    int s = 0;
    #pragma unroll
    for (int i = 0; i < 40; i++) {
        int idx = base + i;
        int v = (idx < NENT) ? deg[idx] : 0;
        local[i] = s;
        s += v;
    }
    sums[t] = s;
    __syncthreads();
    #pragma unroll
    for (int off = 1; off < 1024; off <<= 1) {
        int add = (t >= off) ? sums[t - off] : 0;
        __syncthreads();
        sums[t] += add;
        __syncthreads();
    }
    int prefix = (t == 0) ? 0 : sums[t - 1];
    #pragma unroll
    for (int i = 0; i < 40; i++) {
        int idx = base + i;
        if (idx < NENT) {
            int p = prefix + local[i];
            rowptr[idx] = p;
            cursor[idx] = p;
        }
    }
    if (t == 1023) rowptr[NENT] = prefix + s;
}

__global__ void k_scatter(const int* __restrict__ src, const int* __restrict__ dst,
                          const int* __restrict__ aet, const float* __restrict__ a2t,
                          const float* __restrict__ a3t, int* __restrict__ cursor,
                          int* __restrict__ ssrc, float* __restrict__ sa1,
                          float* __restrict__ sa2) {
    int e = blockIdx.x * 256 + threadIdx.x;
    if (e >= NE) return;
    int tt = (e < NTE) ? e + NTE : (e < 2 * NTE ? e - NTE : e);
    int t0 = aet[e], t1 = aet[tt];
    int pos = atomicAdd(&cursor[dst[e]], 1);
    ssrc[pos] = src[e];
    sa1[pos] = a2t[t0] + a2t[t1];
    sa2[pos] = a3t[t0] + a3t[t1];
}

// =================== CSR aggregation (fp16 feats), fused epilogues ===========
// One wave per dst row; 4-edge unroll to deepen the gather pipeline.
// EPI=1: bn+tanh -> bf16 hi/lo planes. EPI=2: bn+tanh -> fp32 out32 + fp16 e.
template<int EPI>
__global__ __launch_bounds__(256) void k_agg_csr(const int* __restrict__ rowptr,
        const int* __restrict__ ssrc, const float* __restrict__ sa,
        const _Float16* __restrict__ feats, float* __restrict__ out32,
        const float* __restrict__ bias, const float* __restrict__ bn,
        unsigned short* __restrict__ oh, unsigned short* __restrict__ ol,
        _Float16* __restrict__ eh) {
    int w = threadIdx.x >> 6, l = threadIdx.x & 63;
    int row = blockIdx.x * 4 + w;
    int beg = rowptr[row], end = rowptr[row + 1];
    bool act = l < 50;
    int col = l * 4;
    float sx = 0.f, sy = 0.f, sz = 0.f, sw = 0.f;
    int i = beg;
    for (; i + 4 <= end; i += 4) {
        int i0 = ssrc[i], i1 = ssrc[i + 1], i2 = ssrc[i + 2], i3 = ssrc[i + 3];
        float a0 = sa[i], a1 = sa[i + 1], a2 = sa[i + 2], a3 = sa[i + 3];
        if (act) {
            h4 v0 = *(const h4*)(feats + (long)i0 * DIM + col);
            h4 v1 = *(const h4*)(feats + (long)i1 * DIM + col);
            h4 v2 = *(const h4*)(feats + (long)i2 * DIM + col);
            h4 v3 = *(const h4*)(feats + (long)i3 * DIM + col);
            sx += a0 * (float)v0[0] + a1 * (float)v1[0] + a2 * (float)v2[0] + a3 * (float)v3[0];
            sy += a0 * (float)v0[1] + a1 * (float)v1[1] + a2 * (float)v2[1] + a3 * (float)v3[1];
            sz += a0 * (float)v0[2] + a1 * (float)v1[2] + a2 * (float)v2[2] + a3 * (float)v3[2];
            sw += a0 * (float)v0[3] + a1 * (float)v1[3] + a2 * (float)v2[3] + a3 * (float)v3[3];
        }
    }
    for (; i < end; i++) {
        int i0 = ssrc[i];
        float a0 = sa[i];
        if (act) {
            h4 v0 = *(const h4*)(feats + (long)i0 * DIM + col);
            sx += a0 * (float)v0[0]; sy += a0 * (float)v0[1];
            sz += a0 * (float)v0[2]; sw += a0 * (float)v0[3];
        }
    }
    if (act) {
        float4 g  = *(const float4*)(bn + col);
        float4 be = *(const float4*)(bn + DIM + col);
        float4 m  = *(const float4*)(bn + 2 * DIM + col);
        float4 v  = *(const float4*)(bn + 3 * DIM + col);
        float4 bb = *(const float4*)(bias + col);
        float4 t;
        t.x = tanhf(g.x * (sx + bb.x - m.x) * rsqrtf(v.x + EPSB) + be.x);
        t.y = tanhf(g.y * (sy + bb.y - m.y) * rsqrtf(v.y + EPSB) + be.y);
        t.z = tanhf(g.z * (sz + bb.z - m.z) * rsqrtf(v.z + EPSB) + be.z);
        t.w = tanhf(g.w * (sw + bb.w - m.w) * rsqrtf(v.w + EPSB) + be.w);
        if (EPI == 1) {
            ushort4 h4v, l4v;
            split_bf16(t.x, h4v.x, l4v.x);
            split_bf16(t.y, h4v.y, l4v.y);
            split_bf16(t.z, h4v.z, l4v.z);
            split_bf16(t.w, h4v.w, l4v.w);
            *(ushort4*)(oh + (long)row * KPAD + col) = h4v;
            *(ushort4*)(ol + (long)row * KPAD + col) = l4v;
        } else {
            *(float4*)(out32 + (long)row * DIM + col) = t;
            h4 e4 = { (_Float16)t.x, (_Float16)t.y, (_Float16)t.z, (_Float16)t.w };
            *(h4*)(eh + (long)row * KPAD + col) = e4;
        }
    } else if (l < 56) {
        // zero the k-pad [200,224): poison bytes can decode as NaN
        if (EPI == 1) {
            ushort4 z = make_ushort4(0, 0, 0, 0);
            *(ushort4*)(oh + (long)row * KPAD + col) = z;
            *(ushort4*)(ol + (long)row * KPAD + col) = z;
        } else {
            h4 z = { (_Float16)0.f, (_Float16)0.f, (_Float16)0.f, (_Float16)0.f };
            *(h4*)(eh + (long)row * KPAD + col) = z;
        }
    }
}

// =================== packing kernels ===================
__global__ void k_pack_A1(const float* __restrict__ emb, const int* __restrict__ ent,
                          unsigned short* __restrict__ ah, unsigned short* __restrict__ al) {
    long i = (long)blockIdx.x * 256 + threadIdx.x;
    if (i >= (long)NENT * 16) return;
    long m = i >> 4;
    int k0 = (int)(i & 15) << 3;
    us8 h = {0, 0, 0, 0, 0, 0, 0, 0};
    us8 lo = {0, 0, 0, 0, 0, 0, 0, 0};
    const float* p = emb + (long)ent[m] * DIM0 + k0;
    #pragma unroll
    for (int j = 0; j < 8; j++) {
        if (k0 + j < DIM0) {
            unsigned short hh, ll;
            split_bf16(p[j], hh, ll);
            h[j] = hh; lo[j] = ll;
        }
    }
    *(us8*)(ah + m * 128 + k0) = h;
    *(us8*)(al + m * 128 + k0) = lo;
}

__global__ void k_pack_B(const float* __restrict__ w, unsigned short* __restrict__ bh,
                         unsigned short* __restrict__ bl, int kin, int kpad) {
    int i = blockIdx.x * 256 + threadIdx.x;
    if (i >= 208 * kpad) return;
    int k = i % kpad, n = i / kpad;
    unsigned short hi = 0, lo = 0;
    if (k < kin && n < DIM) split_bf16(w[(long)k * DIM + n], hi, lo);
    bh[i] = hi; bl[i] = lo;
}

__global__ void k_hq(const int* __restrict__ e1, const int* __restrict__ rel,
                     const float* __restrict__ eall, const float* __restrict__ embrel,
                     const float* __restrict__ bn0, float* __restrict__ hq) {
    int i = blockIdx.x * 256 + threadIdx.x;
    if (i >= BQ * 2 * DIM) return;
    int d = i % DIM, c = (i / DIM) & 1, b = i / (2 * DIM);
    float val = (c == 0) ? eall[(long)e1[b] * DIM + d]
                         : embrel[(long)rel[b] * DIM + d];
    float g = bn0[c], be = bn0[2 + c], m = bn0[4 + c], v = bn0[6 + c];
    hq[i] = g * (val - m) * rsqrtf(v + EPSB) + be;
}

// fcw [200][25600] -> fp16 plane [208][FCK] (rows >=200 zero)
__global__ void k_pack_fcw(const float* __restrict__ w, _Float16* __restrict__ wf) {
    long i = (long)blockIdx.x * 256 + threadIdx.x;
    if (i >= (long)208 * (FCK / 8)) return;
    int n = (int)(i / (FCK / 8));
    long k0 = (i % (FCK / 8)) * 8;
    h8 h = {};
    if (n < DIM) {
        const float* p = w + (long)n * FCK + k0;
        #pragma unroll
        for (int j = 0; j < 8; j++) h[j] = (_Float16)p[j];
    }
    *(h8*)(wf + (long)n * FCK + k0) = h;
}

// =================== layer GEMM (direct-B, small K, bf16 hi/lo, fp16 out) ====
__global__ __launch_bounds__(256) void k_gemm_mfma(
        const unsigned short* __restrict__ Ah, const unsigned short* __restrict__ Al,
        const unsigned short* __restrict__ Bh, const unsigned short* __restrict__ Bl,
        _Float16* __restrict__ C, int kpad) {
    int w = threadIdx.x >> 6, l = threadIdx.x & 63;
    long m0 = (long)blockIdx.x * 64 + w * 16;
    long arow = m0 + (l & 15);
    int kg = (l >> 4) * 8;
    const unsigned short* ahp = Ah + arow * kpad + kg;
    const unsigned short* alp = Al + arow * kpad + kg;
    f32x4 acc[13];
    #pragma unroll
    for (int i = 0; i < 13; i++) acc[i] = (f32x4){0.f, 0.f, 0.f, 0.f};
    for (int kb = 0; kb < kpad; kb += 32) {
        bf16x8 a_h = *(const bf16x8*)(ahp + kb);
        bf16x8 a_l = *(const bf16x8*)(alp + kb);
        #pragma unroll
        for (int nt = 0; nt < 13; nt++) {
            long boff = (long)(nt * 16 + (l & 15)) * kpad + kb + kg;
            bf16x8 b_h = *(const bf16x8*)(Bh + boff);
            bf16x8 b_l = *(const bf16x8*)(Bl + boff);
            acc[nt] = __builtin_amdgcn_mfma_f32_16x16x32_bf16(a_h, b_h, acc[nt], 0, 0, 0);
            acc[nt] = __builtin_amdgcn_mfma_f32_16x16x32_bf16(a_h, b_l, acc[nt], 0, 0, 0);
            acc[nt] = __builtin_amdgcn_mfma_f32_16x16x32_bf16(a_l, b_h, acc[nt], 0, 0, 0);
        }
    }
    long rowo = m0 + (l >> 4) * 4;
    #pragma unroll
    for (int nt = 0; nt < 13; nt++) {
        int col = nt * 16 + (l & 15);
        if (col < DIM) {
            #pragma unroll
            for (int rr = 0; rr < 4; rr++)
                C[(rowo + rr) * DIM + col] = (_Float16)acc[nt][rr];
        }
    }
}

// =================== conv1d + bn1 + relu -> hconv fp16 plane (chunk) =========
__global__ __launch_bounds__(256) void k_conv2(const float* __restrict__ hq,
        const float* __restrict__ convw, const float* __restrict__ convb,
        const float* __restrict__ bn1, _Float16* __restrict__ hc, int rowoff) {
    __shared__ float hql[400];
    __shared__ float cwl[1280];
    __shared__ float scs[128], shs[128];
    int bl = blockIdx.x;
    int t = threadIdx.x;
    long b = rowoff + bl;
    for (int i = t; i < 400; i += 256) hql[i] = hq[b * 400 + i];
    for (int i = t; i < 1280; i += 256) cwl[i] = convw[i];
    if (t < 128) {
        float g = bn1[t], be = bn1[CCH + t], m = bn1[2 * CCH + t], v = bn1[3 * CCH + t];
        float s = g * rsqrtf(v + EPSB);
        scs[t] = s;
        shs[t] = be - m * s + s * convb[t];
    }
    __syncthreads();
    int c = t >> 1, half = t & 1, p0 = half * 100;
    float cw[10];
    #pragma unroll
    for (int k = 0; k < 10; k++) cw[k] = cwl[c * 10 + k];
    float sc_ = scs[c], sh_ = shs[c];
    long obase = (long)bl * FCK + c * DIM + p0;
    for (int pc = 0; pc < 100; pc += 4) {
        float w0[8], w1[8];
        #pragma unroll
        for (int j = 0; j < 8; j++) {
            int pp = p0 + pc - 2 + j;
            bool ok = (pp >= 0 && pp < DIM);
            w0[j] = ok ? hql[pp] : 0.f;
            w1[j] = ok ? hql[DIM + pp] : 0.f;
        }
        h4 o;
        #pragma unroll
        for (int j = 0; j < 4; j++) {
            float s = 0.f;
            #pragma unroll
            for (int k = 0; k < 5; k++) s += w0[j + k] * cw[k] + w1[j + k] * cw[5 + k];
            o[j] = (_Float16)fmaxf(sc_ * s + sh_, 0.f);
        }
        *(h4*)&hc[obase + pc] = o;
    }
}

// =================== FC GEMM: fp16, LDS-staged B, split-K, atomics ===========
// grid (8, 64): 16 m-blocks x 32 splits, XCD swizzle (split-major per XCD).
__global__ __launch_bounds__(256) void k_fc2(
        const _Float16* __restrict__ A, const _Float16* __restrict__ B,
        float* __restrict__ fcsum, int rowoff) {
    __shared__ __align__(16) _Float16 ldsB[2][6656];   // 208 rows x 32 k
    int bid = blockIdx.y * 8 + blockIdx.x;
    int wsw = (bid & 7) * 64 + (bid >> 3);
    int mb = wsw & 15, split = wsw >> 4;
    int t = threadIdx.x;
    int w = t >> 6, l = t & 63;
    int kbase = split * KSEG;
    long arow = mb * 64 + w * 16 + (l & 15);
    int kg = (l >> 4) * 8;
    const _Float16* ahp = A + arow * FCK + kbase + kg;

    #pragma unroll
    for (int i = 0; i < 4; i++) {
        int u = i * 256 + t;
        if (u < 832) {
            int r = u >> 2, kc = u & 3;
            gload_lds16(B + (long)r * FCK + kbase + kc * 8, &ldsB[0][u * 8]);
        }
    }
    h8 aN = *(const h8*)(ahp);

    f32x4 acc[13];
    #pragma unroll
    for (int i = 0; i < 13; i++) acc[i] = (f32x4){0.f, 0.f, 0.f, 0.f};

    int buf = 0;
    for (int ks = 0; ks < 25; ks++) {
        __syncthreads();
        if (ks + 1 < 25) {
            int knext = kbase + (ks + 1) * 32;
            #pragma unroll
            for (int i = 0; i < 4; i++) {
                int u = i * 256 + t;
                if (u < 832) {
                    int r = u >> 2, kc = u & 3;
                    gload_lds16(B + (long)r * FCK + knext + kc * 8, &ldsB[buf ^ 1][u * 8]);
                }
            }
        }
        h8 aC = aN;
        if (ks + 1 < 25) aN = *(const h8*)(ahp + (ks + 1) * 32);
        const _Float16* b_base = &ldsB[buf][(l & 15) * 32 + kg];
        #pragma unroll
        for (int nt = 0; nt < 13; nt++) {
            h8 b = *(const h8*)(b_base + nt * 512);
            acc[nt] = __builtin_amdgcn_mfma_f32_16x16x32_f16(aC, b, acc[nt], 0, 0, 0);
        }
        buf ^= 1;
    }
    long rowo = rowoff + mb * 64 + w * 16 + (l >> 4) * 4;
    #pragma unroll
    for (int nt = 0; nt < 13; nt++) {
        int col = nt * 16 + (l & 15);
        if (col < DIM) {
            #pragma unroll
            for (int rr = 0; rr < 4; rr++)
                unsafeAtomicAdd(&fcsum[(rowo + rr) * DIM + col], acc[nt][rr]);
        }
    }
}

// =================== fcsum + bias + bn2 + relu -> h3 fp16 plane ===============
__global__ void k_fcreduce(const float* __restrict__ fcsum, const float* __restrict__ fcb,
                           const float* __restrict__ bn2, _Float16* __restrict__ h3) {
    int i = blockIdx.x * 256 + threadIdx.x;
    if (i >= BQ * KPAD) return;
    int j = i % KPAD, b = i / KPAD;
    _Float16 o = (_Float16)0.f;
    if (j < DIM) {
        float s = fcsum[(long)b * DIM + j] + fcb[j];
        float g = bn2[j], be = bn2[DIM + j], m = bn2[2 * DIM + j], v = bn2[3 * DIM + j];
        s = g * (s - m) * rsqrtf(v + EPSB) + be;
        o = (_Float16)fmaxf(s, 0.f);
    }
    h3[i] = o;
}

// =================== final: sigmoid(h3 @ e_all^T), fp16 single MFMA ==========
// grid (8, 625), XCD swizzle; wave = 64 rows x 64 cols.
// BOTH A and B fragments are register double-buffered (prefetch kt+1's 8 loads
// before the 16 MFMAs of kt) so load latency hides under compute.
__global__ __launch_bounds__(256) void k_mfma_final(
        const _Float16* __restrict__ A, const _Float16* __restrict__ B,
        float* __restrict__ out) {
    int bid = blockIdx.y * 8 + blockIdx.x;
    int wsw = (bid & 7) * 625 + (bid >> 3);
    int mbb = wsw & 7, nbb = wsw >> 3;
    int w = threadIdx.x >> 6, l = threadIdx.x & 63;
    int n0 = nbb * 64;
    int m0 = mbb * 256 + w * 64;
    int lr = l & 15;
    int kb = (l >> 4) * 8;
    const _Float16* aph = A + (long)(m0 + lr) * KPAD + kb;
    const _Float16* bph = B + (long)(n0 + lr) * KPAD + kb;
    h8 ac[4], bc[4], an[4], bn_[4];
    #pragma unroll
    for (int x = 0; x < 4; x++) {
        ac[x] = *(const h8*)(aph + (long)x * 16 * KPAD);
        bc[x] = *(const h8*)(bph + (long)x * 16 * KPAD);
    }
    f32x4 acc[4][4];
    #pragma unroll
    for (int i = 0; i < 4; i++)
        #pragma unroll
        for (int j = 0; j < 4; j++) acc[i][j] = (f32x4){0.f, 0.f, 0.f, 0.f};
    for (int kt = 0; kt < 7; kt++) {
        int ko = kt * 32 + 32;
        if (kt < 6) {
            #pragma unroll
            for (int x = 0; x < 4; x++) {
                an[x]  = *(const h8*)(aph + (long)x * 16 * KPAD + ko);
                bn_[x] = *(const h8*)(bph + (long)x * 16 * KPAD + ko);
            }
        }
        #pragma unroll
        for (int mt = 0; mt < 4; mt++)
            #pragma unroll
            for (int nt = 0; nt < 4; nt++)
                acc[mt][nt] = __builtin_amdgcn_mfma_f32_16x16x32_f16(ac[mt], bc[nt], acc[mt][nt], 0, 0, 0);
        if (kt < 6) {
            #pragma unroll
            for (int x = 0; x < 4; x++) { ac[x] = an[x]; bc[x] = bn_[x]; }
        }
    }
    int rowb = m0 + (l >> 4) * 4;
    #pragma unroll
    for (int mt = 0; mt < 4; mt++)
        #pragma unroll
        for (int r = 0; r < 4; r++) {
            long row = rowb + mt * 16 + r;
            #pragma unroll
            for (int nt = 0; nt < 4; nt++) {
                float v = acc[mt][nt][r];
                float e = __expf(-v);
                out[row * NENT + n0 + nt * 16 + lr] = __builtin_amdgcn_rcpf(1.f + e);
            }
        }
}

extern "C" void kernel_launch(void* const* d_in, const int* in_sizes, int n_in,
                              void* d_out, int out_size, void* d_ws, size_t ws_size,
                              hipStream_t stream) {
    (void)in_sizes; (void)n_in; (void)out_size; (void)ws_size;
    const int* src      = (const int*)d_in[0];
    const int* dst      = (const int*)d_in[1];
    const int* aet      = (const int*)d_in[2];
    const int* e1       = (const int*)d_in[3];
    const int* rel      = (const int*)d_in[4];
    const int* entity   = (const int*)d_in[5];
    const float* emb_e  = (const float*)d_in[6];
    const float* embrel = (const float*)d_in[7];
    const float* w2     = (const float*)d_in[8];
    const float* b2     = (const float*)d_in[9];
    const float* alpha2 = (const float*)d_in[10];
    const float* w3     = (const float*)d_in[11];
    const float* b3     = (const float*)d_in[12];
    const float* alpha3 = (const float*)d_in[13];
    const float* bn3    = (const float*)d_in[14];
    const float* bn4    = (const float*)d_in[15];
    const float* bn0    = (const float*)d_in[16];
    const float* bn1    = (const float*)d_in[17];
    const float* bn2    = (const float*)d_in[18];
    const float* convw  = (const float*)d_in[19];
    const float* convb  = (const float*)d_in[20];
    const float* fcw    = (const float*)d_in[21];
    const float* fcb    = (const float*)d_in[22];
    float* out = (float*)d_out;
    float* ws = (float*)d_ws;

    // ---- workspace layout (float offsets, lifetime-based reuse; <=167MB) ----
    _Float16* feats_f = (_Float16*)ws;
    _Float16* fcw_f   = (_Float16*)(ws + 4500000);
    float* xbuf   = ws + 16000000;
    _Float16* hc_f  = (_Float16*)(ws + 16000000);
    unsigned short* a1_h  = (unsigned short*)(ws + 24000000);
    unsigned short* a1_l  = (unsigned short*)(ws + 26560000);
    unsigned short* a2_h  = (unsigned short*)(ws + 29120000);
    unsigned short* a2_l  = (unsigned short*)(ws + 33600000);
    _Float16* e_f   = (_Float16*)(ws + 29120000);  // reuses a2 (dead after gemm2)
    int*   deg    = (int*)(ws + 38100000);
    int*   rowptr = (int*)(ws + 38150000);
    int*   cursor = (int*)(ws + 38200000);
    int*   ssrc   = (int*)(ws + 38250000);
    float* sa1    = ws + 38800000;
    float* sa2    = ws + 39350000;
    float* fcsum  = ws + 39900000;
    float* hq     = ws + 40350000;
    _Float16* h3_f = (_Float16*)(ws + 41200000);
    unsigned short* w2t_h = (unsigned short*)(ws + 41700000);
    unsigned short* w2t_l = (unsigned short*)(ws + 41720000);
    unsigned short* w3t_h = (unsigned short*)(ws + 41740000);
    unsigned short* w3t_l = (unsigned short*)(ws + 41770000);

    // ---- CSR build (shared by both layers) ----
    hipMemsetAsync(deg, 0, NENT * 4, stream);
    k_hist<<<(NE + 255) / 256, 256, 0, stream>>>(dst, deg);
    k_scan<<<1, 1024, 0, stream>>>(deg, rowptr, cursor);
    k_scatter<<<(NE + 255) / 256, 256, 0, stream>>>(src, dst, aet, alpha2, alpha3,
                                                    cursor, ssrc, sa1, sa2);

    // ---- pack inputs ----
    k_pack_A1<<<(NENT * 16 + 255) / 256, 256, 0, stream>>>(emb_e, entity, a1_h, a1_l);
    k_pack_B<<<(208 * 128 + 255) / 256, 256, 0, stream>>>(w2, w2t_h, w2t_l, DIM0, 128);
    k_pack_B<<<(208 * KPAD + 255) / 256, 256, 0, stream>>>(w3, w3t_h, w3t_l, DIM, KPAD);

    // ---- GCN layer 1 (agg fuses bn3+tanh+bf16-pack) ----
    k_gemm_mfma<<<NENT / 64, 256, 0, stream>>>(a1_h, a1_l, w2t_h, w2t_l, feats_f, 128);
    k_agg_csr<1><<<NENT / 4, 256, 0, stream>>>(rowptr, ssrc, sa1, feats_f, nullptr,
                                               b2, bn3, a2_h, a2_l, nullptr);

    // ---- GCN layer 2 (agg fuses bn4+tanh, writes xbuf fp32 + e fp16 plane) ----
    k_gemm_mfma<<<NENT / 64, 256, 0, stream>>>(a2_h, a2_l, w3t_h, w3t_l, feats_f, KPAD);
    k_agg_csr<2><<<NENT / 4, 256, 0, stream>>>(rowptr, ssrc, sa2, feats_f, xbuf,
                                               b3, bn4, nullptr, nullptr, e_f);

    // ---- decoder input + fcw pack ----
    k_hq<<<(BQ * 2 * DIM + 255) / 256, 256, 0, stream>>>(e1, rel, xbuf, embrel, bn0, hq);
    k_pack_fcw<<<(int)(((long)208 * (FCK / 8) + 255) / 256), 256, 0, stream>>>(fcw, fcw_f);

    // ---- conv + FC in 2 chunks of 1024 rows ----
    hipMemsetAsync(fcsum, 0, (size_t)BQ * DIM * 4, stream);
    for (int ch = 0; ch < BQ / QCH; ch++) {
        int rowoff = ch * QCH;
        k_conv2<<<QCH, 256, 0, stream>>>(hq, convw, convb, bn1, hc_f, rowoff);
        k_fc2<<<dim3(8, 64), 256, 0, stream>>>(hc_f, fcw_f, fcsum, rowoff);
    }
    k_fcreduce<<<(BQ * KPAD + 255) / 256, 256, 0, stream>>>(fcsum, fcb, bn2, h3_f);

    // ---- final scoring ----
    k_mfma_final<<<dim3(8, NENT / 64), 256, 0, stream>>>(h3_f, e_f, out);
}

// Round 13
// 547.095 us; speedup vs baseline: 8.3095x; 1.1611x over previous
//
#include <hip/hip_runtime.h>
#include <math.h>

#define NENT 40000
#define NTE  250000
#define NE   540000      // 2*NTE + NENT
#define DIM0 100
#define DIM  200
#define CCH  128
#define BQ   2048
#define FCK  25600       // CCH*DIM
#define EPSB 1e-5f
#define KPAD 224         // 200 padded to 7*32
#define NSPLIT 32        // split-K for FC
#define KSEG 800         // FCK / NSPLIT

typedef float f32x4 __attribute__((ext_vector_type(4)));
typedef _Float16 h8 __attribute__((ext_vector_type(8)));
typedef _Float16 h4 __attribute__((ext_vector_type(4)));

#if defined(__has_builtin)
#if __has_builtin(__builtin_amdgcn_global_load_lds)
#define HAVE_GLL 1
#endif
#endif

__device__ __forceinline__ void gload_lds16(const void* g, void* l) {
#ifdef HAVE_GLL
    __builtin_amdgcn_global_load_lds((const __attribute__((address_space(1))) unsigned int*)g,
                                     (__attribute__((address_space(3))) unsigned int*)l, 16, 0, 0);
#else
    *(uint4*)l = *(const uint4*)g;
#endif
}

// =================== CSR build ===================
__global__ void k_hist(const int* __restrict__ dst, int* __restrict__ deg) {
    int e = blockIdx.x * 256 + threadIdx.x;
    if (e < NE) atomicAdd(&deg[dst[e]], 1);
}

__global__ __launch_bounds__(1024) void k_scan(const int* __restrict__ deg,
        int* __restrict__ rowptr, int* __restrict__ cursor) {
    __shared__ int sums[1024];
    int t = threadIdx.x;
    int base = t * 40;
    int local[40];
    int s = 0;
    #pragma unroll
    for (int i = 0; i < 40; i++) {
        int idx = base + i;
        int v = (idx < NENT) ? deg[idx] : 0;
        local[i] = s;
        s += v;
    }
    sums[t] = s;
    __syncthreads();
    #pragma unroll
    for (int off = 1; off < 1024; off <<= 1) {
        int add = (t >= off) ? sums[t - off] : 0;
        __syncthreads();
        sums[t] += add;
        __syncthreads();
    }
    int prefix = (t == 0) ? 0 : sums[t - 1];
    #pragma unroll
    for (int i = 0; i < 40; i++) {
        int idx = base + i;
        if (idx < NENT) {
            int p = prefix + local[i];
            rowptr[idx] = p;
            cursor[idx] = p;
        }
    }
    if (t == 1023) rowptr[NENT] = prefix + s;
}

__global__ void k_scatter(const int* __restrict__ src, const int* __restrict__ dst,
                          const int* __restrict__ aet, const float* __restrict__ a2t,
                          const float* __restrict__ a3t, int* __restrict__ cursor,
                          int* __restrict__ ssrc, float* __restrict__ sa1,
                          float* __restrict__ sa2) {
    int e = blockIdx.x * 256 + threadIdx.x;
    if (e >= NE) return;
    int tt = (e < NTE) ? e + NTE : (e < 2 * NTE ? e - NTE : e);
    int t0 = aet[e], t1 = aet[tt];
    int pos = atomicAdd(&cursor[dst[e]], 1);
    ssrc[pos] = src[e];
    sa1[pos] = a2t[t0] + a2t[t1];
    sa2[pos] = a3t[t0] + a3t[t1];
}

// =================== CSR aggregation (fp16 feats), fused epilogues ===========
// One wave per dst row; 4-edge unroll. Epilogue: bn+tanh -> fp16 plane
// [row][KPAD] (zero pads). W32 additionally writes fp32 out32 [row][DIM].
template<bool W32>
__global__ __launch_bounds__(256) void k_agg_csr(const int* __restrict__ rowptr,
        const int* __restrict__ ssrc, const float* __restrict__ sa,
        const _Float16* __restrict__ feats, float* __restrict__ out32,
        const float* __restrict__ bias, const float* __restrict__ bn,
        _Float16* __restrict__ eh) {
    int w = threadIdx.x >> 6, l = threadIdx.x & 63;
    int row = blockIdx.x * 4 + w;
    int beg = rowptr[row], end = rowptr[row + 1];
    bool act = l < 50;
    int col = l * 4;
    float sx = 0.f, sy = 0.f, sz = 0.f, sw = 0.f;
    int i = beg;
    for (; i + 4 <= end; i += 4) {
        int i0 = ssrc[i], i1 = ssrc[i + 1], i2 = ssrc[i + 2], i3 = ssrc[i + 3];
        float a0 = sa[i], a1 = sa[i + 1], a2 = sa[i + 2], a3 = sa[i + 3];
        if (act) {
            h4 v0 = *(const h4*)(feats + (long)i0 * DIM + col);
            h4 v1 = *(const h4*)(feats + (long)i1 * DIM + col);
            h4 v2 = *(const h4*)(feats + (long)i2 * DIM + col);
            h4 v3 = *(const h4*)(feats + (long)i3 * DIM + col);
            sx += a0 * (float)v0[0] + a1 * (float)v1[0] + a2 * (float)v2[0] + a3 * (float)v3[0];
            sy += a0 * (float)v0[1] + a1 * (float)v1[1] + a2 * (float)v2[1] + a3 * (float)v3[1];
            sz += a0 * (float)v0[2] + a1 * (float)v1[2] + a2 * (float)v2[2] + a3 * (float)v3[2];
            sw += a0 * (float)v0[3] + a1 * (float)v1[3] + a2 * (float)v2[3] + a3 * (float)v3[3];
        }
    }
    for (; i < end; i++) {
        int i0 = ssrc[i];
        float a0 = sa[i];
        if (act) {
            h4 v0 = *(const h4*)(feats + (long)i0 * DIM + col);
            sx += a0 * (float)v0[0]; sy += a0 * (float)v0[1];
            sz += a0 * (float)v0[2]; sw += a0 * (float)v0[3];
        }
    }
    if (act) {
        float4 g  = *(const float4*)(bn + col);
        float4 be = *(const float4*)(bn + DIM + col);
        float4 m  = *(const float4*)(bn + 2 * DIM + col);
        float4 v  = *(const float4*)(bn + 3 * DIM + col);
        float4 bb = *(const float4*)(bias + col);
        float4 t;
        t.x = tanhf(g.x * (sx + bb.x - m.x) * rsqrtf(v.x + EPSB) + be.x);
        t.y = tanhf(g.y * (sy + bb.y - m.y) * rsqrtf(v.y + EPSB) + be.y);
        t.z = tanhf(g.z * (sz + bb.z - m.z) * rsqrtf(v.z + EPSB) + be.z);
        t.w = tanhf(g.w * (sw + bb.w - m.w) * rsqrtf(v.w + EPSB) + be.w);
        if (W32) *(float4*)(out32 + (long)row * DIM + col) = t;
        h4 e4 = { (_Float16)t.x, (_Float16)t.y, (_Float16)t.z, (_Float16)t.w };
        *(h4*)(eh + (long)row * KPAD + col) = e4;
    } else if (l < 56) {
        // zero the k-pad [200,224): poison bytes can decode as NaN
        h4 z = { (_Float16)0.f, (_Float16)0.f, (_Float16)0.f, (_Float16)0.f };
        *(h4*)(eh + (long)row * KPAD + col) = z;
    }
}

// =================== packing kernels (fp16 single plane) ===================
__global__ void k_pack_emb(const float* __restrict__ emb, const int* __restrict__ ent,
                           _Float16* __restrict__ o) {
    long i = (long)blockIdx.x * 256 + threadIdx.x;
    if (i >= (long)NENT * 16) return;
    long m = i >> 4;
    int k0 = (int)(i & 15) << 3;
    h8 h = {};
    const float* p = emb + (long)ent[m] * DIM0 + k0;
    #pragma unroll
    for (int j = 0; j < 8; j++)
        if (k0 + j < DIM0) h[j] = (_Float16)p[j];
    *(h8*)(o + m * 128 + k0) = h;
}

__global__ void k_pack_B16(const float* __restrict__ w, _Float16* __restrict__ bf,
                           int kin, int kpad) {
    int i = blockIdx.x * 256 + threadIdx.x;
    if (i >= 208 * kpad) return;
    int k = i % kpad, n = i / kpad;
    bf[i] = (k < kin && n < DIM) ? (_Float16)w[(long)k * DIM + n] : (_Float16)0.f;
}

__global__ void k_hq(const int* __restrict__ e1, const int* __restrict__ rel,
                     const float* __restrict__ eall, const float* __restrict__ embrel,
                     const float* __restrict__ bn0, float* __restrict__ hq) {
    int i = blockIdx.x * 256 + threadIdx.x;
    if (i >= BQ * 2 * DIM) return;
    int d = i % DIM, c = (i / DIM) & 1, b = i / (2 * DIM);
    float val = (c == 0) ? eall[(long)e1[b] * DIM + d]
                         : embrel[(long)rel[b] * DIM + d];
    float g = bn0[c], be = bn0[2 + c], m = bn0[4 + c], v = bn0[6 + c];
    hq[i] = g * (val - m) * rsqrtf(v + EPSB) + be;
}

// fcw [200][25600] -> fp16 plane [208][FCK] (rows >=200 zero)
__global__ void k_pack_fcw(const float* __restrict__ w, _Float16* __restrict__ wf) {
    long i = (long)blockIdx.x * 256 + threadIdx.x;
    if (i >= (long)208 * (FCK / 8)) return;
    int n = (int)(i / (FCK / 8));
    long k0 = (i % (FCK / 8)) * 8;
    h8 h = {};
    if (n < DIM) {
        const float* p = w + (long)n * FCK + k0;
        #pragma unroll
        for (int j = 0; j < 8; j++) h[j] = (_Float16)p[j];
    }
    *(h8*)(wf + (long)n * FCK + k0) = h;
}

// =================== layer GEMM (fp16 single MFMA, direct-B) =================
__global__ __launch_bounds__(256) void k_gemm16(
        const _Float16* __restrict__ A, const _Float16* __restrict__ B,
        _Float16* __restrict__ C, int kpad) {
    int w = threadIdx.x >> 6, l = threadIdx.x & 63;
    long m0 = (long)blockIdx.x * 64 + w * 16;
    long arow = m0 + (l & 15);
    int kg = (l >> 4) * 8;
    const _Float16* ap = A + arow * kpad + kg;
    f32x4 acc[13];
    #pragma unroll
    for (int i = 0; i < 13; i++) acc[i] = (f32x4){0.f, 0.f, 0.f, 0.f};
    for (int kb = 0; kb < kpad; kb += 32) {
        h8 a = *(const h8*)(ap + kb);
        #pragma unroll
        for (int nt = 0; nt < 13; nt++) {
            h8 b = *(const h8*)(B + (long)(nt * 16 + (l & 15)) * kpad + kb + kg);
            acc[nt] = __builtin_amdgcn_mfma_f32_16x16x32_f16(a, b, acc[nt], 0, 0, 0);
        }
    }
    long rowo = m0 + (l >> 4) * 4;
    #pragma unroll
    for (int nt = 0; nt < 13; nt++) {
        int col = nt * 16 + (l & 15);
        if (col < DIM) {
            #pragma unroll
            for (int rr = 0; rr < 4; rr++)
                C[(rowo + rr) * DIM + col] = (_Float16)acc[nt][rr];
        }
    }
}

// =================== conv1d + bn1 + relu -> hconv fp16 plane =================
__global__ __launch_bounds__(256) void k_conv2(const float* __restrict__ hq,
        const float* __restrict__ convw, const float* __restrict__ convb,
        const float* __restrict__ bn1, _Float16* __restrict__ hc) {
    __shared__ float hql[400];
    __shared__ float cwl[1280];
    __shared__ float scs[128], shs[128];
    int bl = blockIdx.x;
    int t = threadIdx.x;
    long b = bl;
    for (int i = t; i < 400; i += 256) hql[i] = hq[b * 400 + i];
    for (int i = t; i < 1280; i += 256) cwl[i] = convw[i];
    if (t < 128) {
        float g = bn1[t], be = bn1[CCH + t], m = bn1[2 * CCH + t], v = bn1[3 * CCH + t];
        float s = g * rsqrtf(v + EPSB);
        scs[t] = s;
        shs[t] = be - m * s + s * convb[t];
    }
    __syncthreads();
    int c = t >> 1, half = t & 1, p0 = half * 100;
    float cw[10];
    #pragma unroll
    for (int k = 0; k < 10; k++) cw[k] = cwl[c * 10 + k];
    float sc_ = scs[c], sh_ = shs[c];
    long obase = (long)bl * FCK + c * DIM + p0;
    for (int pc = 0; pc < 100; pc += 4) {
        float w0[8], w1[8];
        #pragma unroll
        for (int j = 0; j < 8; j++) {
            int pp = p0 + pc - 2 + j;
            bool ok = (pp >= 0 && pp < DIM);
            w0[j] = ok ? hql[pp] : 0.f;
            w1[j] = ok ? hql[DIM + pp] : 0.f;
        }
        h4 o;
        #pragma unroll
        for (int j = 0; j < 4; j++) {
            float s = 0.f;
            #pragma unroll
            for (int k = 0; k < 5; k++) s += w0[j + k] * cw[k] + w1[j + k] * cw[5 + k];
            o[j] = (_Float16)fmaxf(sc_ * s + sh_, 0.f);
        }
        *(h4*)&hc[obase + pc] = o;
    }
}

// =================== FC GEMM: fp16, LDS-staged B, split-K, atomics ===========
// grid (8, 128): 32 m-blocks x 32 splits; XCD swizzle (bid%8 = XCD): each XCD
// runs 4 splits x all 32 m-blocks -> B segs L2-resident per XCD.
__global__ __launch_bounds__(256) void k_fc2(
        const _Float16* __restrict__ A, const _Float16* __restrict__ B,
        float* __restrict__ fcsum) {
    __shared__ __align__(16) _Float16 ldsB[2][6656];   // 208 rows x 32 k
    int bid = blockIdx.y * 8 + blockIdx.x;
    int wsw = (bid & 7) * 128 + (bid >> 3);
    int mb = wsw & 31, split = wsw >> 5;
    int t = threadIdx.x;
    int w = t >> 6, l = t & 63;
    int kbase = split * KSEG;
    long arow = mb * 64 + w * 16 + (l & 15);
    int kg = (l >> 4) * 8;
    const _Float16* ahp = A + arow * FCK + kbase + kg;

    #pragma unroll
    for (int i = 0; i < 4; i++) {
        int u = i * 256 + t;
        if (u < 832) {
            int r = u >> 2, kc = u & 3;
            gload_lds16(B + (long)r * FCK + kbase + kc * 8, &ldsB[0][u * 8]);
        }
    }
    h8 aN = *(const h8*)(ahp);

    f32x4 acc[13];
    #pragma unroll
    for (int i = 0; i < 13; i++) acc[i] = (f32x4){0.f, 0.f, 0.f, 0.f};

    int buf = 0;
    for (int ks = 0; ks < 25; ks++) {
        __syncthreads();
        if (ks + 1 < 25) {
            int knext = kbase + (ks + 1) * 32;
            #pragma unroll
            for (int i = 0; i < 4; i++) {
                int u = i * 256 + t;
                if (u < 832) {
                    int r = u >> 2, kc = u & 3;
                    gload_lds16(B + (long)r * FCK + knext + kc * 8, &ldsB[buf ^ 1][u * 8]);
                }
            }
        }
        h8 aC = aN;
        if (ks + 1 < 25) aN = *(const h8*)(ahp + (ks + 1) * 32);
        const _Float16* b_base = &ldsB[buf][(l & 15) * 32 + kg];
        #pragma unroll
        for (int nt = 0; nt < 13; nt++) {
            h8 b = *(const h8*)(b_base + nt * 512);
            acc[nt] = __builtin_amdgcn_mfma_f32_16x16x32_f16(aC, b, acc[nt], 0, 0, 0);
        }
        buf ^= 1;
    }
    long rowo = mb * 64 + w * 16 + (l >> 4) * 4;
    #pragma unroll
    for (int nt = 0; nt < 13; nt++) {
        int col = nt * 16 + (l & 15);
        if (col < DIM) {
            #pragma unroll
            for (int rr = 0; rr < 4; rr++)
                unsafeAtomicAdd(&fcsum[(rowo + rr) * DIM + col], acc[nt][rr]);
        }
    }
}

// =================== fcsum + bias + bn2 + relu -> h3 fp16 plane ===============
__global__ void k_fcreduce(const float* __restrict__ fcsum, const float* __restrict__ fcb,
                           const float* __restrict__ bn2, _Float16* __restrict__ h3) {
    int i = blockIdx.x * 256 + threadIdx.x;
    if (i >= BQ * KPAD) return;
    int j = i % KPAD, b = i / KPAD;
    _Float16 o = (_Float16)0.f;
    if (j < DIM) {
        float s = fcsum[(long)b * DIM + j] + fcb[j];
        float g = bn2[j], be = bn2[DIM + j], m = bn2[2 * DIM + j], v = bn2[3 * DIM + j];
        s = g * (s - m) * rsqrtf(v + EPSB) + be;
        o = (_Float16)fmaxf(s, 0.f);
    }
    h3[i] = o;
}

// =================== final: sigmoid(h3 @ e_all^T), fp16 MFMA =================
// grid (8, 625), XCD swizzle; wave = 64 rows x 64 cols; A+B reg double-buffer.
// Epilogue: wave-local LDS transpose -> f32x4 nontemporal stores (full lines).
__global__ __launch_bounds__(256) void k_mfma_final(
        const _Float16* __restrict__ A, const _Float16* __restrict__ B,
        float* __restrict__ out) {
    __shared__ float tl[4][32][68];
    int bid = blockIdx.y * 8 + blockIdx.x;
    int wsw = (bid & 7) * 625 + (bid >> 3);
    int mbb = wsw & 7, nbb = wsw >> 3;
    int w = threadIdx.x >> 6, l = threadIdx.x & 63;
    int n0 = nbb * 64;
    int m0 = mbb * 256 + w * 64;
    int lr = l & 15;
    int kb = (l >> 4) * 8;
    const _Float16* aph = A + (long)(m0 + lr) * KPAD + kb;
    const _Float16* bph = B + (long)(n0 + lr) * KPAD + kb;
    h8 ac[4], bc[4], an[4], bn_[4];
    #pragma unroll
    for (int x = 0; x < 4; x++) {
        ac[x] = *(const h8*)(aph + (long)x * 16 * KPAD);
        bc[x] = *(const h8*)(bph + (long)x * 16 * KPAD);
    }
    f32x4 acc[4][4];
    #pragma unroll
    for (int i = 0; i < 4; i++)
        #pragma unroll
        for (int j = 0; j < 4; j++) acc[i][j] = (f32x4){0.f, 0.f, 0.f, 0.f};
    for (int kt = 0; kt < 7; kt++) {
        int ko = kt * 32 + 32;
        if (kt < 6) {
            #pragma unroll
            for (int x = 0; x < 4; x++) {
                an[x]  = *(const h8*)(aph + (long)x * 16 * KPAD + ko);
                bn_[x] = *(const h8*)(bph + (long)x * 16 * KPAD + ko);
            }
        }
        #pragma unroll
        for (int mt = 0; mt < 4; mt++)
            #pragma unroll
            for (int nt = 0; nt < 4; nt++)
                acc[mt][nt] = __builtin_amdgcn_mfma_f32_16x16x32_f16(ac[mt], bc[nt], acc[mt][nt], 0, 0, 0);
        if (kt < 6) {
            #pragma unroll
            for (int x = 0; x < 4; x++) { ac[x] = an[x]; bc[x] = bn_[x]; }
        }
    }
    // epilogue: per 32-row half, transpose via wave-local LDS, f32x4 NT stores
    #pragma unroll
    for (int hh = 0; hh < 2; hh++) {
        #pragma unroll
        for (int mt2 = 0; mt2 < 2; mt2++) {
            int mt = hh * 2 + mt2;
            #pragma unroll
            for (int nt = 0; nt < 4; nt++)
                #pragma unroll
                for (int r = 0; r < 4; r++)
                    tl[w][mt2 * 16 + (l >> 4) * 4 + r][nt * 16 + lr] = acc[mt][nt][r];
        }
        // wave-local LDS reuse: in-wave lgkmcnt ordering suffices (no barrier)
        #pragma unroll
        for (int i = 0; i < 8; i++) {
            int rr = i * 4 + (l >> 4);
            f32x4 v = *(const f32x4*)&tl[w][rr][lr * 4];
            f32x4 o;
            o.x = __builtin_amdgcn_rcpf(1.f + __expf(-v.x));
            o.y = __builtin_amdgcn_rcpf(1.f + __expf(-v.y));
            o.z = __builtin_amdgcn_rcpf(1.f + __expf(-v.z));
            o.w = __builtin_amdgcn_rcpf(1.f + __expf(-v.w));
            long row = m0 + hh * 32 + rr;
            __builtin_nontemporal_store(o, (f32x4*)&out[row * NENT + n0 + lr * 4]);
        }
    }
}

extern "C" void kernel_launch(void* const* d_in, const int* in_sizes, int n_in,
                              void* d_out, int out_size, void* d_ws, size_t ws_size,
                              hipStream_t stream) {
    (void)in_sizes; (void)n_in; (void)out_size; (void)ws_size;
    const int* src      = (const int*)d_in[0];
    const int* dst      = (const int*)d_in[1];
    const int* aet      = (const int*)d_in[2];
    const int* e1       = (const int*)d_in[3];
    const int* rel      = (const int*)d_in[4];
    const int* entity   = (const int*)d_in[5];
    const float* emb_e  = (const float*)d_in[6];
    const float* embrel = (const float*)d_in[7];
    const float* w2     = (const float*)d_in[8];
    const float* b2     = (const float*)d_in[9];
    const float* alpha2 = (const float*)d_in[10];
    const float* w3     = (const float*)d_in[11];
    const float* b3     = (const float*)d_in[12];
    const float* alpha3 = (const float*)d_in[13];
    const float* bn3    = (const float*)d_in[14];
    const float* bn4    = (const float*)d_in[15];
    const float* bn0    = (const float*)d_in[16];
    const float* bn1    = (const float*)d_in[17];
    const float* bn2    = (const float*)d_in[18];
    const float* convw  = (const float*)d_in[19];
    const float* convb  = (const float*)d_in[20];
    const float* fcw    = (const float*)d_in[21];
    const float* fcb    = (const float*)d_in[22];
    float* out = (float*)d_out;
    float* ws = (float*)d_ws;

    // ---- workspace layout (float offsets; ws is ~1.3GB, we use ~280MB) ----
    _Float16* feats_f = (_Float16*)ws;
    _Float16* fcw_f   = (_Float16*)(ws + 4500000);
    float* xbuf   = ws + 16000000;
    _Float16* emb16 = (_Float16*)(ws + 24000000);
    _Float16* x1_f  = (_Float16*)(ws + 29120000);
    _Float16* e_f   = (_Float16*)(ws + 29120000);  // reuses x1 (dead after gemm2)
    int*   deg    = (int*)(ws + 38100000);
    int*   rowptr = (int*)(ws + 38150000);
    int*   cursor = (int*)(ws + 38200000);
    int*   ssrc   = (int*)(ws + 38250000);
    float* sa1    = ws + 38800000;
    float* sa2    = ws + 39350000;
    float* fcsum  = ws + 39900000;
    float* hq     = ws + 40350000;
    _Float16* h3_f = (_Float16*)(ws + 41200000);
    _Float16* w2t_f = (_Float16*)(ws + 41700000);   // 208*128 fp16
    _Float16* w3t_f = (_Float16*)(ws + 41740000);   // 208*224 fp16
    _Float16* hc_f  = (_Float16*)(ws + 43000000);

    // ---- CSR build (shared by both layers) ----
    hipMemsetAsync(deg, 0, NENT * 4, stream);
    k_hist<<<(NE + 255) / 256, 256, 0, stream>>>(dst, deg);
    k_scan<<<1, 1024, 0, stream>>>(deg, rowptr, cursor);
    k_scatter<<<(NE + 255) / 256, 256, 0, stream>>>(src, dst, aet, alpha2, alpha3,
                                                    cursor, ssrc, sa1, sa2);

    // ---- pack inputs (fp16 single plane) ----
    k_pack_emb<<<(NENT * 16 + 255) / 256, 256, 0, stream>>>(emb_e, entity, emb16);
    k_pack_B16<<<(208 * 128 + 255) / 256, 256, 0, stream>>>(w2, w2t_f, DIM0, 128);
    k_pack_B16<<<(208 * KPAD + 255) / 256, 256, 0, stream>>>(w3, w3t_f, DIM, KPAD);

    // ---- GCN layer 1: gemm -> agg(bn3+tanh) -> x1 fp16 plane ----
    k_gemm16<<<NENT / 64, 256, 0, stream>>>(emb16, w2t_f, feats_f, 128);
    k_agg_csr<false><<<NENT / 4, 256, 0, stream>>>(rowptr, ssrc, sa1, feats_f,
                                                   nullptr, b2, bn3, x1_f);

    // ---- GCN layer 2: gemm -> agg(bn4+tanh) -> xbuf fp32 + e fp16 plane ----
    k_gemm16<<<NENT / 64, 256, 0, stream>>>(x1_f, w3t_f, feats_f, KPAD);
    k_agg_csr<true><<<NENT / 4, 256, 0, stream>>>(rowptr, ssrc, sa2, feats_f,
                                                  xbuf, b3, bn4, e_f);

    // ---- decoder input + fcw pack ----
    k_hq<<<(BQ * 2 * DIM + 255) / 256, 256, 0, stream>>>(e1, rel, xbuf, embrel, bn0, hq);
    k_pack_fcw<<<(int)(((long)208 * (FCK / 8) + 255) / 256), 256, 0, stream>>>(fcw, fcw_f);

    // ---- conv + FC (single pass, full batch) ----
    hipMemsetAsync(fcsum, 0, (size_t)BQ * DIM * 4, stream);
    k_conv2<<<BQ, 256, 0, stream>>>(hq, convw, convb, bn1, hc_f);
    k_fc2<<<dim3(8, 128), 256, 0, stream>>>(hc_f, fcw_f, fcsum);
    k_fcreduce<<<(BQ * KPAD + 255) / 256, 256, 0, stream>>>(fcsum, fcb, bn2, h3_f);

    // ---- final scoring ----
    k_mfma_final<<<dim3(8, NENT / 64), 256, 0, stream>>>(h3_f, e_f, out);
}

// Round 14
// 543.934 us; speedup vs baseline: 8.3578x; 1.0058x over previous
//
#include <hip/hip_runtime.h>
#include <math.h>

#define NENT 40000
#define NTE  250000
#define NE   540000      // 2*NTE + NENT
#define DIM0 100
#define DIM  200
#define CCH  128
#define BQ   2048
#define FCK  25600       // CCH*DIM
#define EPSB 1e-5f
#define KPAD 224         // 200 padded to 7*32
#define EMBS 104         // emb16 row stride (100 padded to 13*8)
#define NSPLIT 32        // split-K for FC
#define KSEG 800         // FCK / NSPLIT

typedef float f32x4 __attribute__((ext_vector_type(4)));
typedef _Float16 h8 __attribute__((ext_vector_type(8)));
typedef _Float16 h4 __attribute__((ext_vector_type(4)));

#if defined(__has_builtin)
#if __has_builtin(__builtin_amdgcn_global_load_lds)
#define HAVE_GLL 1
#endif
#endif

__device__ __forceinline__ void gload_lds16(const void* g, void* l) {
#ifdef HAVE_GLL
    __builtin_amdgcn_global_load_lds((const __attribute__((address_space(1))) unsigned int*)g,
                                     (__attribute__((address_space(3))) unsigned int*)l, 16, 0, 0);
#else
    *(uint4*)l = *(const uint4*)g;
#endif
}

// =================== CSR build ===================
__global__ void k_hist(const int* __restrict__ dst, int* __restrict__ deg) {
    int e = blockIdx.x * 256 + threadIdx.x;
    if (e < NE) atomicAdd(&deg[dst[e]], 1);
}

__global__ __launch_bounds__(1024) void k_scan(const int* __restrict__ deg,
        int* __restrict__ rowptr, int* __restrict__ cursor) {
    __shared__ int sums[1024];
    int t = threadIdx.x;
    int base = t * 40;
    int local[40];
    int s = 0;
    #pragma unroll
    for (int i = 0; i < 40; i++) {
        int idx = base + i;
        int v = (idx < NENT) ? deg[idx] : 0;
        local[i] = s;
        s += v;
    }
    sums[t] = s;
    __syncthreads();
    #pragma unroll
    for (int off = 1; off < 1024; off <<= 1) {
        int add = (t >= off) ? sums[t - off] : 0;
        __syncthreads();
        sums[t] += add;
        __syncthreads();
    }
    int prefix = (t == 0) ? 0 : sums[t - 1];
    #pragma unroll
    for (int i = 0; i < 40; i++) {
        int idx = base + i;
        if (idx < NENT) {
            int p = prefix + local[i];
            rowptr[idx] = p;
            cursor[idx] = p;
        }
    }
    if (t == 1023) rowptr[NENT] = prefix + s;
}

__global__ void k_scatter(const int* __restrict__ src, const int* __restrict__ dst,
                          const int* __restrict__ aet, const float* __restrict__ a2t,
                          const float* __restrict__ a3t, int* __restrict__ cursor,
                          int* __restrict__ ssrc, float* __restrict__ sa1,
                          float* __restrict__ sa2) {
    int e = blockIdx.x * 256 + threadIdx.x;
    if (e >= NE) return;
    int tt = (e < NTE) ? e + NTE : (e < 2 * NTE ? e - NTE : e);
    int t0 = aet[e], t1 = aet[tt];
    int pos = atomicAdd(&cursor[dst[e]], 1);
    ssrc[pos] = src[e];
    sa1[pos] = a2t[t0] + a2t[t1];
    sa2[pos] = a3t[t0] + a3t[t1];
}

// =================== raw CSR aggregation (pre-GEMM, linearity) ===============
// outd[row] = sum over edges alpha * srcd[src]. fp32 accum, fp16 in/out.
// NL lanes x h4 cover SS cols; lanes [NL,NPADL) write zero pads up to OS.
template<int NL, int NPADL, int SS, int OS>
__global__ __launch_bounds__(256) void k_agg_raw(const int* __restrict__ rowptr,
        const int* __restrict__ ssrc, const float* __restrict__ sa,
        const _Float16* __restrict__ srcd, _Float16* __restrict__ outd) {
    int w = threadIdx.x >> 6, l = threadIdx.x & 63;
    int row = blockIdx.x * 4 + w;
    int beg = rowptr[row], end = rowptr[row + 1];
    bool act = l < NL;
    int col = l * 4;
    float sx = 0.f, sy = 0.f, sz = 0.f, sw = 0.f;
    int i = beg;
    for (; i + 4 <= end; i += 4) {
        int i0 = ssrc[i], i1 = ssrc[i + 1], i2 = ssrc[i + 2], i3 = ssrc[i + 3];
        float a0 = sa[i], a1 = sa[i + 1], a2 = sa[i + 2], a3 = sa[i + 3];
        if (act) {
            h4 v0 = *(const h4*)(srcd + (long)i0 * SS + col);
            h4 v1 = *(const h4*)(srcd + (long)i1 * SS + col);
            h4 v2 = *(const h4*)(srcd + (long)i2 * SS + col);
            h4 v3 = *(const h4*)(srcd + (long)i3 * SS + col);
            sx += a0 * (float)v0[0] + a1 * (float)v1[0] + a2 * (float)v2[0] + a3 * (float)v3[0];
            sy += a0 * (float)v0[1] + a1 * (float)v1[1] + a2 * (float)v2[1] + a3 * (float)v3[1];
            sz += a0 * (float)v0[2] + a1 * (float)v1[2] + a2 * (float)v2[2] + a3 * (float)v3[2];
            sw += a0 * (float)v0[3] + a1 * (float)v1[3] + a2 * (float)v2[3] + a3 * (float)v3[3];
        }
    }
    for (; i < end; i++) {
        int i0 = ssrc[i];
        float a0 = sa[i];
        if (act) {
            h4 v0 = *(const h4*)(srcd + (long)i0 * SS + col);
            sx += a0 * (float)v0[0]; sy += a0 * (float)v0[1];
            sz += a0 * (float)v0[2]; sw += a0 * (float)v0[3];
        }
    }
    if (act) {
        h4 o = { (_Float16)sx, (_Float16)sy, (_Float16)sz, (_Float16)sw };
        *(h4*)(outd + (long)row * OS + col) = o;
    } else if (l < NPADL) {
        h4 z = { (_Float16)0.f, (_Float16)0.f, (_Float16)0.f, (_Float16)0.f };
        *(h4*)(outd + (long)row * OS + col) = z;
    }
}

// =================== packing kernels ===================
// emb_e[entity] -> fp16 [NENT][EMBS] (cols >=100 zero)
__global__ void k_pack_emb(const float* __restrict__ emb, const int* __restrict__ ent,
                           _Float16* __restrict__ o) {
    long i = (long)blockIdx.x * 256 + threadIdx.x;
    if (i >= (long)NENT * 13) return;
    long m = i / 13;
    int k0 = (int)(i % 13) * 8;
    h8 h = {};
    const float* p = emb + (long)ent[m] * DIM0 + k0;
    #pragma unroll
    for (int j = 0; j < 8; j++)
        if (k0 + j < DIM0) h[j] = (_Float16)p[j];
    *(h8*)(o + m * EMBS + k0) = h;
}

// layer weight [kin][200] -> fp16 B plane [nrows][kpad] (OOB zero)
__global__ void k_pack_B16(const float* __restrict__ w, _Float16* __restrict__ bf,
                           int kin, int kpad, int nrows) {
    int i = blockIdx.x * 256 + threadIdx.x;
    if (i >= nrows * kpad) return;
    int k = i % kpad, n = i / kpad;
    bf[i] = (k < kin && n < DIM) ? (_Float16)w[(long)k * DIM + n] : (_Float16)0.f;
}

// decoder input: bn0-normalized [e(fp16 plane); rel_emb] -> hq fp32
__global__ void k_hq(const int* __restrict__ e1, const int* __restrict__ rel,
                     const _Float16* __restrict__ ef, const float* __restrict__ embrel,
                     const float* __restrict__ bn0, float* __restrict__ hq) {
    int i = blockIdx.x * 256 + threadIdx.x;
    if (i >= BQ * 2 * DIM) return;
    int d = i % DIM, c = (i / DIM) & 1, b = i / (2 * DIM);
    float val = (c == 0) ? (float)ef[(long)e1[b] * KPAD + d]
                         : embrel[(long)rel[b] * DIM + d];
    float g = bn0[c], be = bn0[2 + c], m = bn0[4 + c], v = bn0[6 + c];
    hq[i] = g * (val - m) * rsqrtf(v + EPSB) + be;
}

// fcw [200][25600] -> fp16 plane [208][FCK] (rows >=200 zero)
__global__ void k_pack_fcw(const float* __restrict__ w, _Float16* __restrict__ wf) {
    long i = (long)blockIdx.x * 256 + threadIdx.x;
    if (i >= (long)208 * (FCK / 8)) return;
    int n = (int)(i / (FCK / 8));
    long k0 = (i % (FCK / 8)) * 8;
    h8 h = {};
    if (n < DIM) {
        const float* p = w + (long)n * FCK + k0;
        #pragma unroll
        for (int j = 0; j < 8; j++) h[j] = (_Float16)p[j];
    }
    *(h8*)(wf + (long)n * FCK + k0) = h;
}

// ======= layer GEMM fused epilogue: C = tanh(bn(A@B + bias)) -> fp16 =========
// A [NENT][kpad] fp16 (aggregated input), B [NT*16][kpad] fp16 (W^T),
// C [NENT][ostride] fp16; cols >=200 written as 0 (if within ostride).
template<int NT>
__global__ __launch_bounds__(256) void k_gemm16f(
        const _Float16* __restrict__ A, const _Float16* __restrict__ B,
        const float* __restrict__ bias, const float* __restrict__ bn,
        _Float16* __restrict__ C, int kpad, int ostride) {
    int w = threadIdx.x >> 6, l = threadIdx.x & 63;
    long m0 = (long)blockIdx.x * 64 + w * 16;
    long arow = m0 + (l & 15);
    int kg = (l >> 4) * 8;
    const _Float16* ap = A + arow * kpad + kg;
    f32x4 acc[NT];
    #pragma unroll
    for (int i = 0; i < NT; i++) acc[i] = (f32x4){0.f, 0.f, 0.f, 0.f};
    for (int kb = 0; kb < kpad; kb += 32) {
        h8 a = *(const h8*)(ap + kb);
        #pragma unroll
        for (int nt = 0; nt < NT; nt++) {
            h8 b = *(const h8*)(B + (long)(nt * 16 + (l & 15)) * kpad + kb + kg);
            acc[nt] = __builtin_amdgcn_mfma_f32_16x16x32_f16(a, b, acc[nt], 0, 0, 0);
        }
    }
    long rowo = m0 + (l >> 4) * 4;
    #pragma unroll
    for (int nt = 0; nt < NT; nt++) {
        int col = nt * 16 + (l & 15);
        if (col < ostride) {
            _Float16 vals[4];
            if (col < DIM) {
                float g = bn[col], be = bn[DIM + col], m = bn[2 * DIM + col],
                      v = bn[3 * DIM + col], bb = bias[col];
                float sc = g * rsqrtf(v + EPSB);
                #pragma unroll
                for (int rr = 0; rr < 4; rr++)
                    vals[rr] = (_Float16)tanhf(sc * (acc[nt][rr] + bb - m) + be);
            } else {
                #pragma unroll
                for (int rr = 0; rr < 4; rr++) vals[rr] = (_Float16)0.f;
            }
            #pragma unroll
            for (int rr = 0; rr < 4; rr++)
                C[(rowo + rr) * ostride + col] = vals[rr];
        }
    }
}

// =================== conv1d + bn1 + relu -> hconv fp16 plane =================
__global__ __launch_bounds__(256) void k_conv2(const float* __restrict__ hq,
        const float* __restrict__ convw, const float* __restrict__ convb,
        const float* __restrict__ bn1, _Float16* __restrict__ hc) {
    __shared__ float hql[400];
    __shared__ float cwl[1280];
    __shared__ float scs[128], shs[128];
    int bl = blockIdx.x;
    int t = threadIdx.x;
    long b = bl;
    for (int i = t; i < 400; i += 256) hql[i] = hq[b * 400 + i];
    for (int i = t; i < 1280; i += 256) cwl[i] = convw[i];
    if (t < 128) {
        float g = bn1[t], be = bn1[CCH + t], m = bn1[2 * CCH + t], v = bn1[3 * CCH + t];
        float s = g * rsqrtf(v + EPSB);
        scs[t] = s;
        shs[t] = be - m * s + s * convb[t];
    }
    __syncthreads();
    int c = t >> 1, half = t & 1, p0 = half * 100;
    float cw[10];
    #pragma unroll
    for (int k = 0; k < 10; k++) cw[k] = cwl[c * 10 + k];
    float sc_ = scs[c], sh_ = shs[c];
    long obase = (long)bl * FCK + c * DIM + p0;
    for (int pc = 0; pc < 100; pc += 4) {
        float w0[8], w1[8];
        #pragma unroll
        for (int j = 0; j < 8; j++) {
            int pp = p0 + pc - 2 + j;
            bool ok = (pp >= 0 && pp < DIM);
            w0[j] = ok ? hql[pp] : 0.f;
            w1[j] = ok ? hql[DIM + pp] : 0.f;
        }
        h4 o;
        #pragma unroll
        for (int j = 0; j < 4; j++) {
            float s = 0.f;
            #pragma unroll
            for (int k = 0; k < 5; k++) s += w0[j + k] * cw[k] + w1[j + k] * cw[5 + k];
            o[j] = (_Float16)fmaxf(sc_ * s + sh_, 0.f);
        }
        *(h4*)&hc[obase + pc] = o;
    }
}

// =================== FC GEMM: fp16, LDS-staged B, split-K, atomics ===========
// grid (8, 128): 32 m-blocks x 32 splits; XCD swizzle (bid%8 = XCD).
__global__ __launch_bounds__(256) void k_fc2(
        const _Float16* __restrict__ A, const _Float16* __restrict__ B,
        float* __restrict__ fcsum) {
    __shared__ __align__(16) _Float16 ldsB[2][6656];   // 208 rows x 32 k
    int bid = blockIdx.y * 8 + blockIdx.x;
    int wsw = (bid & 7) * 128 + (bid >> 3);
    int mb = wsw & 31, split = wsw >> 5;
    int t = threadIdx.x;
    int w = t >> 6, l = t & 63;
    int kbase = split * KSEG;
    long arow = mb * 64 + w * 16 + (l & 15);
    int kg = (l >> 4) * 8;
    const _Float16* ahp = A + arow * FCK + kbase + kg;

    #pragma unroll
    for (int i = 0; i < 4; i++) {
        int u = i * 256 + t;
        if (u < 832) {
            int r = u >> 2, kc = u & 3;
            gload_lds16(B + (long)r * FCK + kbase + kc * 8, &ldsB[0][u * 8]);
        }
    }
    h8 aN = *(const h8*)(ahp);

    f32x4 acc[13];
    #pragma unroll
    for (int i = 0; i < 13; i++) acc[i] = (f32x4){0.f, 0.f, 0.f, 0.f};

    int buf = 0;
    for (int ks = 0; ks < 25; ks++) {
        __syncthreads();
        if (ks + 1 < 25) {
            int knext = kbase + (ks + 1) * 32;
            #pragma unroll
            for (int i = 0; i < 4; i++) {
                int u = i * 256 + t;
                if (u < 832) {
                    int r = u >> 2, kc = u & 3;
                    gload_lds16(B + (long)r * FCK + knext + kc * 8, &ldsB[buf ^ 1][u * 8]);
                }
            }
        }
        h8 aC = aN;
        if (ks + 1 < 25) aN = *(const h8*)(ahp + (ks + 1) * 32);
        const _Float16* b_base = &ldsB[buf][(l & 15) * 32 + kg];
        #pragma unroll
        for (int nt = 0; nt < 13; nt++) {
            h8 b = *(const h8*)(b_base + nt * 512);
            acc[nt] = __builtin_amdgcn_mfma_f32_16x16x32_f16(aC, b, acc[nt], 0, 0, 0);
        }
        buf ^= 1;
    }
    long rowo = mb * 64 + w * 16 + (l >> 4) * 4;
    #pragma unroll
    for (int nt = 0; nt < 13; nt++) {
        int col = nt * 16 + (l & 15);
        if (col < DIM) {
            #pragma unroll
            for (int rr = 0; rr < 4; rr++)
                unsafeAtomicAdd(&fcsum[(rowo + rr) * DIM + col], acc[nt][rr]);
        }
    }
}

// =================== fcsum + bias + bn2 + relu -> h3 fp16 plane ===============
__global__ void k_fcreduce(const float* __restrict__ fcsum, const float* __restrict__ fcb,
                           const float* __restrict__ bn2, _Float16* __restrict__ h3) {
    int i = blockIdx.x * 256 + threadIdx.x;
    if (i >= BQ * KPAD) return;
    int j = i % KPAD, b = i / KPAD;
    _Float16 o = (_Float16)0.f;
    if (j < DIM) {
        float s = fcsum[(long)b * DIM + j] + fcb[j];
        float g = bn2[j], be = bn2[DIM + j], m = bn2[2 * DIM + j], v = bn2[3 * DIM + j];
        s = g * (s - m) * rsqrtf(v + EPSB) + be;
        o = (_Float16)fmaxf(s, 0.f);
    }
    h3[i] = o;
}

// =================== final: sigmoid(h3 @ e_all^T), fp16 MFMA =================
// grid (8, 625), XCD swizzle; wave = 64 rows x 64 cols; A+B reg double-buffer.
// Epilogue: wave-local LDS transpose -> f32x4 nontemporal stores (full lines).
__global__ __launch_bounds__(256) void k_mfma_final(
        const _Float16* __restrict__ A, const _Float16* __restrict__ B,
        float* __restrict__ out) {
    __shared__ float tl[4][32][68];
    int bid = blockIdx.y * 8 + blockIdx.x;
    int wsw = (bid & 7) * 625 + (bid >> 3);
    int mbb = wsw & 7, nbb = wsw >> 3;
    int w = threadIdx.x >> 6, l = threadIdx.x & 63;
    int n0 = nbb * 64;
    int m0 = mbb * 256 + w * 64;
    int lr = l & 15;
    int kb = (l >> 4) * 8;
    const _Float16* aph = A + (long)(m0 + lr) * KPAD + kb;
    const _Float16* bph = B + (long)(n0 + lr) * KPAD + kb;
    h8 ac[4], bc[4], an[4], bn_[4];
    #pragma unroll
    for (int x = 0; x < 4; x++) {
        ac[x] = *(const h8*)(aph + (long)x * 16 * KPAD);
        bc[x] = *(const h8*)(bph + (long)x * 16 * KPAD);
    }
    f32x4 acc[4][4];
    #pragma unroll
    for (int i = 0; i < 4; i++)
        #pragma unroll
        for (int j = 0; j < 4; j++) acc[i][j] = (f32x4){0.f, 0.f, 0.f, 0.f};
    for (int kt = 0; kt < 7; kt++) {
        int ko = kt * 32 + 32;
        if (kt < 6) {
            #pragma unroll
            for (int x = 0; x < 4; x++) {
                an[x]  = *(const h8*)(aph + (long)x * 16 * KPAD + ko);
                bn_[x] = *(const h8*)(bph + (long)x * 16 * KPAD + ko);
            }
        }
        #pragma unroll
        for (int mt = 0; mt < 4; mt++)
            #pragma unroll
            for (int nt = 0; nt < 4; nt++)
                acc[mt][nt] = __builtin_amdgcn_mfma_f32_16x16x32_f16(ac[mt], bc[nt], acc[mt][nt], 0, 0, 0);
        if (kt < 6) {
            #pragma unroll
            for (int x = 0; x < 4; x++) { ac[x] = an[x]; bc[x] = bn_[x]; }
        }
    }
    // epilogue: per 32-row half, transpose via wave-local LDS, f32x4 NT stores
    #pragma unroll
    for (int hh = 0; hh < 2; hh++) {
        #pragma unroll
        for (int mt2 = 0; mt2 < 2; mt2++) {
            int mt = hh * 2 + mt2;
            #pragma unroll
            for (int nt = 0; nt < 4; nt++)
                #pragma unroll
                for (int r = 0; r < 4; r++)
                    tl[w][mt2 * 16 + (l >> 4) * 4 + r][nt * 16 + lr] = acc[mt][nt][r];
        }
        // wave-local LDS reuse: in-wave lgkmcnt ordering suffices (no barrier)
        #pragma unroll
        for (int i = 0; i < 8; i++) {
            int rr = i * 4 + (l >> 4);
            f32x4 v = *(const f32x4*)&tl[w][rr][lr * 4];
            f32x4 o;
            o.x = __builtin_amdgcn_rcpf(1.f + __expf(-v.x));
            o.y = __builtin_amdgcn_rcpf(1.f + __expf(-v.y));
            o.z = __builtin_amdgcn_rcpf(1.f + __expf(-v.z));
            o.w = __builtin_amdgcn_rcpf(1.f + __expf(-v.w));
            long row = m0 + hh * 32 + rr;
            __builtin_nontemporal_store(o, (f32x4*)&out[row * NENT + n0 + lr * 4]);
        }
    }
}

extern "C" void kernel_launch(void* const* d_in, const int* in_sizes, int n_in,
                              void* d_out, int out_size, void* d_ws, size_t ws_size,
                              hipStream_t stream) {
    (void)in_sizes; (void)n_in; (void)out_size; (void)ws_size;
    const int* src      = (const int*)d_in[0];
    const int* dst      = (const int*)d_in[1];
    const int* aet      = (const int*)d_in[2];
    const int* e1       = (const int*)d_in[3];
    const int* rel      = (const int*)d_in[4];
    const int* entity   = (const int*)d_in[5];
    const float* emb_e  = (const float*)d_in[6];
    const float* embrel = (const float*)d_in[7];
    const float* w2     = (const float*)d_in[8];
    const float* b2     = (const float*)d_in[9];
    const float* alpha2 = (const float*)d_in[10];
    const float* w3     = (const float*)d_in[11];
    const float* b3     = (const float*)d_in[12];
    const float* alpha3 = (const float*)d_in[13];
    const float* bn3    = (const float*)d_in[14];
    const float* bn4    = (const float*)d_in[15];
    const float* bn0    = (const float*)d_in[16];
    const float* bn1    = (const float*)d_in[17];
    const float* bn2    = (const float*)d_in[18];
    const float* convw  = (const float*)d_in[19];
    const float* convb  = (const float*)d_in[20];
    const float* fcw    = (const float*)d_in[21];
    const float* fcb    = (const float*)d_in[22];
    float* out = (float*)d_out;
    float* ws = (float*)d_ws;

    // ---- workspace layout (float offsets; non-overlapping, ~220MB) ----
    _Float16* emb16 = (_Float16*)ws;                 // [40000][104]
    _Float16* aggE  = (_Float16*)(ws + 3000000);     // [40000][128]
    _Float16* x1_f  = (_Float16*)(ws + 6000000);     // [40000][200] compact
    _Float16* aggX  = (_Float16*)(ws + 11000000);    // [40000][224]
    _Float16* e_f   = (_Float16*)(ws + 16000000);    // [40000][224]
    _Float16* fcw_f = (_Float16*)(ws + 21000000);    // [208][25600]
    _Float16* hc_f  = (_Float16*)(ws + 24000000);    // [2048][25600]
    int*   deg    = (int*)(ws + 51000000);
    int*   rowptr = (int*)(ws + 51050000);
    int*   cursor = (int*)(ws + 51100000);
    int*   ssrc   = (int*)(ws + 51200000);
    float* sa1    = ws + 51800000;
    float* sa2    = ws + 52400000;
    float* fcsum  = ws + 53000000;
    float* hq     = ws + 53500000;
    _Float16* h3_f  = (_Float16*)(ws + 54400000);    // [2048][224]
    _Float16* w2t_f = (_Float16*)(ws + 54700000);    // [208][128]
    _Float16* w3t_f = (_Float16*)(ws + 54750000);    // [224][224]

    // ---- CSR build (shared by both layers) ----
    hipMemsetAsync(deg, 0, NENT * 4, stream);
    k_hist<<<(NE + 255) / 256, 256, 0, stream>>>(dst, deg);
    k_scan<<<1, 1024, 0, stream>>>(deg, rowptr, cursor);
    k_scatter<<<(NE + 255) / 256, 256, 0, stream>>>(src, dst, aet, alpha2, alpha3,
                                                    cursor, ssrc, sa1, sa2);

    // ---- pack inputs ----
    k_pack_emb<<<(NENT * 13 + 255) / 256, 256, 0, stream>>>(emb_e, entity, emb16);
    k_pack_B16<<<(208 * 128 + 255) / 256, 256, 0, stream>>>(w2, w2t_f, DIM0, 128, 208);
    k_pack_B16<<<(224 * KPAD + 255) / 256, 256, 0, stream>>>(w3, w3t_f, DIM, KPAD, 224);

    // ---- GCN layer 1: aggregate RAW emb (linearity), then GEMM+bn3+tanh ----
    k_agg_raw<26, 32, EMBS, 128><<<NENT / 4, 256, 0, stream>>>(rowptr, ssrc, sa1,
                                                               emb16, aggE);
    k_gemm16f<13><<<NENT / 64, 256, 0, stream>>>(aggE, w2t_f, b2, bn3, x1_f, 128, DIM);

    // ---- GCN layer 2: aggregate x1, then GEMM+bn4+tanh -> e plane ----
    k_agg_raw<50, 56, DIM, KPAD><<<NENT / 4, 256, 0, stream>>>(rowptr, ssrc, sa2,
                                                               x1_f, aggX);
    k_gemm16f<14><<<NENT / 64, 256, 0, stream>>>(aggX, w3t_f, b3, bn4, e_f, KPAD, KPAD);

    // ---- decoder input + fcw pack ----
    k_hq<<<(BQ * 2 * DIM + 255) / 256, 256, 0, stream>>>(e1, rel, e_f, embrel, bn0, hq);
    k_pack_fcw<<<(int)(((long)208 * (FCK / 8) + 255) / 256), 256, 0, stream>>>(fcw, fcw_f);

    // ---- conv + FC (single pass, full batch) ----
    hipMemsetAsync(fcsum, 0, (size_t)BQ * DIM * 4, stream);
    k_conv2<<<BQ, 256, 0, stream>>>(hq, convw, convb, bn1, hc_f);
    k_fc2<<<dim3(8, 128), 256, 0, stream>>>(hc_f, fcw_f, fcsum);
    k_fcreduce<<<(BQ * KPAD + 255) / 256, 256, 0, stream>>>(fcsum, fcb, bn2, h3_f);

    // ---- final scoring ----
    k_mfma_final<<<dim3(8, NENT / 64), 256, 0, stream>>>(h3_f, e_f, out);
}

// Round 15
// 518.341 us; speedup vs baseline: 8.7705x; 1.0494x over previous
//
#include <hip/hip_runtime.h>
#include <math.h>

#define NENT 40000
#define NTE  250000
#define NE   540000      // 2*NTE + NENT
#define DIM0 100
#define DIM  200
#define CCH  128
#define BQ   2048
#define FCK  25600       // CCH*DIM
#define EPSB 1e-5f
#define KPAD 224         // 200 padded to 7*32
#define EMBS 104         // emb16 row stride

typedef float f32x4 __attribute__((ext_vector_type(4)));
typedef _Float16 h8 __attribute__((ext_vector_type(8)));
typedef _Float16 h4 __attribute__((ext_vector_type(4)));

// =================== CSR build ===================
__global__ void k_hist(const int* __restrict__ dst, int* __restrict__ deg) {
    int e = blockIdx.x * 256 + threadIdx.x;
    if (e < NE) atomicAdd(&deg[dst[e]], 1);
}

__global__ __launch_bounds__(1024) void k_scan(const int* __restrict__ deg,
        int* __restrict__ rowptr, int* __restrict__ cursor) {
    __shared__ int sums[1024];
    int t = threadIdx.x;
    int base = t * 40;
    int local[40];
    int s = 0;
    #pragma unroll
    for (int i = 0; i < 40; i++) {
        int idx = base + i;
        int v = (idx < NENT) ? deg[idx] : 0;
        local[i] = s;
        s += v;
    }
    sums[t] = s;
    __syncthreads();
    #pragma unroll
    for (int off = 1; off < 1024; off <<= 1) {
        int add = (t >= off) ? sums[t - off] : 0;
        __syncthreads();
        sums[t] += add;
        __syncthreads();
    }
    int prefix = (t == 0) ? 0 : sums[t - 1];
    #pragma unroll
    for (int i = 0; i < 40; i++) {
        int idx = base + i;
        if (idx < NENT) {
            int p = prefix + local[i];
            rowptr[idx] = p;
            cursor[idx] = p;
        }
    }
    if (t == 1023) rowptr[NENT] = prefix + s;
}

__global__ void k_scatter(const int* __restrict__ src, const int* __restrict__ dst,
                          const int* __restrict__ aet, const float* __restrict__ a2t,
                          const float* __restrict__ a3t, int* __restrict__ cursor,
                          int* __restrict__ ssrc, float* __restrict__ sa1,
                          float* __restrict__ sa2) {
    int e = blockIdx.x * 256 + threadIdx.x;
    if (e >= NE) return;
    int tt = (e < NTE) ? e + NTE : (e < 2 * NTE ? e - NTE : e);
    int t0 = aet[e], t1 = aet[tt];
    int pos = atomicAdd(&cursor[dst[e]], 1);
    ssrc[pos] = src[e];
    sa1[pos] = a2t[t0] + a2t[t1];
    sa2[pos] = a3t[t0] + a3t[t1];
}

// =================== raw CSR aggregation (pre-GEMM, linearity) ===============
template<int NL, int NPADL, int SS, int OS>
__global__ __launch_bounds__(256) void k_agg_raw(const int* __restrict__ rowptr,
        const int* __restrict__ ssrc, const float* __restrict__ sa,
        const _Float16* __restrict__ srcd, _Float16* __restrict__ outd) {
    int w = threadIdx.x >> 6, l = threadIdx.x & 63;
    int row = blockIdx.x * 4 + w;
    int beg = rowptr[row], end = rowptr[row + 1];
    bool act = l < NL;
    int col = l * 4;
    float sx = 0.f, sy = 0.f, sz = 0.f, sw = 0.f;
    int i = beg;
    for (; i + 4 <= end; i += 4) {
        int i0 = ssrc[i], i1 = ssrc[i + 1], i2 = ssrc[i + 2], i3 = ssrc[i + 3];
        float a0 = sa[i], a1 = sa[i + 1], a2 = sa[i + 2], a3 = sa[i + 3];
        if (act) {
            h4 v0 = *(const h4*)(srcd + (long)i0 * SS + col);
            h4 v1 = *(const h4*)(srcd + (long)i1 * SS + col);
            h4 v2 = *(const h4*)(srcd + (long)i2 * SS + col);
            h4 v3 = *(const h4*)(srcd + (long)i3 * SS + col);
            sx += a0 * (float)v0[0] + a1 * (float)v1[0] + a2 * (float)v2[0] + a3 * (float)v3[0];
            sy += a0 * (float)v0[1] + a1 * (float)v1[1] + a2 * (float)v2[1] + a3 * (float)v3[1];
            sz += a0 * (float)v0[2] + a1 * (float)v1[2] + a2 * (float)v2[2] + a3 * (float)v3[2];
            sw += a0 * (float)v0[3] + a1 * (float)v1[3] + a2 * (float)v2[3] + a3 * (float)v3[3];
        }
    }
    for (; i < end; i++) {
        int i0 = ssrc[i];
        float a0 = sa[i];
        if (act) {
            h4 v0 = *(const h4*)(srcd + (long)i0 * SS + col);
            sx += a0 * (float)v0[0]; sy += a0 * (float)v0[1];
            sz += a0 * (float)v0[2]; sw += a0 * (float)v0[3];
        }
    }
    if (act) {
        h4 o = { (_Float16)sx, (_Float16)sy, (_Float16)sz, (_Float16)sw };
        *(h4*)(outd + (long)row * OS + col) = o;
    } else if (l < NPADL) {
        h4 z = { (_Float16)0.f, (_Float16)0.f, (_Float16)0.f, (_Float16)0.f };
        *(h4*)(outd + (long)row * OS + col) = z;
    }
}

// =================== packing kernels ===================
__global__ void k_pack_emb(const float* __restrict__ emb, const int* __restrict__ ent,
                           _Float16* __restrict__ o) {
    long i = (long)blockIdx.x * 256 + threadIdx.x;
    if (i >= (long)NENT * 13) return;
    long m = i / 13;
    int k0 = (int)(i % 13) * 8;
    h8 h = {};
    const float* p = emb + (long)ent[m] * DIM0 + k0;
    #pragma unroll
    for (int j = 0; j < 8; j++)
        if (k0 + j < DIM0) h[j] = (_Float16)p[j];
    *(h8*)(o + m * EMBS + k0) = h;
}

__global__ void k_pack_B16(const float* __restrict__ w, _Float16* __restrict__ bf,
                           int kin, int kpad, int nrows) {
    int i = blockIdx.x * 256 + threadIdx.x;
    if (i >= nrows * kpad) return;
    int k = i % kpad, n = i / kpad;
    bf[i] = (k < kin && n < DIM) ? (_Float16)w[(long)k * DIM + n] : (_Float16)0.f;
}

// decoder input: bn0-normalized [e(fp16 plane); rel_emb] -> hq16 fp16 [2048][400]
__global__ void k_hq16(const int* __restrict__ e1, const int* __restrict__ rel,
                       const _Float16* __restrict__ ef, const float* __restrict__ embrel,
                       const float* __restrict__ bn0, _Float16* __restrict__ hq) {
    int i = blockIdx.x * 256 + threadIdx.x;
    if (i >= BQ * 2 * DIM) return;
    int d = i % DIM, c = (i / DIM) & 1, b = i / (2 * DIM);
    float val = (c == 0) ? (float)ef[(long)e1[b] * KPAD + d]
                         : embrel[(long)rel[b] * DIM + d];
    float g = bn0[c], be = bn0[2 + c], m = bn0[4 + c], v = bn0[6 + c];
    hq[i] = (_Float16)(g * (val - m) * rsqrtf(v + EPSB) + be);
}

// fcw [200][25600] -> fp16 plane [208][FCK] (rows >=200 zero)
__global__ void k_pack_fcw(const float* __restrict__ w, _Float16* __restrict__ wf) {
    long i = (long)blockIdx.x * 256 + threadIdx.x;
    if (i >= (long)208 * (FCK / 8)) return;
    int n = (int)(i / (FCK / 8));
    long k0 = (i % (FCK / 8)) * 8;
    h8 h = {};
    if (n < DIM) {
        const float* p = w + (long)n * FCK + k0;
        #pragma unroll
        for (int j = 0; j < 8; j++) h[j] = (_Float16)p[j];
    }
    *(h8*)(wf + (long)n * FCK + k0) = h;
}

// ======= layer GEMM fused epilogue: C = tanh(bn(A@B + bias)) -> fp16 =========
template<int NT>
__global__ __launch_bounds__(256) void k_gemm16f(
        const _Float16* __restrict__ A, const _Float16* __restrict__ B,
        const float* __restrict__ bias, const float* __restrict__ bn,
        _Float16* __restrict__ C, int kpad, int ostride) {
    int w = threadIdx.x >> 6, l = threadIdx.x & 63;
    long m0 = (long)blockIdx.x * 64 + w * 16;
    long arow = m0 + (l & 15);
    int kg = (l >> 4) * 8;
    const _Float16* ap = A + arow * kpad + kg;
    f32x4 acc[NT];
    #pragma unroll
    for (int i = 0; i < NT; i++) acc[i] = (f32x4){0.f, 0.f, 0.f, 0.f};
    for (int kb = 0; kb < kpad; kb += 32) {
        h8 a = *(const h8*)(ap + kb);
        #pragma unroll
        for (int nt = 0; nt < NT; nt++) {
            h8 b = *(const h8*)(B + (long)(nt * 16 + (l & 15)) * kpad + kb + kg);
            acc[nt] = __builtin_amdgcn_mfma_f32_16x16x32_f16(a, b, acc[nt], 0, 0, 0);
        }
    }
    long rowo = m0 + (l >> 4) * 4;
    #pragma unroll
    for (int nt = 0; nt < NT; nt++) {
        int col = nt * 16 + (l & 15);
        if (col < ostride) {
            _Float16 vals[4];
            if (col < DIM) {
                float g = bn[col], be = bn[DIM + col], m = bn[2 * DIM + col],
                      v = bn[3 * DIM + col], bb = bias[col];
                float sc = g * rsqrtf(v + EPSB);
                #pragma unroll
                for (int rr = 0; rr < 4; rr++)
                    vals[rr] = (_Float16)tanhf(sc * (acc[nt][rr] + bb - m) + be);
            } else {
                #pragma unroll
                for (int rr = 0; rr < 4; rr++) vals[rr] = (_Float16)0.f;
            }
            #pragma unroll
            for (int rr = 0; rr < 4; rr++)
                C[(rowo + rr) * ostride + col] = vals[rr];
        }
    }
}

// =========== FUSED conv1d+bn1+relu + FC GEMM (split-K, atomics) ==============
// grid (8, 128): wsw=(bid%8)*128+bid/8; mb = wsw&31 (64-row tile), split =
// wsw>>5 (k in [split*800,+800) = 4 whole channels). Per k-step: threads
// compute the [64][32] conv A-tile in regs from L2-resident hq16, B is
// reg-staged; both go to single-buffered LDS (stride 40h kills the 8-way
// ds_read_b128 bank conflict of the old 32h layout); 2 barriers per k-step.
__global__ __launch_bounds__(256) void k_convfc(
        const _Float16* __restrict__ hq16, const float* __restrict__ convw,
        const float* __restrict__ convb, const float* __restrict__ bn1,
        const _Float16* __restrict__ B, float* __restrict__ fcsum) {
    __shared__ _Float16 ldsA[64][40];
    __shared__ _Float16 ldsB[208][40];
    __shared__ float cwl[4][12];
    int bid = blockIdx.y * 8 + blockIdx.x;
    int wsw = (bid & 7) * 128 + (bid >> 3);
    int mb = wsw & 31, split = wsw >> 5;
    int t = threadIdx.x;
    int w = t >> 6, l = t & 63;
    int kbase = split * 800;
    int c0 = split * 4;
    if (t < 40) cwl[t / 10][t % 10] = convw[(c0 + t / 10) * 10 + t % 10];
    if (t < 4) {
        int c = c0 + t;
        float g = bn1[c], be = bn1[CCH + c], m = bn1[2 * CCH + c], v = bn1[3 * CCH + c];
        float s = g * rsqrtf(v + EPSB);
        cwl[t][10] = s;
        cwl[t][11] = be - m * s + s * convb[c];
    }
    __syncthreads();

    int r = t >> 2, q = t & 3;
    const _Float16* hrow = hq16 + (long)(mb * 64 + r) * 400;

    h8 z = {};
    h8 v0a, v1a, v2a, v0b, v1b, v2b;
    {
        int p = q * 8;                      // ks=0: off = q*8 < 200 -> p = off
        v0a = (p >= 8) ? *(const h8*)(hrow + p - 8) : z;
        v1a = *(const h8*)(hrow + p);
        v2a = (p + 8 < DIM) ? *(const h8*)(hrow + p + 8) : z;
        v0b = (p >= 8) ? *(const h8*)(hrow + DIM + p - 8) : z;
        v1b = *(const h8*)(hrow + DIM + p);
        v2b = (p + 8 < DIM) ? *(const h8*)(hrow + DIM + p + 8) : z;
    }
    h8 bR[4];
    #pragma unroll
    for (int i2 = 0; i2 < 4; i2++) {
        int u = i2 * 256 + t;
        bR[i2] = (u < 832) ? *(const h8*)(B + (long)(u >> 2) * FCK + kbase + (u & 3) * 8) : z;
    }

    f32x4 acc[13];
    #pragma unroll
    for (int i = 0; i < 13; i++) acc[i] = (f32x4){0.f, 0.f, 0.f, 0.f};

    for (int ks = 0; ks < 25; ks++) {
        // ---- conv compute for ks (window regs -> 8 fp16 outputs) ----
        int off = ks * 32 + q * 8;
        int cl = off / 200;                 // output channel (local), const per group
        float cwv[12];
        #pragma unroll
        for (int k2 = 0; k2 < 12; k2++) cwv[k2] = cwl[cl][k2];
        float wa[12], wb[12];
        wa[0] = (float)v0a[6]; wa[1] = (float)v0a[7];
        wb[0] = (float)v0b[6]; wb[1] = (float)v0b[7];
        #pragma unroll
        for (int m2 = 0; m2 < 8; m2++) {
            wa[2 + m2] = (float)v1a[m2];
            wb[2 + m2] = (float)v1b[m2];
        }
        wa[10] = (float)v2a[0]; wa[11] = (float)v2a[1];
        wb[10] = (float)v2b[0]; wb[11] = (float)v2b[1];
        h8 aOut;
        #pragma unroll
        for (int j = 0; j < 8; j++) {
            float s = 0.f;
            #pragma unroll
            for (int kk = 0; kk < 5; kk++)
                s += wa[j + kk] * cwv[kk] + wb[j + kk] * cwv[5 + kk];
            aOut[j] = (_Float16)fmaxf(cwv[10] * s + cwv[11], 0.f);
        }
        // ---- write A,B tiles to LDS (prev MFMA reads done: trailing barrier) ----
        *(h8*)&ldsA[r][q * 8] = aOut;
        #pragma unroll
        for (int i2 = 0; i2 < 4; i2++) {
            int u = i2 * 256 + t;
            if (u < 832) *(h8*)&ldsB[u >> 2][(u & 3) * 8] = bR[i2];
        }
        __syncthreads();
        // ---- prefetch ks+1 (latency hides under MFMA) ----
        if (ks + 1 < 25) {
            int off1 = (ks + 1) * 32 + q * 8;
            int cl1 = off1 / 200;
            int p1 = off1 - cl1 * 200;
            v0a = (p1 >= 8) ? *(const h8*)(hrow + p1 - 8) : z;
            v1a = *(const h8*)(hrow + p1);
            v2a = (p1 + 8 < DIM) ? *(const h8*)(hrow + p1 + 8) : z;
            v0b = (p1 >= 8) ? *(const h8*)(hrow + DIM + p1 - 8) : z;
            v1b = *(const h8*)(hrow + DIM + p1);
            v2b = (p1 + 8 < DIM) ? *(const h8*)(hrow + DIM + p1 + 8) : z;
            int knext = kbase + (ks + 1) * 32;
            #pragma unroll
            for (int i2 = 0; i2 < 4; i2++) {
                int u = i2 * 256 + t;
                if (u < 832) bR[i2] = *(const h8*)(B + (long)(u >> 2) * FCK + knext + (u & 3) * 8);
            }
        }
        // ---- MFMA on current LDS tiles ----
        h8 a = *(const h8*)&ldsA[w * 16 + (l & 15)][(l >> 4) * 8];
        #pragma unroll
        for (int nt = 0; nt < 13; nt++) {
            h8 b = *(const h8*)&ldsB[nt * 16 + (l & 15)][(l >> 4) * 8];
            acc[nt] = __builtin_amdgcn_mfma_f32_16x16x32_f16(a, b, acc[nt], 0, 0, 0);
        }
        __syncthreads();
    }
    long rowo = mb * 64 + w * 16 + (l >> 4) * 4;
    #pragma unroll
    for (int nt = 0; nt < 13; nt++) {
        int col = nt * 16 + (l & 15);
        if (col < DIM) {
            #pragma unroll
            for (int rr = 0; rr < 4; rr++)
                unsafeAtomicAdd(&fcsum[(rowo + rr) * DIM + col], acc[nt][rr]);
        }
    }
}

// =================== fcsum + bias + bn2 + relu -> h3 fp16 plane ===============
__global__ void k_fcreduce(const float* __restrict__ fcsum, const float* __restrict__ fcb,
                           const float* __restrict__ bn2, _Float16* __restrict__ h3) {
    int i = blockIdx.x * 256 + threadIdx.x;
    if (i >= BQ * KPAD) return;
    int j = i % KPAD, b = i / KPAD;
    _Float16 o = (_Float16)0.f;
    if (j < DIM) {
        float s = fcsum[(long)b * DIM + j] + fcb[j];
        float g = bn2[j], be = bn2[DIM + j], m = bn2[2 * DIM + j], v = bn2[3 * DIM + j];
        s = g * (s - m) * rsqrtf(v + EPSB) + be;
        o = (_Float16)fmaxf(s, 0.f);
    }
    h3[i] = o;
}

// =================== final: sigmoid(h3 @ e_all^T), fp16 MFMA =================
__global__ __launch_bounds__(256) void k_mfma_final(
        const _Float16* __restrict__ A, const _Float16* __restrict__ B,
        float* __restrict__ out) {
    __shared__ float tl[4][32][68];
    int bid = blockIdx.y * 8 + blockIdx.x;
    int wsw = (bid & 7) * 625 + (bid >> 3);
    int mbb = wsw & 7, nbb = wsw >> 3;
    int w = threadIdx.x >> 6, l = threadIdx.x & 63;
    int n0 = nbb * 64;
    int m0 = mbb * 256 + w * 64;
    int lr = l & 15;
    int kb = (l >> 4) * 8;
    const _Float16* aph = A + (long)(m0 + lr) * KPAD + kb;
    const _Float16* bph = B + (long)(n0 + lr) * KPAD + kb;
    h8 ac[4], bc[4], an[4], bn_[4];
    #pragma unroll
    for (int x = 0; x < 4; x++) {
        ac[x] = *(const h8*)(aph + (long)x * 16 * KPAD);
        bc[x] = *(const h8*)(bph + (long)x * 16 * KPAD);
    }
    f32x4 acc[4][4];
    #pragma unroll
    for (int i = 0; i < 4; i++)
        #pragma unroll
        for (int j = 0; j < 4; j++) acc[i][j] = (f32x4){0.f, 0.f, 0.f, 0.f};
    for (int kt = 0; kt < 7; kt++) {
        int ko = kt * 32 + 32;
        if (kt < 6) {
            #pragma unroll
            for (int x = 0; x < 4; x++) {
                an[x]  = *(const h8*)(aph + (long)x * 16 * KPAD + ko);
                bn_[x] = *(const h8*)(bph + (long)x * 16 * KPAD + ko);
            }
        }
        #pragma unroll
        for (int mt = 0; mt < 4; mt++)
            #pragma unroll
            for (int nt = 0; nt < 4; nt++)
                acc[mt][nt] = __builtin_amdgcn_mfma_f32_16x16x32_f16(ac[mt], bc[nt], acc[mt][nt], 0, 0, 0);
        if (kt < 6) {
            #pragma unroll
            for (int x = 0; x < 4; x++) { ac[x] = an[x]; bc[x] = bn_[x]; }
        }
    }
    #pragma unroll
    for (int hh = 0; hh < 2; hh++) {
        #pragma unroll
        for (int mt2 = 0; mt2 < 2; mt2++) {
            int mt = hh * 2 + mt2;
            #pragma unroll
            for (int nt = 0; nt < 4; nt++)
                #pragma unroll
                for (int r = 0; r < 4; r++)
                    tl[w][mt2 * 16 + (l >> 4) * 4 + r][nt * 16 + lr] = acc[mt][nt][r];
        }
        #pragma unroll
        for (int i = 0; i < 8; i++) {
            int rr = i * 4 + (l >> 4);
            f32x4 v = *(const f32x4*)&tl[w][rr][lr * 4];
            f32x4 o;
            o.x = __builtin_amdgcn_rcpf(1.f + __expf(-v.x));
            o.y = __builtin_amdgcn_rcpf(1.f + __expf(-v.y));
            o.z = __builtin_amdgcn_rcpf(1.f + __expf(-v.z));
            o.w = __builtin_amdgcn_rcpf(1.f + __expf(-v.w));
            long row = m0 + hh * 32 + rr;
            __builtin_nontemporal_store(o, (f32x4*)&out[row * NENT + n0 + lr * 4]);
        }
    }
}

extern "C" void kernel_launch(void* const* d_in, const int* in_sizes, int n_in,
                              void* d_out, int out_size, void* d_ws, size_t ws_size,
                              hipStream_t stream) {
    (void)in_sizes; (void)n_in; (void)out_size; (void)ws_size;
    const int* src      = (const int*)d_in[0];
    const int* dst      = (const int*)d_in[1];
    const int* aet      = (const int*)d_in[2];
    const int* e1       = (const int*)d_in[3];
    const int* rel      = (const int*)d_in[4];
    const int* entity   = (const int*)d_in[5];
    const float* emb_e  = (const float*)d_in[6];
    const float* embrel = (const float*)d_in[7];
    const float* w2     = (const float*)d_in[8];
    const float* b2     = (const float*)d_in[9];
    const float* alpha2 = (const float*)d_in[10];
    const float* w3     = (const float*)d_in[11];
    const float* b3     = (const float*)d_in[12];
    const float* alpha3 = (const float*)d_in[13];
    const float* bn3    = (const float*)d_in[14];
    const float* bn4    = (const float*)d_in[15];
    const float* bn0    = (const float*)d_in[16];
    const float* bn1    = (const float*)d_in[17];
    const float* bn2    = (const float*)d_in[18];
    const float* convw  = (const float*)d_in[19];
    const float* convb  = (const float*)d_in[20];
    const float* fcw    = (const float*)d_in[21];
    const float* fcb    = (const float*)d_in[22];
    float* out = (float*)d_out;
    float* ws = (float*)d_ws;

    // ---- workspace layout (float offsets; non-overlapping) ----
    _Float16* emb16 = (_Float16*)ws;                 // [40000][104]
    _Float16* aggE  = (_Float16*)(ws + 3000000);     // [40000][128]
    _Float16* x1_f  = (_Float16*)(ws + 6000000);     // [40000][200]
    _Float16* aggX  = (_Float16*)(ws + 11000000);    // [40000][224]
    _Float16* e_f   = (_Float16*)(ws + 16000000);    // [40000][224]
    _Float16* fcw_f = (_Float16*)(ws + 21000000);    // [208][25600]
    _Float16* hq16  = (_Float16*)(ws + 24000000);    // [2048][400]
    int*   deg    = (int*)(ws + 51000000);
    int*   rowptr = (int*)(ws + 51050000);
    int*   cursor = (int*)(ws + 51100000);
    int*   ssrc   = (int*)(ws + 51200000);
    float* sa1    = ws + 51800000;
    float* sa2    = ws + 52400000;
    float* fcsum  = ws + 53000000;
    _Float16* h3_f  = (_Float16*)(ws + 54400000);    // [2048][224]
    _Float16* w2t_f = (_Float16*)(ws + 54700000);    // [208][128]
    _Float16* w3t_f = (_Float16*)(ws + 54750000);    // [224][224]

    // ---- CSR build (shared by both layers) ----
    hipMemsetAsync(deg, 0, NENT * 4, stream);
    k_hist<<<(NE + 255) / 256, 256, 0, stream>>>(dst, deg);
    k_scan<<<1, 1024, 0, stream>>>(deg, rowptr, cursor);
    k_scatter<<<(NE + 255) / 256, 256, 0, stream>>>(src, dst, aet, alpha2, alpha3,
                                                    cursor, ssrc, sa1, sa2);

    // ---- pack inputs ----
    k_pack_emb<<<(NENT * 13 + 255) / 256, 256, 0, stream>>>(emb_e, entity, emb16);
    k_pack_B16<<<(208 * 128 + 255) / 256, 256, 0, stream>>>(w2, w2t_f, DIM0, 128, 208);
    k_pack_B16<<<(224 * KPAD + 255) / 256, 256, 0, stream>>>(w3, w3t_f, DIM, KPAD, 224);

    // ---- GCN layer 1: aggregate RAW emb (linearity), then GEMM+bn3+tanh ----
    k_agg_raw<26, 32, EMBS, 128><<<NENT / 4, 256, 0, stream>>>(rowptr, ssrc, sa1,
                                                               emb16, aggE);
    k_gemm16f<13><<<NENT / 64, 256, 0, stream>>>(aggE, w2t_f, b2, bn3, x1_f, 128, DIM);

    // ---- GCN layer 2: aggregate x1, then GEMM+bn4+tanh -> e plane ----
    k_agg_raw<50, 56, DIM, KPAD><<<NENT / 4, 256, 0, stream>>>(rowptr, ssrc, sa2,
                                                               x1_f, aggX);
    k_gemm16f<14><<<NENT / 64, 256, 0, stream>>>(aggX, w3t_f, b3, bn4, e_f, KPAD, KPAD);

    // ---- decoder input + fcw pack ----
    k_hq16<<<(BQ * 2 * DIM + 255) / 256, 256, 0, stream>>>(e1, rel, e_f, embrel, bn0, hq16);
    k_pack_fcw<<<(int)(((long)208 * (FCK / 8) + 255) / 256), 256, 0, stream>>>(fcw, fcw_f);

    // ---- fused conv + FC (no hconv materialization) ----
    hipMemsetAsync(fcsum, 0, (size_t)BQ * DIM * 4, stream);
    k_convfc<<<dim3(8, 128), 256, 0, stream>>>(hq16, convw, convb, bn1, fcw_f, fcsum);
    k_fcreduce<<<(BQ * KPAD + 255) / 256, 256, 0, stream>>>(fcsum, fcb, bn2, h3_f);

    // ---- final scoring ----
    k_mfma_final<<<dim3(8, NENT / 64), 256, 0, stream>>>(h3_f, e_f, out);
}